// Round 2
// baseline (1484.290 us; speedup 1.0000x reference)
//
#include <hip/hip_runtime.h>
#include <math.h>

#define LALPHA 0.2f

__device__ __forceinline__ float wave_sum(float v) {
#pragma unroll
  for (int off = 32; off > 0; off >>= 1) v += __shfl_xor(v, off);
  return v;
}
__device__ __forceinline__ float wave_max(float v) {
#pragma unroll
  for (int off = 32; off > 0; off >>= 1) v = fmaxf(v, __shfl_xor(v, off));
  return v;
}
__device__ __forceinline__ float lrelu(float x) { return x >= 0.f ? x : LALPHA * x; }

// bf16 pair <-> float2 helpers (manual bit ops; bf16 = high 16 bits of f32)
__device__ __forceinline__ float2 bfp2f(unsigned int u) {
  float lo = __uint_as_float(u << 16);
  float hi = __uint_as_float(u & 0xffff0000u);
  return make_float2(lo, hi);
}
__device__ __forceinline__ unsigned short f2bf(float x) {
  unsigned int b = __float_as_uint(x);
  return (unsigned short)((b + 0x7fffu + ((b >> 16) & 1u)) >> 16);  // RNE
}

// ---------------- CSR build ----------------
__global__ void zero2_kernel(int* a, int* b, int n) {
  for (int i = blockIdx.x * blockDim.x + threadIdx.x; i < n; i += gridDim.x * blockDim.x) {
    a[i] = 0;
    b[i] = 0;
  }
}

__global__ void hist_kernel(const int* __restrict__ adj, int* __restrict__ deg, int E) {
  for (int e = blockIdx.x * blockDim.x + threadIdx.x; e < E; e += gridDim.x * blockDim.x)
    atomicAdd(&deg[adj[2 * e]], 1);
}

__global__ void scan_kernel(const int* __restrict__ deg, int* __restrict__ row_ptr, int n) {
  __shared__ int sm[1024];
  int tid = threadIdx.x;
  int carry = 0;
  for (int base = 0; base < n; base += 1024) {
    int idx = base + tid;
    int v = (idx < n) ? deg[idx] : 0;
    sm[tid] = v;
    __syncthreads();
    for (int off = 1; off < 1024; off <<= 1) {
      int t = (tid >= off) ? sm[tid - off] : 0;
      __syncthreads();
      sm[tid] += t;
      __syncthreads();
    }
    if (idx < n) row_ptr[idx] = carry + sm[tid] - v;
    carry += sm[1023];
    __syncthreads();  // protect sm before next chunk overwrites
  }
  if (tid == 0) row_ptr[n] = carry;
}

__global__ void scatter_kernel(const int* __restrict__ adj, const float* __restrict__ av,
                               const int* __restrict__ row_ptr, int* __restrict__ cursor,
                               int* __restrict__ csr_dst, float* __restrict__ csr_w, int E) {
  for (int e = blockIdx.x * blockDim.x + threadIdx.x; e < E; e += gridDim.x * blockDim.x) {
    int s = adj[2 * e], d = adj[2 * e + 1];
    int pos = row_ptr[s] + atomicAdd(&cursor[s], 1);
    csr_dst[pos] = d;
    csr_w[pos] = av[e];
  }
}

// ---------------- ft = features @ W_trans (all heads), bf16 output ----------------
// A: N x 256 row-major f32. W: (H,256,128) f32. Output ft layout (H,N,128) bf16.
__global__ __launch_bounds__(256) void gemm_kernel(const float* __restrict__ A,
                                                   const float* __restrict__ W,
                                                   unsigned short* __restrict__ ft, int N) {
  const int K = 256, D = 128;
  __shared__ float As[16][64];
  __shared__ float Bs[16][64];
  int n0 = blockIdx.x * 64;
  int c0 = blockIdx.y * 64;  // global column = h*128 + d; 64-wide tile stays in one head
  int h = c0 >> 7;
  int db = c0 & 127;
  int tid = threadIdx.x;
  int tx = tid & 15, ty = tid >> 4;
  int la_n = tid >> 2, la_k = (tid & 3) * 4;
  int lb_k = tid >> 4, lb_c = (tid & 15) * 4;
  float acc[4][4] = {};
  for (int k0 = 0; k0 < K; k0 += 16) {
    int n = n0 + la_n;
    float4 av = make_float4(0.f, 0.f, 0.f, 0.f);
    if (n < N) av = *(const float4*)&A[(size_t)n * K + k0 + la_k];
    As[la_k + 0][la_n] = av.x;
    As[la_k + 1][la_n] = av.y;
    As[la_k + 2][la_n] = av.z;
    As[la_k + 3][la_n] = av.w;
    float4 bv = *(const float4*)&W[(size_t)h * K * D + (size_t)(k0 + lb_k) * D + db + lb_c];
    Bs[lb_k][lb_c + 0] = bv.x;
    Bs[lb_k][lb_c + 1] = bv.y;
    Bs[lb_k][lb_c + 2] = bv.z;
    Bs[lb_k][lb_c + 3] = bv.w;
    __syncthreads();
#pragma unroll
    for (int kk = 0; kk < 16; ++kk) {
      float4 a = *(const float4*)&As[kk][ty * 4];
      float4 b = *(const float4*)&Bs[kk][tx * 4];
      float ar[4] = {a.x, a.y, a.z, a.w};
      float br[4] = {b.x, b.y, b.z, b.w};
#pragma unroll
      for (int r = 0; r < 4; ++r)
#pragma unroll
        for (int c = 0; c < 4; ++c) acc[r][c] = fmaf(ar[r], br[c], acc[r][c]);
    }
    __syncthreads();
  }
#pragma unroll
  for (int r = 0; r < 4; ++r) {
    int n = n0 + ty * 4 + r;
    if (n < N) {
      ushort4 o;
      o.x = f2bf(acc[r][0]);
      o.y = f2bf(acc[r][1]);
      o.z = f2bf(acc[r][2]);
      o.w = f2bf(acc[r][3]);
      *(ushort4*)&ft[((size_t)h * N + n) * D + db + tx * 4] = o;
    }
  }
}

// ---------------- per-node prep: rnorm, ftx, fty ----------------
__global__ __launch_bounds__(256) void node_prep(const unsigned short* __restrict__ ft,
                                                 const float* __restrict__ w_ftx,
                                                 const float* __restrict__ w_fty,
                                                 float* __restrict__ rnorm,
                                                 float* __restrict__ ftx,
                                                 float* __restrict__ fty, int N, int H) {
  int wid = blockIdx.x * 4 + (threadIdx.x >> 6);  // wid = h*N + n
  int lane = threadIdx.x & 63;
  if (wid >= N * H) return;
  int h = wid / N;
  float2 f = bfp2f(*(const unsigned int*)&ft[(size_t)wid * 128 + lane * 2]);
  float2 wx = *(const float2*)&w_ftx[(size_t)h * 128 + lane * 2];
  float2 wy = *(const float2*)&w_fty[(size_t)h * 128 + lane * 2];
  float ss = wave_sum(f.x * f.x + f.y * f.y);
  float sx = wave_sum(f.x * wx.x + f.y * wx.y);
  float sy = wave_sum(f.x * wy.x + f.y * wy.y);
  if (lane == 0) {
    rnorm[wid] = rsqrtf(fmaxf(ss, 1e-12f));
    ftx[wid] = sx;
    fty[wid] = sy;
  }
}

// ---------------- per-edge cosine similarity ----------------
__global__ __launch_bounds__(256) void sim_kernel(const unsigned short* __restrict__ ft,
                                                  const float* __restrict__ rnorm,
                                                  const int* __restrict__ row_ptr,
                                                  const int* __restrict__ csr_dst,
                                                  float* __restrict__ sim, int E, int N,
                                                  const int* __restrict__ src_of) {
  int h = blockIdx.y;
  int j = blockIdx.x * 4 + (threadIdx.x >> 6);
  int lane = threadIdx.x & 63;
  if (j >= E) return;
  int s = src_of[j], d = csr_dst[j];
  float2 a = bfp2f(*(const unsigned int*)&ft[((size_t)h * N + s) * 128 + lane * 2]);
  float2 b = bfp2f(*(const unsigned int*)&ft[((size_t)h * N + d) * 128 + lane * 2]);
  float p = wave_sum(a.x * b.x + a.y * b.y);
  if (lane == 0)
    sim[(size_t)h * E + j] = p * rnorm[(size_t)h * N + s] * rnorm[(size_t)h * N + d];
}

// fill src_of[j] = owning node of CSR slot j (wave per node)
__global__ void srcfill_kernel(const int* __restrict__ row_ptr, int* __restrict__ src_of,
                               int N) {
  int n = blockIdx.x * 4 + (threadIdx.x >> 6);
  int lane = threadIdx.x & 63;
  if (n >= N) return;
  int start = row_ptr[n], end = row_ptr[n + 1];
  for (int j = start + lane; j < end; j += 64) src_of[j] = n;
}

// ---------------- fused aggregation + view attention + ELU ----------------
__global__ __launch_bounds__(256) void aggregate_kernel(
    const unsigned short* __restrict__ ft, const float* __restrict__ ftx,
    const float* __restrict__ fty, const float* __restrict__ sim,
    const int* __restrict__ row_ptr, const int* __restrict__ csr_dst,
    const float* __restrict__ csr_w, const float* __restrict__ w_view,
    const float* __restrict__ bias, float* __restrict__ out, int N, int E, int H) {
  int h = blockIdx.y;
  int n = blockIdx.x * 4 + (threadIdx.x >> 6);
  int lane = threadIdx.x & 63;
  if (n >= N) return;
  int start = row_ptr[n], end = row_ptr[n + 1];
  int deg = end - start;
  const unsigned short* fth = ft + (size_t)h * N * 128;
  const float* fyh = fty + (size_t)h * N;
  const float* simh = sim + (size_t)h * E;
  float ftx_i = ftx[(size_t)h * N + n];

  float mx_a = -INFINITY, mx_s = -INFINITY, mx_n = -INFINITY;
  float s_a = 0.f, s_s = 0.f, s_n1 = 0.f, s_n2 = 0.f, inv_s1 = 0.f;
  if (deg > 0) {
    // pass 1: segment maxima (lanes over edges)
    for (int j = start + lane; j < end; j += 64) {
      mx_a = fmaxf(mx_a, csr_w[j]);
      mx_s = fmaxf(mx_s, simh[j]);
      mx_n = fmaxf(mx_n, lrelu(ftx_i + fyh[csr_dst[j]]));
    }
    mx_a = wave_max(mx_a);
    mx_s = wave_max(mx_s);
    mx_n = wave_max(mx_n);
    // pass 2: softmax denominators
    for (int j = start + lane; j < end; j += 64) {
      s_a += expf(csr_w[j] - mx_a);
      s_s += expf(simh[j] - mx_s);
      s_n1 += expf(lrelu(ftx_i + fyh[csr_dst[j]]) - mx_n);
    }
    s_a = wave_sum(s_a);
    s_s = wave_sum(s_s);
    s_n1 = wave_sum(s_n1);
    inv_s1 = 1.f / s_n1;
    // pass 3: second softmax of nn channel. max(nn_vals) = 1/s_n1 analytically.
    for (int j = start + lane; j < end; j += 64) {
      float e1 = expf(lrelu(ftx_i + fyh[csr_dst[j]]) - mx_n);
      s_n2 += expf((e1 - 1.f) * inv_s1);
    }
    s_n2 = wave_sum(s_n2);
  }
  float r_a = deg > 0 ? 1.f / s_a : 0.f;
  float r_s = deg > 0 ? 1.f / s_s : 0.f;
  float r_n = deg > 0 ? 1.f / s_n2 : 0.f;

  // pass 4: weighted aggregation, lanes over D (2 dims each), edges sequential
  float2 aa = {0.f, 0.f}, av = {0.f, 0.f}, an = {0.f, 0.f};
  for (int j = start; j < end; ++j) {
    int d = csr_dst[j];
    float pa = expf(csr_w[j] - mx_a) * r_a;
    float ps = expf(simh[j] - mx_s) * r_s;
    float e1 = expf(lrelu(ftx_i + fyh[d]) - mx_n);
    float pn = expf((e1 - 1.f) * inv_s1) * r_n;
    float2 f = bfp2f(*(const unsigned int*)&fth[(size_t)d * 128 + lane * 2]);
    aa.x = fmaf(pa, f.x, aa.x);
    aa.y = fmaf(pa, f.y, aa.y);
    av.x = fmaf(ps, f.x, av.x);
    av.y = fmaf(ps, f.y, av.y);
    an.x = fmaf(pn, f.x, an.x);
    an.y = fmaf(pn, f.y, an.y);
  }

  // epilogue: view attention
  float2 fi = bfp2f(*(const unsigned int*)&fth[(size_t)n * 128 + lane * 2]);
  float2 wa = *(const float2*)&w_view[(size_t)h * 256 + lane * 2];
  float2 wb = *(const float2*)&w_view[(size_t)h * 256 + 128 + lane * 2];
  float d0 = wave_sum(fi.x * wa.x + fi.y * wa.y);
  float b0 = wave_sum(fi.x * wb.x + fi.y * wb.y);
  float b1 = wave_sum(aa.x * wb.x + aa.y * wb.y);
  float b2 = wave_sum(av.x * wb.x + av.y * wb.y);
  float b3 = wave_sum(an.x * wb.x + an.y * wb.y);
  float z0 = expf(lrelu(d0 + b0));
  float z1 = expf(lrelu(d0 + b1));
  float z2 = expf(lrelu(d0 + b2));
  float z3 = expf(lrelu(d0 + b3));
  float zm = fmaxf(fmaxf(z0, z1), fmaxf(z2, z3));
  float c0 = expf(z0 - zm), c1 = expf(z1 - zm), c2 = expf(z2 - zm), c3 = expf(z3 - zm);
  float rcs = 1.f / (c0 + c1 + c2 + c3);
  c0 *= rcs;
  c1 *= rcs;
  c2 *= rcs;
  c3 *= rcs;
  float2 bb = *(const float2*)&bias[(size_t)h * 128 + lane * 2];
  float ox = c0 * fi.x + c1 * aa.x + c2 * av.x + c3 * an.x + bb.x;
  float oy = c0 * fi.y + c1 * aa.y + c2 * av.y + c3 * an.y + bb.y;
  ox = ox > 0.f ? ox : expm1f(ox);
  oy = oy > 0.f ? oy : expm1f(oy);
  *(float2*)&out[(size_t)n * (H * 128) + (size_t)h * 128 + lane * 2] = make_float2(ox, oy);
}

extern "C" void kernel_launch(void* const* d_in, const int* in_sizes, int n_in,
                              void* d_out, int out_size, void* d_ws, size_t ws_size,
                              hipStream_t stream) {
  const float* features = (const float*)d_in[0];
  const int* adj = (const int*)d_in[1];
  const float* adj_val = (const float*)d_in[2];
  const float* W_trans = (const float*)d_in[3];
  const float* w_ftx = (const float*)d_in[4];
  const float* w_fty = (const float*)d_in[5];
  const float* w_view = (const float*)d_in[6];
  const float* bias = (const float*)d_in[7];
  float* out = (float*)d_out;

  const int IN_DIM = 256, D = 128;
  const int N = in_sizes[0] / IN_DIM;
  const int E = in_sizes[2];
  const int H = in_sizes[7] / D;

  char* p = (char*)d_ws;
  auto alloc = [&](size_t bytes) {
    char* r = p;
    p += (bytes + 255) & ~(size_t)255;
    return r;
  };
  // total ~76 MB (ft in bf16) — must stay well within ws_size
  unsigned short* ft = (unsigned short*)alloc((size_t)H * N * D * 2);  // 51.2 MB
  float* rnorm = (float*)alloc((size_t)H * N * 4);
  float* ftx = (float*)alloc((size_t)H * N * 4);
  float* fty = (float*)alloc((size_t)H * N * 4);
  float* sim = (float*)alloc((size_t)H * E * 4);  // 12.8 MB
  int* row_ptr = (int*)alloc((size_t)(N + 1) * 4);
  int* deg = (int*)alloc((size_t)N * 4);
  int* cursor = (int*)alloc((size_t)N * 4);
  int* csr_dst = (int*)alloc((size_t)E * 4);
  float* csr_w = (float*)alloc((size_t)E * 4);
  int* src_of = (int*)alloc((size_t)E * 4);
  (void)ws_size;
  (void)n_in;
  (void)out_size;

  // CSR build
  zero2_kernel<<<256, 256, 0, stream>>>(deg, cursor, N);
  hist_kernel<<<1024, 256, 0, stream>>>(adj, deg, E);
  scan_kernel<<<1, 1024, 0, stream>>>(deg, row_ptr, N);
  scatter_kernel<<<1024, 256, 0, stream>>>(adj, adj_val, row_ptr, cursor, csr_dst, csr_w, E);
  srcfill_kernel<<<(N + 3) / 4, 256, 0, stream>>>(row_ptr, src_of, N);

  // ft = features @ W_trans (all heads), bf16 out
  dim3 ggrid((N + 63) / 64, (H * D) / 64);
  gemm_kernel<<<ggrid, 256, 0, stream>>>(features, W_trans, ft, N);

  // per-node scalars
  int waves = N * H;
  node_prep<<<(waves + 3) / 4, 256, 0, stream>>>(ft, w_ftx, w_fty, rnorm, ftx, fty, N, H);

  // per-edge similarity
  dim3 sgrid((E + 3) / 4, H);
  sim_kernel<<<sgrid, 256, 0, stream>>>(ft, rnorm, row_ptr, csr_dst, sim, E, N, src_of);

  // fused aggregation + view attention
  dim3 agrid((N + 3) / 4, H);
  aggregate_kernel<<<agrid, 256, 0, stream>>>(ft, ftx, fty, sim, row_ptr, csr_dst, csr_w,
                                              w_view, bias, out, N, E, H);
}

// Round 3
// 860.325 us; speedup vs baseline: 1.7253x; 1.7253x over previous
//
#include <hip/hip_runtime.h>
#include <math.h>

#define LALPHA 0.2f

using bf16x8 = __attribute__((ext_vector_type(8))) short;
using f32x4 = __attribute__((ext_vector_type(4))) float;

__device__ __forceinline__ float wave_sum(float v) {
#pragma unroll
  for (int off = 32; off > 0; off >>= 1) v += __shfl_xor(v, off);
  return v;
}
__device__ __forceinline__ float wave_max(float v) {
#pragma unroll
  for (int off = 32; off > 0; off >>= 1) v = fmaxf(v, __shfl_xor(v, off));
  return v;
}
__device__ __forceinline__ float lrelu(float x) { return x >= 0.f ? x : LALPHA * x; }

// bf16 pair <-> float2 helpers (bf16 = high 16 bits of f32)
__device__ __forceinline__ float2 bfp2f(unsigned int u) {
  float lo = __uint_as_float(u << 16);
  float hi = __uint_as_float(u & 0xffff0000u);
  return make_float2(lo, hi);
}
__device__ __forceinline__ unsigned short f2bf(float x) {
  unsigned int b = __float_as_uint(x);
  return (unsigned short)((b + 0x7fffu + ((b >> 16) & 1u)) >> 16);  // RNE
}

// ---------------- CSR build ----------------
__global__ void zero2_kernel(int* a, int* b, int n) {
  for (int i = blockIdx.x * blockDim.x + threadIdx.x; i < n; i += gridDim.x * blockDim.x) {
    a[i] = 0;
    b[i] = 0;
  }
}

__global__ void hist_kernel(const int* __restrict__ adj, int* __restrict__ deg, int E) {
  for (int e = blockIdx.x * blockDim.x + threadIdx.x; e < E; e += gridDim.x * blockDim.x)
    atomicAdd(&deg[adj[2 * e]], 1);
}

__global__ void scan_kernel(const int* __restrict__ deg, int* __restrict__ row_ptr, int n) {
  __shared__ int sm[1024];
  int tid = threadIdx.x;
  int carry = 0;
  for (int base = 0; base < n; base += 1024) {
    int idx = base + tid;
    int v = (idx < n) ? deg[idx] : 0;
    sm[tid] = v;
    __syncthreads();
    for (int off = 1; off < 1024; off <<= 1) {
      int t = (tid >= off) ? sm[tid - off] : 0;
      __syncthreads();
      sm[tid] += t;
      __syncthreads();
    }
    if (idx < n) row_ptr[idx] = carry + sm[tid] - v;
    carry += sm[1023];
    __syncthreads();
  }
  if (tid == 0) row_ptr[n] = carry;
}

__global__ void scatter_kernel(const int* __restrict__ adj, const float* __restrict__ av,
                               const int* __restrict__ row_ptr, int* __restrict__ cursor,
                               int* __restrict__ csr_dst, float* __restrict__ csr_w, int E) {
  for (int e = blockIdx.x * blockDim.x + threadIdx.x; e < E; e += gridDim.x * blockDim.x) {
    int s = adj[2 * e], d = adj[2 * e + 1];
    int pos = row_ptr[s] + atomicAdd(&cursor[s], 1);
    csr_dst[pos] = d;
    csr_w[pos] = av[e];
  }
}

// fill src_of[j] = owning node of CSR slot j (wave per node)
__global__ void srcfill_kernel(const int* __restrict__ row_ptr, int* __restrict__ src_of,
                               int N) {
  int n = blockIdx.x * 4 + (threadIdx.x >> 6);
  int lane = threadIdx.x & 63;
  if (n >= N) return;
  int start = row_ptr[n], end = row_ptr[n + 1];
  for (int j = start + lane; j < end; j += 64) src_of[j] = n;
}

// ---------------- ft = features @ W_trans (all heads), bf16 output ----------------
__global__ __launch_bounds__(256) void gemm_kernel(const float* __restrict__ A,
                                                   const float* __restrict__ W,
                                                   unsigned short* __restrict__ ft, int N) {
  const int K = 256, D = 128;
  __shared__ float As[16][64];
  __shared__ float Bs[16][64];
  int n0 = blockIdx.x * 64;
  int c0 = blockIdx.y * 64;
  int h = c0 >> 7;
  int db = c0 & 127;
  int tid = threadIdx.x;
  int tx = tid & 15, ty = tid >> 4;
  int la_n = tid >> 2, la_k = (tid & 3) * 4;
  int lb_k = tid >> 4, lb_c = (tid & 15) * 4;
  float acc[4][4] = {};
  for (int k0 = 0; k0 < K; k0 += 16) {
    int n = n0 + la_n;
    float4 av = make_float4(0.f, 0.f, 0.f, 0.f);
    if (n < N) av = *(const float4*)&A[(size_t)n * K + k0 + la_k];
    As[la_k + 0][la_n] = av.x;
    As[la_k + 1][la_n] = av.y;
    As[la_k + 2][la_n] = av.z;
    As[la_k + 3][la_n] = av.w;
    float4 bv = *(const float4*)&W[(size_t)h * K * D + (size_t)(k0 + lb_k) * D + db + lb_c];
    Bs[lb_k][lb_c + 0] = bv.x;
    Bs[lb_k][lb_c + 1] = bv.y;
    Bs[lb_k][lb_c + 2] = bv.z;
    Bs[lb_k][lb_c + 3] = bv.w;
    __syncthreads();
#pragma unroll
    for (int kk = 0; kk < 16; ++kk) {
      float4 a = *(const float4*)&As[kk][ty * 4];
      float4 b = *(const float4*)&Bs[kk][tx * 4];
      float ar[4] = {a.x, a.y, a.z, a.w};
      float br[4] = {b.x, b.y, b.z, b.w};
#pragma unroll
      for (int r = 0; r < 4; ++r)
#pragma unroll
        for (int c = 0; c < 4; ++c) acc[r][c] = fmaf(ar[r], br[c], acc[r][c]);
    }
    __syncthreads();
  }
#pragma unroll
  for (int r = 0; r < 4; ++r) {
    int n = n0 + ty * 4 + r;
    if (n < N) {
      ushort4 o;
      o.x = f2bf(acc[r][0]);
      o.y = f2bf(acc[r][1]);
      o.z = f2bf(acc[r][2]);
      o.w = f2bf(acc[r][3]);
      *(ushort4*)&ft[((size_t)h * N + n) * D + db + tx * 4] = o;
    }
  }
}

// ---------------- per-node prep: rnorm, ftx, fty ----------------
__global__ __launch_bounds__(256) void node_prep(const unsigned short* __restrict__ ft,
                                                 const float* __restrict__ w_ftx,
                                                 const float* __restrict__ w_fty,
                                                 float* __restrict__ rnorm,
                                                 float* __restrict__ ftx,
                                                 float* __restrict__ fty, int N, int H) {
  int wid = blockIdx.x * 4 + (threadIdx.x >> 6);  // wid = h*N + n
  int lane = threadIdx.x & 63;
  if (wid >= N * H) return;
  int h = wid / N;
  float2 f = bfp2f(*(const unsigned int*)&ft[(size_t)wid * 128 + lane * 2]);
  float2 wx = *(const float2*)&w_ftx[(size_t)h * 128 + lane * 2];
  float2 wy = *(const float2*)&w_fty[(size_t)h * 128 + lane * 2];
  float ss = wave_sum(f.x * f.x + f.y * f.y);
  float sx = wave_sum(f.x * wx.x + f.y * wx.y);
  float sy = wave_sum(f.x * wy.x + f.y * wy.y);
  if (lane == 0) {
    rnorm[wid] = rsqrtf(fmaxf(ss, 1e-12f));
    ftx[wid] = sx;
    fty[wid] = sy;
  }
}

// ---------------- per-edge cosine similarity via MFMA diagonal ----------------
// 16 edges per wave. A-frag rows = src rows, B-frag cols = dst rows.
// C[e][e] = dot(src_e, dst_e). C/D layout (m89-verified): col=lane&15, row=(lane>>4)*4+reg.
__global__ __launch_bounds__(256) void sim_kernel(const unsigned short* __restrict__ ft,
                                                  const float* __restrict__ rnorm,
                                                  const int* __restrict__ src_of,
                                                  const int* __restrict__ csr_dst,
                                                  float* __restrict__ sim, int E, int N) {
  int h = blockIdx.y;
  int wid = blockIdx.x * 4 + (threadIdx.x >> 6);
  int lane = threadIdx.x & 63;
  long base = (long)wid * 16;
  if (base >= E) return;
  int e = (int)base + (lane & 15);
  bool ok = e < E;
  int ec = ok ? e : (int)base;
  int s = src_of[ec], d = csr_dst[ec];
  int g = lane >> 4;
  const unsigned short* fs = ft + ((size_t)h * N + s) * 128 + g * 8;
  const unsigned short* fd = ft + ((size_t)h * N + d) * 128 + g * 8;
  f32x4 acc = {0.f, 0.f, 0.f, 0.f};
#pragma unroll
  for (int t = 0; t < 4; ++t) {
    bf16x8 a = *(const bf16x8*)(fs + t * 32);
    bf16x8 b = *(const bf16x8*)(fd + t * 32);
    acc = __builtin_amdgcn_mfma_f32_16x16x32_bf16(a, b, acc, 0, 0, 0);
  }
  if ((((lane & 15) >> 2) == g) && ok) {
    float v = acc[lane & 3];
    sim[(size_t)h * E + e] = v * rnorm[(size_t)h * N + s] * rnorm[(size_t)h * N + d];
  }
}

// ---------------- fused aggregation + view attention + ELU ----------------
#define VCACHE 4
__global__ __launch_bounds__(256) void aggregate_kernel(
    const unsigned short* __restrict__ ft, const float* __restrict__ ftx,
    const float* __restrict__ fty, const float* __restrict__ sim,
    const int* __restrict__ row_ptr, const int* __restrict__ csr_dst,
    const float* __restrict__ csr_w, const float* __restrict__ w_view,
    const float* __restrict__ bias, float* __restrict__ out, int N, int E, int H) {
  int h = blockIdx.y;
  int n = blockIdx.x * 4 + (threadIdx.x >> 6);
  int lane = threadIdx.x & 63;
  if (n >= N) return;
  int start = row_ptr[n], end = row_ptr[n + 1];
  int deg = end - start;
  const unsigned short* fth = ft + (size_t)h * N * 128;
  const float* fyh = fty + (size_t)h * N;
  const float* simh = sim + (size_t)h * E;
  float ftx_i = ftx[(size_t)h * N + n];

  float mx_a = -INFINITY, mx_s = -INFINITY, mx_n = -INFINITY;
  float s_a = 0.f, s_s = 0.f, s_n1 = 0.f, s_n2 = 0.f, inv_s1 = 0.f;
  float vc[VCACHE];
  int nchunk = (deg + 63) >> 6;
  if (deg > 0) {
    // pass 1: maxima; cache v = lrelu(ftx_i + fty[dst]) (the expensive gather)
    for (int c = 0; c < nchunk; ++c) {
      int j = start + c * 64 + lane;
      bool in = j < end;
      float w = in ? csr_w[j] : -INFINITY;
      float si = in ? simh[j] : -INFINITY;
      float v = in ? lrelu(ftx_i + fyh[csr_dst[j]]) : -INFINITY;
      if (c < VCACHE) vc[c] = v;
      mx_a = fmaxf(mx_a, w);
      mx_s = fmaxf(mx_s, si);
      mx_n = fmaxf(mx_n, v);
    }
    mx_a = wave_max(mx_a);
    mx_s = wave_max(mx_s);
    mx_n = wave_max(mx_n);
    // pass 2: denominators; convert cache v -> e1
    for (int c = 0; c < nchunk; ++c) {
      int j = start + c * 64 + lane;
      bool in = j < end;
      float w = in ? csr_w[j] : -INFINITY;
      float si = in ? simh[j] : -INFINITY;
      float v;
      if (c < VCACHE)
        v = vc[c];
      else
        v = in ? lrelu(ftx_i + fyh[csr_dst[j]]) : -INFINITY;
      float e1 = expf(v - mx_n);  // 0 for !in
      if (c < VCACHE) vc[c] = e1;
      s_a += expf(w - mx_a);
      s_s += expf(si - mx_s);
      s_n1 += e1;
    }
    s_a = wave_sum(s_a);
    s_s = wave_sum(s_s);
    s_n1 = wave_sum(s_n1);
    inv_s1 = 1.f / s_n1;
    // pass 3: second softmax denom of nn channel (max = 1/s_n1 analytically)
    for (int c = 0; c < nchunk; ++c) {
      int j = start + c * 64 + lane;
      bool in = j < end;
      float e1;
      if (c < VCACHE)
        e1 = vc[c];
      else
        e1 = in ? expf(lrelu(ftx_i + fyh[csr_dst[j]]) - mx_n) : 0.f;
      s_n2 += in ? expf((e1 - 1.f) * inv_s1) : 0.f;
    }
    s_n2 = wave_sum(s_n2);
  }
  float r_a = deg > 0 ? 1.f / s_a : 0.f;
  float r_s = deg > 0 ? 1.f / s_s : 0.f;
  float r_n = deg > 0 ? 1.f / s_n2 : 0.f;

  // pass 4: phase A (lanes over edges) computes weights once; phase B broadcasts
  // via shuffles and accumulates rows with lanes over D.
  float2 aa = {0.f, 0.f}, av = {0.f, 0.f}, an = {0.f, 0.f};
  for (int c = 0; c < nchunk; ++c) {
    int j = start + c * 64 + lane;
    bool in = j < end;
    float w = in ? csr_w[j] : 0.f;
    float si = in ? simh[j] : 0.f;
    float e1;
    if (c < VCACHE)
      e1 = vc[c];
    else
      e1 = in ? expf(lrelu(ftx_i + fyh[csr_dst[j]]) - mx_n) : 0.f;
    float pa_l = expf(w - mx_a) * r_a;
    float ps_l = expf(si - mx_s) * r_s;
    float pn_l = expf((e1 - 1.f) * inv_s1) * r_n;
    int d_l = in ? csr_dst[j] : 0;
    int len = end - (start + c * 64);
    if (len > 64) len = 64;
    for (int jj = 0; jj < len; ++jj) {
      float pa = __shfl(pa_l, jj);
      float ps = __shfl(ps_l, jj);
      float pn = __shfl(pn_l, jj);
      int d = __shfl(d_l, jj);
      float2 f = bfp2f(*(const unsigned int*)&fth[(size_t)d * 128 + lane * 2]);
      aa.x = fmaf(pa, f.x, aa.x);
      aa.y = fmaf(pa, f.y, aa.y);
      av.x = fmaf(ps, f.x, av.x);
      av.y = fmaf(ps, f.y, av.y);
      an.x = fmaf(pn, f.x, an.x);
      an.y = fmaf(pn, f.y, an.y);
    }
  }

  // epilogue: view attention
  float2 fi = bfp2f(*(const unsigned int*)&fth[(size_t)n * 128 + lane * 2]);
  float2 wa = *(const float2*)&w_view[(size_t)h * 256 + lane * 2];
  float2 wb = *(const float2*)&w_view[(size_t)h * 256 + 128 + lane * 2];
  float d0 = wave_sum(fi.x * wa.x + fi.y * wa.y);
  float b0 = wave_sum(fi.x * wb.x + fi.y * wb.y);
  float b1 = wave_sum(aa.x * wb.x + aa.y * wb.y);
  float b2 = wave_sum(av.x * wb.x + av.y * wb.y);
  float b3 = wave_sum(an.x * wb.x + an.y * wb.y);
  float z0 = expf(lrelu(d0 + b0));
  float z1 = expf(lrelu(d0 + b1));
  float z2 = expf(lrelu(d0 + b2));
  float z3 = expf(lrelu(d0 + b3));
  float zm = fmaxf(fmaxf(z0, z1), fmaxf(z2, z3));
  float c0 = expf(z0 - zm), c1 = expf(z1 - zm), c2 = expf(z2 - zm), c3 = expf(z3 - zm);
  float rcs = 1.f / (c0 + c1 + c2 + c3);
  c0 *= rcs;
  c1 *= rcs;
  c2 *= rcs;
  c3 *= rcs;
  float2 bb = *(const float2*)&bias[(size_t)h * 128 + lane * 2];
  float ox = c0 * fi.x + c1 * aa.x + c2 * av.x + c3 * an.x + bb.x;
  float oy = c0 * fi.y + c1 * aa.y + c2 * av.y + c3 * an.y + bb.y;
  ox = ox > 0.f ? ox : expm1f(ox);
  oy = oy > 0.f ? oy : expm1f(oy);
  *(float2*)&out[(size_t)n * (H * 128) + (size_t)h * 128 + lane * 2] = make_float2(ox, oy);
}

extern "C" void kernel_launch(void* const* d_in, const int* in_sizes, int n_in,
                              void* d_out, int out_size, void* d_ws, size_t ws_size,
                              hipStream_t stream) {
  const float* features = (const float*)d_in[0];
  const int* adj = (const int*)d_in[1];
  const float* adj_val = (const float*)d_in[2];
  const float* W_trans = (const float*)d_in[3];
  const float* w_ftx = (const float*)d_in[4];
  const float* w_fty = (const float*)d_in[5];
  const float* w_view = (const float*)d_in[6];
  const float* bias = (const float*)d_in[7];
  float* out = (float*)d_out;

  const int IN_DIM = 256, D = 128;
  const int N = in_sizes[0] / IN_DIM;
  const int E = in_sizes[2];
  const int H = in_sizes[7] / D;

  char* p = (char*)d_ws;
  auto alloc = [&](size_t bytes) {
    char* r = p;
    p += (bytes + 255) & ~(size_t)255;
    return r;
  };
  // total ~76 MB
  unsigned short* ft = (unsigned short*)alloc((size_t)H * N * D * 2);  // 51.2 MB
  float* rnorm = (float*)alloc((size_t)H * N * 4);
  float* ftx = (float*)alloc((size_t)H * N * 4);
  float* fty = (float*)alloc((size_t)H * N * 4);
  float* sim = (float*)alloc((size_t)H * E * 4);  // 12.8 MB
  int* row_ptr = (int*)alloc((size_t)(N + 1) * 4);
  int* deg = (int*)alloc((size_t)N * 4);
  int* cursor = (int*)alloc((size_t)N * 4);
  int* csr_dst = (int*)alloc((size_t)E * 4);
  float* csr_w = (float*)alloc((size_t)E * 4);
  int* src_of = (int*)alloc((size_t)E * 4);
  (void)ws_size;
  (void)n_in;
  (void)out_size;

  // CSR build
  zero2_kernel<<<256, 256, 0, stream>>>(deg, cursor, N);
  hist_kernel<<<1024, 256, 0, stream>>>(adj, deg, E);
  scan_kernel<<<1, 1024, 0, stream>>>(deg, row_ptr, N);
  scatter_kernel<<<1024, 256, 0, stream>>>(adj, adj_val, row_ptr, cursor, csr_dst, csr_w, E);
  srcfill_kernel<<<(N + 3) / 4, 256, 0, stream>>>(row_ptr, src_of, N);

  // ft = features @ W_trans (all heads), bf16 out
  dim3 ggrid((N + 63) / 64, (H * D) / 64);
  gemm_kernel<<<ggrid, 256, 0, stream>>>(features, W_trans, ft, N);

  // per-node scalars
  int waves = N * H;
  node_prep<<<(waves + 3) / 4, 256, 0, stream>>>(ft, w_ftx, w_fty, rnorm, ftx, fty, N, H);

  // per-edge similarity (MFMA diagonal, 16 edges/wave)
  dim3 sgrid((E + 63) / 64, H);
  sim_kernel<<<sgrid, 256, 0, stream>>>(ft, rnorm, src_of, csr_dst, sim, E, N);

  // fused aggregation + view attention
  dim3 agrid((N + 3) / 4, H);
  aggregate_kernel<<<agrid, 256, 0, stream>>>(ft, ftx, fty, sim, row_ptr, csr_dst, csr_w,
                                              w_view, bias, out, N, E, H);
}

// Round 4
// 665.622 us; speedup vs baseline: 2.2299x; 1.2925x over previous
//
#include <hip/hip_runtime.h>
#include <math.h>

#define LALPHA 0.2f

using bf16x8 = __attribute__((ext_vector_type(8))) short;
using f32x4 = __attribute__((ext_vector_type(4))) float;

__device__ __forceinline__ float wave_sum(float v) {
#pragma unroll
  for (int off = 32; off > 0; off >>= 1) v += __shfl_xor(v, off);
  return v;
}
__device__ __forceinline__ float wave_max(float v) {
#pragma unroll
  for (int off = 32; off > 0; off >>= 1) v = fmaxf(v, __shfl_xor(v, off));
  return v;
}
__device__ __forceinline__ float lrelu(float x) { return x >= 0.f ? x : LALPHA * x; }

// bf16 pair <-> float2 helpers (bf16 = high 16 bits of f32)
__device__ __forceinline__ float2 bfp2f(unsigned int u) {
  float lo = __uint_as_float(u << 16);
  float hi = __uint_as_float(u & 0xffff0000u);
  return make_float2(lo, hi);
}
__device__ __forceinline__ unsigned short f2bf(float x) {
  unsigned int b = __float_as_uint(x);
  return (unsigned short)((b + 0x7fffu + ((b >> 16) & 1u)) >> 16);  // RNE
}
// packed 2xf32 -> 2xbf16 (RNE) in one instruction
__device__ __forceinline__ unsigned int cvtpk(float lo, float hi) {
  unsigned int r;
  asm("v_cvt_pk_bf16_f32 %0, %1, %2" : "=v"(r) : "v"(lo), "v"(hi));
  return r;
}

// ---------------- CSR build ----------------
__global__ void zero2_kernel(int* a, int* b, int n) {
  for (int i = blockIdx.x * blockDim.x + threadIdx.x; i < n; i += gridDim.x * blockDim.x) {
    a[i] = 0;
    b[i] = 0;
  }
}

__global__ void hist_kernel(const int* __restrict__ adj, int* __restrict__ deg, int E) {
  for (int e = blockIdx.x * blockDim.x + threadIdx.x; e < E; e += gridDim.x * blockDim.x)
    atomicAdd(&deg[adj[2 * e]], 1);
}

// hierarchical scan: per-tile exclusive scan + tile totals
__global__ __launch_bounds__(1024) void scan_a(const int* __restrict__ deg,
                                               int* __restrict__ row_ptr,
                                               int* __restrict__ tilesum, int n) {
  __shared__ int sm[1024];
  int tid = threadIdx.x;
  int idx = blockIdx.x * 1024 + tid;
  int v = (idx < n) ? deg[idx] : 0;
  sm[tid] = v;
  __syncthreads();
  for (int off = 1; off < 1024; off <<= 1) {
    int t = (tid >= off) ? sm[tid - off] : 0;
    __syncthreads();
    sm[tid] += t;
    __syncthreads();
  }
  if (idx < n) row_ptr[idx] = sm[tid] - v;  // tile-local exclusive
  if (tid == 1023) tilesum[blockIdx.x] = sm[1023];
}

__global__ __launch_bounds__(1024) void scan_b(int* __restrict__ tilesum, int ntiles) {
  __shared__ int sm[1024];
  int tid = threadIdx.x;
  int v = (tid < ntiles) ? tilesum[tid] : 0;
  sm[tid] = v;
  __syncthreads();
  for (int off = 1; off < 1024; off <<= 1) {
    int t = (tid >= off) ? sm[tid - off] : 0;
    __syncthreads();
    sm[tid] += t;
    __syncthreads();
  }
  if (tid < ntiles) tilesum[tid] = sm[tid] - v;  // exclusive tile offsets
  if (tid == ntiles - 1) tilesum[ntiles] = sm[tid];  // grand total
}

__global__ __launch_bounds__(1024) void scan_c(int* __restrict__ row_ptr,
                                               const int* __restrict__ tilesum, int n,
                                               int ntiles) {
  int idx = blockIdx.x * 1024 + threadIdx.x;
  if (idx < n) row_ptr[idx] += tilesum[blockIdx.x];
  if (idx == 0) row_ptr[n] = tilesum[ntiles];
}

__global__ void scatter_kernel(const int* __restrict__ adj, const float* __restrict__ av,
                               const int* __restrict__ row_ptr, int* __restrict__ cursor,
                               int* __restrict__ csr_dst, float* __restrict__ csr_w, int E) {
  for (int e = blockIdx.x * blockDim.x + threadIdx.x; e < E; e += gridDim.x * blockDim.x) {
    int s = adj[2 * e], d = adj[2 * e + 1];
    int pos = row_ptr[s] + atomicAdd(&cursor[s], 1);
    csr_dst[pos] = d;
    csr_w[pos] = av[e];
  }
}

// fill src_of[j] = owning node of CSR slot j (wave per node)
__global__ void srcfill_kernel(const int* __restrict__ row_ptr, int* __restrict__ src_of,
                               int N) {
  int n = blockIdx.x * 4 + (threadIdx.x >> 6);
  int lane = threadIdx.x & 63;
  if (n >= N) return;
  int start = row_ptr[n], end = row_ptr[n + 1];
  for (int j = start + lane; j < end; j += 64) src_of[j] = n;
}

// ---------------- W transpose: WT[h][d][k] = bf16(W[h][k][d]) ----------------
__global__ void transw_kernel(const float* __restrict__ W, unsigned short* __restrict__ WT) {
  int idx = blockIdx.x * 256 + threadIdx.x;  // H*K*D = 4*256*128 = 131072
  int d = idx & 127;
  int k = (idx >> 7) & 255;
  int h = idx >> 15;
  WT[((size_t)h * 128 + d) * 256 + k] = f2bf(W[idx]);
}

// ---------------- ft = features @ W_trans via MFMA, bf16 out ----------------
// A: N x 256 f32 (converted in-register). WT: [H][128][256] bf16. ft: (H,N,128) bf16.
// Wave computes 32 rows x 128 cols; block (4 waves) = 128 rows x 128 cols; grid (H, ceil(N/128)).
__global__ __launch_bounds__(256) void gemm_mfma(const float* __restrict__ A,
                                                 const unsigned short* __restrict__ WT,
                                                 unsigned short* __restrict__ ft, int N) {
  const int K = 256;
  int h = blockIdx.x;
  int r0 = blockIdx.y * 128 + (threadIdx.x >> 6) * 32;
  int lane = threadIdx.x & 63;
  int lr = lane & 15, lg = lane >> 4;
  int ra0 = min(r0 + lr, N - 1);
  int ra1 = min(r0 + 16 + lr, N - 1);
  const float* pa0 = A + (size_t)ra0 * K + lg * 8;
  const float* pa1 = A + (size_t)ra1 * K + lg * 8;
  const unsigned short* pb = WT + ((size_t)h * 128 + lr) * K + lg * 8;

  f32x4 acc[2][8] = {};
  for (int k0 = 0; k0 < K; k0 += 32) {
    union {
      bf16x8 v;
      unsigned int u[4];
    } a0, a1;
    float4 f0 = *(const float4*)(pa0 + k0);
    float4 f1 = *(const float4*)(pa0 + k0 + 4);
    a0.u[0] = cvtpk(f0.x, f0.y);
    a0.u[1] = cvtpk(f0.z, f0.w);
    a0.u[2] = cvtpk(f1.x, f1.y);
    a0.u[3] = cvtpk(f1.z, f1.w);
    float4 g0 = *(const float4*)(pa1 + k0);
    float4 g1 = *(const float4*)(pa1 + k0 + 4);
    a1.u[0] = cvtpk(g0.x, g0.y);
    a1.u[1] = cvtpk(g0.z, g0.w);
    a1.u[2] = cvtpk(g1.x, g1.y);
    a1.u[3] = cvtpk(g1.z, g1.w);
    bf16x8 b[8];
#pragma unroll
    for (int cb = 0; cb < 8; ++cb) b[cb] = *(const bf16x8*)(pb + (size_t)cb * 16 * K + k0);
#pragma unroll
    for (int cb = 0; cb < 8; ++cb) {
      acc[0][cb] = __builtin_amdgcn_mfma_f32_16x16x32_bf16(a0.v, b[cb], acc[0][cb], 0, 0, 0);
      acc[1][cb] = __builtin_amdgcn_mfma_f32_16x16x32_bf16(a1.v, b[cb], acc[1][cb], 0, 0, 0);
    }
  }
  // C/D layout (m89-verified): col = lane&15, row = (lane>>4)*4 + v
#pragma unroll
  for (int i = 0; i < 2; ++i) {
#pragma unroll
    for (int cb = 0; cb < 8; ++cb) {
      int nb = r0 + i * 16 + lg * 4;
      int d = cb * 16 + lr;
      unsigned short* po = ft + ((size_t)h * N + nb) * 128 + d;
      unsigned int u01 = cvtpk(acc[i][cb][0], acc[i][cb][1]);
      unsigned int u23 = cvtpk(acc[i][cb][2], acc[i][cb][3]);
      if (nb + 3 < N) {
        po[0] = (unsigned short)u01;
        po[128] = (unsigned short)(u01 >> 16);
        po[256] = (unsigned short)u23;
        po[384] = (unsigned short)(u23 >> 16);
      } else {
        if (nb < N) po[0] = (unsigned short)u01;
        if (nb + 1 < N) po[128] = (unsigned short)(u01 >> 16);
        if (nb + 2 < N) po[256] = (unsigned short)u23;
        if (nb + 3 < N) po[384] = (unsigned short)(u23 >> 16);
      }
    }
  }
}

// ---------------- per-node prep: rnorm, ftx, fty ----------------
__global__ __launch_bounds__(256) void node_prep(const unsigned short* __restrict__ ft,
                                                 const float* __restrict__ w_ftx,
                                                 const float* __restrict__ w_fty,
                                                 float* __restrict__ rnorm,
                                                 float* __restrict__ ftx,
                                                 float* __restrict__ fty, int N, int H) {
  int wid = blockIdx.x * 4 + (threadIdx.x >> 6);  // wid = h*N + n
  int lane = threadIdx.x & 63;
  if (wid >= N * H) return;
  int h = wid / N;
  float2 f = bfp2f(*(const unsigned int*)&ft[(size_t)wid * 128 + lane * 2]);
  float2 wx = *(const float2*)&w_ftx[(size_t)h * 128 + lane * 2];
  float2 wy = *(const float2*)&w_fty[(size_t)h * 128 + lane * 2];
  float ss = wave_sum(f.x * f.x + f.y * f.y);
  float sx = wave_sum(f.x * wx.x + f.y * wx.y);
  float sy = wave_sum(f.x * wy.x + f.y * wy.y);
  if (lane == 0) {
    rnorm[wid] = rsqrtf(fmaxf(ss, 1e-12f));
    ftx[wid] = sx;
    fty[wid] = sy;
  }
}

// ---------------- per-edge cosine similarity via MFMA diagonal ----------------
__global__ __launch_bounds__(256) void sim_kernel(const unsigned short* __restrict__ ft,
                                                  const float* __restrict__ rnorm,
                                                  const int* __restrict__ src_of,
                                                  const int* __restrict__ csr_dst,
                                                  float* __restrict__ sim, int E, int N) {
  int h = blockIdx.y;
  int wid = blockIdx.x * 4 + (threadIdx.x >> 6);
  int lane = threadIdx.x & 63;
  long base = (long)wid * 16;
  if (base >= E) return;
  int e = (int)base + (lane & 15);
  bool ok = e < E;
  int ec = ok ? e : (int)base;
  int s = src_of[ec], d = csr_dst[ec];
  int g = lane >> 4;
  const unsigned short* fs = ft + ((size_t)h * N + s) * 128 + g * 8;
  const unsigned short* fd = ft + ((size_t)h * N + d) * 128 + g * 8;
  f32x4 acc = {0.f, 0.f, 0.f, 0.f};
#pragma unroll
  for (int t = 0; t < 4; ++t) {
    bf16x8 a = *(const bf16x8*)(fs + t * 32);
    bf16x8 b = *(const bf16x8*)(fd + t * 32);
    acc = __builtin_amdgcn_mfma_f32_16x16x32_bf16(a, b, acc, 0, 0, 0);
  }
  if ((((lane & 15) >> 2) == g) && ok) {
    float v = acc[lane & 3];
    sim[(size_t)h * E + e] = v * rnorm[(size_t)h * N + s] * rnorm[(size_t)h * N + d];
  }
}

// ---------------- fused aggregation + view attention + ELU ----------------
#define VCACHE 4
__global__ __launch_bounds__(256) void aggregate_kernel(
    const unsigned short* __restrict__ ft, const float* __restrict__ ftx,
    const float* __restrict__ fty, const float* __restrict__ sim,
    const int* __restrict__ row_ptr, const int* __restrict__ csr_dst,
    const float* __restrict__ csr_w, const float* __restrict__ w_view,
    const float* __restrict__ bias, float* __restrict__ out, int N, int E, int H) {
  int h = blockIdx.y;
  int n = blockIdx.x * 4 + (threadIdx.x >> 6);
  int lane = threadIdx.x & 63;
  if (n >= N) return;
  int start = row_ptr[n], end = row_ptr[n + 1];
  int deg = end - start;
  const unsigned short* fth = ft + (size_t)h * N * 128;
  const float* fyh = fty + (size_t)h * N;
  const float* simh = sim + (size_t)h * E;
  float ftx_i = ftx[(size_t)h * N + n];

  float mx_a = -INFINITY, mx_s = -INFINITY, mx_n = -INFINITY;
  float s_a = 0.f, s_s = 0.f, s_n1 = 0.f, s_n2 = 0.f, inv_s1 = 0.f;
  float vc[VCACHE];
  int nchunk = (deg + 63) >> 6;
  if (deg > 0) {
    // pass 1: maxima; cache v = lrelu(ftx_i + fty[dst])
    for (int c = 0; c < nchunk; ++c) {
      int j = start + c * 64 + lane;
      bool in = j < end;
      float w = in ? csr_w[j] : -INFINITY;
      float si = in ? simh[j] : -INFINITY;
      float v = in ? lrelu(ftx_i + fyh[csr_dst[j]]) : -INFINITY;
      if (c < VCACHE) vc[c] = v;
      mx_a = fmaxf(mx_a, w);
      mx_s = fmaxf(mx_s, si);
      mx_n = fmaxf(mx_n, v);
    }
    mx_a = wave_max(mx_a);
    mx_s = wave_max(mx_s);
    mx_n = wave_max(mx_n);
    // pass 2: denominators; cache -> e1
    for (int c = 0; c < nchunk; ++c) {
      int j = start + c * 64 + lane;
      bool in = j < end;
      float w = in ? csr_w[j] : -INFINITY;
      float si = in ? simh[j] : -INFINITY;
      float v;
      if (c < VCACHE)
        v = vc[c];
      else
        v = in ? lrelu(ftx_i + fyh[csr_dst[j]]) : -INFINITY;
      float e1 = expf(v - mx_n);
      if (c < VCACHE) vc[c] = e1;
      s_a += expf(w - mx_a);
      s_s += expf(si - mx_s);
      s_n1 += e1;
    }
    s_a = wave_sum(s_a);
    s_s = wave_sum(s_s);
    s_n1 = wave_sum(s_n1);
    inv_s1 = 1.f / s_n1;
    // pass 3: second softmax denom of nn channel (max = 1/s_n1 analytically)
    for (int c = 0; c < nchunk; ++c) {
      int j = start + c * 64 + lane;
      bool in = j < end;
      float e1;
      if (c < VCACHE)
        e1 = vc[c];
      else
        e1 = in ? expf(lrelu(ftx_i + fyh[csr_dst[j]]) - mx_n) : 0.f;
      s_n2 += in ? expf((e1 - 1.f) * inv_s1) : 0.f;
    }
    s_n2 = wave_sum(s_n2);
  }
  float r_a = deg > 0 ? 1.f / s_a : 0.f;
  float r_s = deg > 0 ? 1.f / s_s : 0.f;
  float r_n = deg > 0 ? 1.f / s_n2 : 0.f;

  // pass 4: per chunk, lanes compute weights in parallel; inner loop broadcasts
  // via v_readlane (uniform index -> SGPR, no DS ops, no lgkm waits).
  float2 aa = {0.f, 0.f}, av = {0.f, 0.f}, an = {0.f, 0.f};
  for (int c = 0; c < nchunk; ++c) {
    int j0 = start + c * 64;
    int j = j0 + lane;
    bool in = j < end;
    float w = in ? csr_w[j] : 0.f;
    float si = in ? simh[j] : 0.f;
    float e1;
    if (c < VCACHE)
      e1 = vc[c];
    else
      e1 = in ? expf(lrelu(ftx_i + fyh[csr_dst[j]]) - mx_n) : 0.f;
    float pa_l = expf(w - mx_a) * r_a;
    float ps_l = expf(si - mx_s) * r_s;
    float pn_l = expf((e1 - 1.f) * inv_s1) * r_n;
    int voff_l = in ? (csr_dst[j] << 8) : 0;  // row byte offset (d * 128 * 2B)
    int len = end - j0;
    if (len > 64) len = 64;
    for (int jj = 0; jj < len; ++jj) {
      float pa = __uint_as_float(__builtin_amdgcn_readlane(__float_as_uint(pa_l), jj));
      float ps = __uint_as_float(__builtin_amdgcn_readlane(__float_as_uint(ps_l), jj));
      float pn = __uint_as_float(__builtin_amdgcn_readlane(__float_as_uint(pn_l), jj));
      int ro = __builtin_amdgcn_readlane(voff_l, jj);
      unsigned int u = *(const unsigned int*)((const char*)fth + ro + lane * 4);
      float2 f = bfp2f(u);
      aa.x = fmaf(pa, f.x, aa.x);
      aa.y = fmaf(pa, f.y, aa.y);
      av.x = fmaf(ps, f.x, av.x);
      av.y = fmaf(ps, f.y, av.y);
      an.x = fmaf(pn, f.x, an.x);
      an.y = fmaf(pn, f.y, an.y);
    }
  }

  // epilogue: view attention
  float2 fi = bfp2f(*(const unsigned int*)&fth[(size_t)n * 128 + lane * 2]);
  float2 wa = *(const float2*)&w_view[(size_t)h * 256 + lane * 2];
  float2 wb = *(const float2*)&w_view[(size_t)h * 256 + 128 + lane * 2];
  float d0 = wave_sum(fi.x * wa.x + fi.y * wa.y);
  float b0 = wave_sum(fi.x * wb.x + fi.y * wb.y);
  float b1 = wave_sum(aa.x * wb.x + aa.y * wb.y);
  float b2 = wave_sum(av.x * wb.x + av.y * wb.y);
  float b3 = wave_sum(an.x * wb.x + an.y * wb.y);
  float z0 = expf(lrelu(d0 + b0));
  float z1 = expf(lrelu(d0 + b1));
  float z2 = expf(lrelu(d0 + b2));
  float z3 = expf(lrelu(d0 + b3));
  float zm = fmaxf(fmaxf(z0, z1), fmaxf(z2, z3));
  float c0 = expf(z0 - zm), c1 = expf(z1 - zm), c2 = expf(z2 - zm), c3 = expf(z3 - zm);
  float rcs = 1.f / (c0 + c1 + c2 + c3);
  c0 *= rcs;
  c1 *= rcs;
  c2 *= rcs;
  c3 *= rcs;
  float2 bb = *(const float2*)&bias[(size_t)h * 128 + lane * 2];
  float ox = c0 * fi.x + c1 * aa.x + c2 * av.x + c3 * an.x + bb.x;
  float oy = c0 * fi.y + c1 * aa.y + c2 * av.y + c3 * an.y + bb.y;
  ox = ox > 0.f ? ox : expm1f(ox);
  oy = oy > 0.f ? oy : expm1f(oy);
  *(float2*)&out[(size_t)n * (H * 128) + (size_t)h * 128 + lane * 2] = make_float2(ox, oy);
}

extern "C" void kernel_launch(void* const* d_in, const int* in_sizes, int n_in,
                              void* d_out, int out_size, void* d_ws, size_t ws_size,
                              hipStream_t stream) {
  const float* features = (const float*)d_in[0];
  const int* adj = (const int*)d_in[1];
  const float* adj_val = (const float*)d_in[2];
  const float* W_trans = (const float*)d_in[3];
  const float* w_ftx = (const float*)d_in[4];
  const float* w_fty = (const float*)d_in[5];
  const float* w_view = (const float*)d_in[6];
  const float* bias = (const float*)d_in[7];
  float* out = (float*)d_out;

  const int IN_DIM = 256, D = 128;
  const int N = in_sizes[0] / IN_DIM;
  const int E = in_sizes[2];
  const int H = in_sizes[7] / D;

  char* p = (char*)d_ws;
  auto alloc = [&](size_t bytes) {
    char* r = p;
    p += (bytes + 255) & ~(size_t)255;
    return r;
  };
  // total ~76.6 MB (same proven footprint as round 2/3)
  unsigned short* ft = (unsigned short*)alloc((size_t)H * N * D * 2);  // 51.2 MB
  float* rnorm = (float*)alloc((size_t)H * N * 4);
  float* ftx = (float*)alloc((size_t)H * N * 4);
  float* fty = (float*)alloc((size_t)H * N * 4);
  float* sim = (float*)alloc((size_t)H * E * 4);  // 12.8 MB
  int* row_ptr = (int*)alloc((size_t)(N + 1) * 4);
  int* deg = (int*)alloc((size_t)N * 4);
  int* cursor = (int*)alloc((size_t)N * 4);
  int* csr_dst = (int*)alloc((size_t)E * 4);
  float* csr_w = (float*)alloc((size_t)E * 4);
  int* src_of = (int*)alloc((size_t)E * 4);
  (void)ws_size;
  (void)n_in;
  (void)out_size;

  // WT (512 KB) and tilesum (4 KB) live INSIDE the sim buffer: both are dead
  // before sim_kernel writes sim (WT last read by gemm; tilesum by scan_c).
  unsigned short* WT = (unsigned short*)sim;
  int* tilesum = (int*)((char*)sim + 512 * 1024);

  int ntiles = (N + 1023) / 1024;

  // CSR build
  zero2_kernel<<<256, 256, 0, stream>>>(deg, cursor, N);
  hist_kernel<<<1024, 256, 0, stream>>>(adj, deg, E);
  scan_a<<<ntiles, 1024, 0, stream>>>(deg, row_ptr, tilesum, N);
  scan_b<<<1, 1024, 0, stream>>>(tilesum, ntiles);
  scan_c<<<ntiles, 1024, 0, stream>>>(row_ptr, tilesum, N, ntiles);
  scatter_kernel<<<1024, 256, 0, stream>>>(adj, adj_val, row_ptr, cursor, csr_dst, csr_w, E);
  srcfill_kernel<<<(N + 3) / 4, 256, 0, stream>>>(row_ptr, src_of, N);

  // W transpose + MFMA GEMM (ft bf16)
  transw_kernel<<<(H * IN_DIM * D) / 256, 256, 0, stream>>>(W_trans, WT);
  dim3 ggrid(H, (N + 127) / 128);
  gemm_mfma<<<ggrid, 256, 0, stream>>>(features, WT, ft, N);

  // per-node scalars
  int waves = N * H;
  node_prep<<<(waves + 3) / 4, 256, 0, stream>>>(ft, w_ftx, w_fty, rnorm, ftx, fty, N, H);

  // per-edge similarity (MFMA diagonal, 16 edges/wave)
  dim3 sgrid((E + 63) / 64, H);
  sim_kernel<<<sgrid, 256, 0, stream>>>(ft, rnorm, src_of, csr_dst, sim, E, N);

  // fused aggregation + view attention
  dim3 agrid((N + 3) / 4, H);
  aggregate_kernel<<<agrid, 256, 0, stream>>>(ft, ftx, fty, sim, row_ptr, csr_dst, csr_w,
                                              w_view, bias, out, N, E, H);
}

// Round 6
// 632.236 us; speedup vs baseline: 2.3477x; 1.0528x over previous
//
#include <hip/hip_runtime.h>
#include <math.h>

#define LALPHA 0.2f

using bf16x8 = __attribute__((ext_vector_type(8))) short;
using f32x4 = __attribute__((ext_vector_type(4))) float;
using f32x2 = __attribute__((ext_vector_type(2))) float;

__device__ __forceinline__ float wave_sum(float v) {
#pragma unroll
  for (int off = 32; off > 0; off >>= 1) v += __shfl_xor(v, off);
  return v;
}
__device__ __forceinline__ float wave_max(float v) {
#pragma unroll
  for (int off = 32; off > 0; off >>= 1) v = fmaxf(v, __shfl_xor(v, off));
  return v;
}
__device__ __forceinline__ float lrelu(float x) { return x >= 0.f ? x : LALPHA * x; }

// bf16 pair -> f32x2 (bf16 = high 16 bits of f32)
__device__ __forceinline__ f32x2 bfp2(unsigned int u) {
  f32x2 r;
  r[0] = __uint_as_float(u << 16);
  r[1] = __uint_as_float(u & 0xffff0000u);
  return r;
}
__device__ __forceinline__ unsigned short f2bf(float x) {
  unsigned int b = __float_as_uint(x);
  return (unsigned short)((b + 0x7fffu + ((b >> 16) & 1u)) >> 16);  // RNE
}
// packed 2xf32 -> 2xbf16 (RNE) in one instruction
__device__ __forceinline__ unsigned int cvtpk(float lo, float hi) {
  unsigned int r;
  asm("v_cvt_pk_bf16_f32 %0, %1, %2" : "=v"(r) : "v"(lo), "v"(hi));
  return r;
}
// acc{a,b,c} += {pa,ps,pn} * f — plain C; clang splats the scalar and fuses.
__device__ __forceinline__ void pkfma3(float pa, float ps, float pn, f32x2 f, f32x2& a,
                                       f32x2& b, f32x2& c) {
  a += f * pa;
  b += f * ps;
  c += f * pn;
}

// ---------------- CSR build ----------------
__global__ void zero2_kernel(int* a, int* b, int n) {
  for (int i = blockIdx.x * blockDim.x + threadIdx.x; i < n; i += gridDim.x * blockDim.x) {
    a[i] = 0;
    b[i] = 0;
  }
}

__global__ void hist_kernel(const int* __restrict__ adj, int* __restrict__ deg, int E) {
  for (int e = blockIdx.x * blockDim.x + threadIdx.x; e < E; e += gridDim.x * blockDim.x)
    atomicAdd(&deg[adj[2 * e]], 1);
}

// hierarchical scan
__global__ __launch_bounds__(1024) void scan_a(const int* __restrict__ deg,
                                               int* __restrict__ row_ptr,
                                               int* __restrict__ tilesum, int n) {
  __shared__ int sm[1024];
  int tid = threadIdx.x;
  int idx = blockIdx.x * 1024 + tid;
  int v = (idx < n) ? deg[idx] : 0;
  sm[tid] = v;
  __syncthreads();
  for (int off = 1; off < 1024; off <<= 1) {
    int t = (tid >= off) ? sm[tid - off] : 0;
    __syncthreads();
    sm[tid] += t;
    __syncthreads();
  }
  if (idx < n) row_ptr[idx] = sm[tid] - v;
  if (tid == 1023) tilesum[blockIdx.x] = sm[1023];
}

__global__ __launch_bounds__(1024) void scan_b(int* __restrict__ tilesum, int ntiles) {
  __shared__ int sm[1024];
  int tid = threadIdx.x;
  int v = (tid < ntiles) ? tilesum[tid] : 0;
  sm[tid] = v;
  __syncthreads();
  for (int off = 1; off < 1024; off <<= 1) {
    int t = (tid >= off) ? sm[tid - off] : 0;
    __syncthreads();
    sm[tid] += t;
    __syncthreads();
  }
  if (tid < ntiles) tilesum[tid] = sm[tid] - v;
  if (tid == ntiles - 1) tilesum[ntiles] = sm[tid];
}

__global__ __launch_bounds__(1024) void scan_c(int* __restrict__ row_ptr,
                                               const int* __restrict__ tilesum, int n,
                                               int ntiles) {
  int idx = blockIdx.x * 1024 + threadIdx.x;
  if (idx < n) row_ptr[idx] += tilesum[blockIdx.x];
  if (idx == 0) row_ptr[n] = tilesum[ntiles];
}

__global__ void scatter_kernel(const int* __restrict__ adj, const float* __restrict__ av,
                               const int* __restrict__ row_ptr, int* __restrict__ cursor,
                               int* __restrict__ csr_dst, float* __restrict__ csr_w, int E) {
  for (int e = blockIdx.x * blockDim.x + threadIdx.x; e < E; e += gridDim.x * blockDim.x) {
    int s = adj[2 * e], d = adj[2 * e + 1];
    int pos = row_ptr[s] + atomicAdd(&cursor[s], 1);
    csr_dst[pos] = d;
    csr_w[pos] = av[e];
  }
}

__global__ void srcfill_kernel(const int* __restrict__ row_ptr, int* __restrict__ src_of,
                               int N) {
  int n = blockIdx.x * 4 + (threadIdx.x >> 6);
  int lane = threadIdx.x & 63;
  if (n >= N) return;
  int start = row_ptr[n], end = row_ptr[n + 1];
  for (int j = start + lane; j < end; j += 64) src_of[j] = n;
}

// ---------------- W transpose: WT[h][d][k] = bf16(W[h][k][d]) ----------------
__global__ void transw_kernel(const float* __restrict__ W, unsigned short* __restrict__ WT) {
  int idx = blockIdx.x * 256 + threadIdx.x;
  int d = idx & 127;
  int k = (idx >> 7) & 255;
  int h = idx >> 15;
  WT[((size_t)h * 128 + d) * 256 + k] = f2bf(W[idx]);
}

// ---------------- ft = features @ W_trans via MFMA, bf16 out ----------------
__global__ __launch_bounds__(256) void gemm_mfma(const float* __restrict__ A,
                                                 const unsigned short* __restrict__ WT,
                                                 unsigned short* __restrict__ ft, int N) {
  const int K = 256;
  int h = blockIdx.x;
  int r0 = blockIdx.y * 128 + (threadIdx.x >> 6) * 32;
  int lane = threadIdx.x & 63;
  int lr = lane & 15, lg = lane >> 4;
  int ra0 = min(r0 + lr, N - 1);
  int ra1 = min(r0 + 16 + lr, N - 1);
  const float* pa0 = A + (size_t)ra0 * K + lg * 8;
  const float* pa1 = A + (size_t)ra1 * K + lg * 8;
  const unsigned short* pb = WT + ((size_t)h * 128 + lr) * K + lg * 8;

  f32x4 acc[2][8] = {};
  for (int k0 = 0; k0 < K; k0 += 32) {
    union {
      bf16x8 v;
      unsigned int u[4];
    } a0, a1;
    float4 f0 = *(const float4*)(pa0 + k0);
    float4 f1 = *(const float4*)(pa0 + k0 + 4);
    a0.u[0] = cvtpk(f0.x, f0.y);
    a0.u[1] = cvtpk(f0.z, f0.w);
    a0.u[2] = cvtpk(f1.x, f1.y);
    a0.u[3] = cvtpk(f1.z, f1.w);
    float4 g0 = *(const float4*)(pa1 + k0);
    float4 g1 = *(const float4*)(pa1 + k0 + 4);
    a1.u[0] = cvtpk(g0.x, g0.y);
    a1.u[1] = cvtpk(g0.z, g0.w);
    a1.u[2] = cvtpk(g1.x, g1.y);
    a1.u[3] = cvtpk(g1.z, g1.w);
    bf16x8 b[8];
#pragma unroll
    for (int cb = 0; cb < 8; ++cb) b[cb] = *(const bf16x8*)(pb + (size_t)cb * 16 * K + k0);
#pragma unroll
    for (int cb = 0; cb < 8; ++cb) {
      acc[0][cb] = __builtin_amdgcn_mfma_f32_16x16x32_bf16(a0.v, b[cb], acc[0][cb], 0, 0, 0);
      acc[1][cb] = __builtin_amdgcn_mfma_f32_16x16x32_bf16(a1.v, b[cb], acc[1][cb], 0, 0, 0);
    }
  }
#pragma unroll
  for (int i = 0; i < 2; ++i) {
#pragma unroll
    for (int cb = 0; cb < 8; ++cb) {
      int nb = r0 + i * 16 + lg * 4;
      int d = cb * 16 + lr;
      unsigned short* po = ft + ((size_t)h * N + nb) * 128 + d;
      unsigned int u01 = cvtpk(acc[i][cb][0], acc[i][cb][1]);
      unsigned int u23 = cvtpk(acc[i][cb][2], acc[i][cb][3]);
      if (nb + 3 < N) {
        po[0] = (unsigned short)u01;
        po[128] = (unsigned short)(u01 >> 16);
        po[256] = (unsigned short)u23;
        po[384] = (unsigned short)(u23 >> 16);
      } else {
        if (nb < N) po[0] = (unsigned short)u01;
        if (nb + 1 < N) po[128] = (unsigned short)(u01 >> 16);
        if (nb + 2 < N) po[256] = (unsigned short)u23;
        if (nb + 3 < N) po[384] = (unsigned short)(u23 >> 16);
      }
    }
  }
}

// ---------------- per-node prep: rnorm, ftx, fty ----------------
__global__ __launch_bounds__(256) void node_prep(const unsigned short* __restrict__ ft,
                                                 const float* __restrict__ w_ftx,
                                                 const float* __restrict__ w_fty,
                                                 float* __restrict__ rnorm,
                                                 float* __restrict__ ftx,
                                                 float* __restrict__ fty, int N, int H) {
  int wid = blockIdx.x * 4 + (threadIdx.x >> 6);
  int lane = threadIdx.x & 63;
  if (wid >= N * H) return;
  int h = wid / N;
  f32x2 f = bfp2(*(const unsigned int*)&ft[(size_t)wid * 128 + lane * 2]);
  float2 wx = *(const float2*)&w_ftx[(size_t)h * 128 + lane * 2];
  float2 wy = *(const float2*)&w_fty[(size_t)h * 128 + lane * 2];
  float ss = wave_sum(f[0] * f[0] + f[1] * f[1]);
  float sx = wave_sum(f[0] * wx.x + f[1] * wx.y);
  float sy = wave_sum(f[0] * wy.x + f[1] * wy.y);
  if (lane == 0) {
    rnorm[wid] = rsqrtf(fmaxf(ss, 1e-12f));
    ftx[wid] = sx;
    fty[wid] = sy;
  }
}

// ---------------- per-edge cosine similarity via MFMA diagonal ----------------
__global__ __launch_bounds__(256) void sim_kernel(const unsigned short* __restrict__ ft,
                                                  const float* __restrict__ rnorm,
                                                  const int* __restrict__ src_of,
                                                  const int* __restrict__ csr_dst,
                                                  float* __restrict__ sim, int E, int N) {
  int h = blockIdx.y;
  int wid = blockIdx.x * 4 + (threadIdx.x >> 6);
  int lane = threadIdx.x & 63;
  long base = (long)wid * 16;
  if (base >= E) return;
  int e = (int)base + (lane & 15);
  bool ok = e < E;
  int ec = ok ? e : (int)base;
  int s = src_of[ec], d = csr_dst[ec];
  int g = lane >> 4;
  const unsigned short* fs = ft + ((size_t)h * N + s) * 128 + g * 8;
  const unsigned short* fd = ft + ((size_t)h * N + d) * 128 + g * 8;
  f32x4 acc = {0.f, 0.f, 0.f, 0.f};
#pragma unroll
  for (int t = 0; t < 4; ++t) {
    bf16x8 a = *(const bf16x8*)(fs + t * 32);
    bf16x8 b = *(const bf16x8*)(fd + t * 32);
    acc = __builtin_amdgcn_mfma_f32_16x16x32_bf16(a, b, acc, 0, 0, 0);
  }
  if ((((lane & 15) >> 2) == g) && ok) {
    float v = acc[lane & 3];
    sim[(size_t)h * E + e] = v * rnorm[(size_t)h * N + s] * rnorm[(size_t)h * N + d];
  }
}

// ---------------- fused aggregation + view attention + ELU ----------------
__global__ __launch_bounds__(256) void aggregate_kernel(
    const unsigned short* __restrict__ ft, const float* __restrict__ ftx,
    const float* __restrict__ fty, const float* __restrict__ sim,
    const int* __restrict__ row_ptr, const int* __restrict__ csr_dst,
    const float* __restrict__ csr_w, const float* __restrict__ w_view,
    const float* __restrict__ bias, float* __restrict__ out, int N, int E, int H) {
  __shared__ float4 wbuf[4][64];  // per-wave (pa, ps, pn, dword-offset) slabs
  int h = blockIdx.y;
  int wslot = threadIdx.x >> 6;
  int n = blockIdx.x * 4 + wslot;
  int lane = threadIdx.x & 63;
  if (n >= N) return;
  int start = __builtin_amdgcn_readfirstlane(row_ptr[n]);
  int end = __builtin_amdgcn_readfirstlane(row_ptr[n + 1]);
  int deg = end - start;
  const unsigned short* fth = ft + (size_t)h * N * 128;
  const unsigned int* fth32 = (const unsigned int*)fth;
  const float* fyh = fty + (size_t)h * N;
  const float* simh = sim + (size_t)h * E;
  float ftx_i = ftx[(size_t)h * N + n];

  f32x2 aa = {0.f, 0.f}, av = {0.f, 0.f}, an = {0.f, 0.f};

  if (deg > 0 && deg <= 64) {
    // ---- fast path: every per-edge value loaded exactly once ----
    int j = start + lane;
    bool in = lane < deg;
    float w = in ? csr_w[j] : -INFINITY;
    float si = in ? simh[j] : -INFINITY;
    int dstj = in ? csr_dst[j] : 0;
    float v = in ? lrelu(ftx_i + fyh[dstj]) : -INFINITY;
    float mx_a = wave_max(w);
    float mx_s = wave_max(si);
    float mx_n = wave_max(v);
    float e_a = in ? expf(w - mx_a) : 0.f;
    float e_s = in ? expf(si - mx_s) : 0.f;
    float e1 = in ? expf(v - mx_n) : 0.f;
    float s_a = wave_sum(e_a);
    float s_s = wave_sum(e_s);
    float inv_s1 = 1.f / wave_sum(e1);
    float en = in ? expf((e1 - 1.f) * inv_s1) : 0.f;
    float s_n2 = wave_sum(en);
    wbuf[wslot][lane] =
        make_float4(e_a / s_a, e_s / s_s, en / s_n2, __int_as_float(dstj << 6));
    // sequential edges, lanes over D; 1 ds_read_b128 + 1 load + FMAs per edge
#pragma unroll 2
    for (int jj = 0; jj < deg; ++jj) {
      float4 wv = wbuf[wslot][jj];
      unsigned int u = fth32[__float_as_int(wv.w) + lane];
      pkfma3(wv.x, wv.y, wv.z, bfp2(u), aa, av, an);
    }
  } else if (deg > 0) {
    // ---- generic path (deg > 64): multi-sweep recompute ----
    float mx_a = -INFINITY, mx_s = -INFINITY, mx_n = -INFINITY;
    for (int j0 = start; j0 < end; j0 += 64) {
      int j = j0 + lane;
      bool in = j < end;
      mx_a = fmaxf(mx_a, in ? csr_w[j] : -INFINITY);
      mx_s = fmaxf(mx_s, in ? simh[j] : -INFINITY);
      mx_n = fmaxf(mx_n, in ? lrelu(ftx_i + fyh[csr_dst[j]]) : -INFINITY);
    }
    mx_a = wave_max(mx_a);
    mx_s = wave_max(mx_s);
    mx_n = wave_max(mx_n);
    float s_a = 0.f, s_s = 0.f, s_n1 = 0.f;
    for (int j0 = start; j0 < end; j0 += 64) {
      int j = j0 + lane;
      bool in = j < end;
      s_a += in ? expf(csr_w[j] - mx_a) : 0.f;
      s_s += in ? expf(simh[j] - mx_s) : 0.f;
      s_n1 += in ? expf(lrelu(ftx_i + fyh[csr_dst[j]]) - mx_n) : 0.f;
    }
    s_a = wave_sum(s_a);
    s_s = wave_sum(s_s);
    float inv_s1 = 1.f / wave_sum(s_n1);
    float s_n2 = 0.f;
    for (int j0 = start; j0 < end; j0 += 64) {
      int j = j0 + lane;
      bool in = j < end;
      float e1 = in ? expf(lrelu(ftx_i + fyh[csr_dst[j]]) - mx_n) : 0.f;
      s_n2 += in ? expf((e1 - 1.f) * inv_s1) : 0.f;
    }
    s_n2 = wave_sum(s_n2);
    float r_a = 1.f / s_a, r_s = 1.f / s_s, r_n = 1.f / s_n2;
    for (int j0 = start; j0 < end; j0 += 64) {
      int j = j0 + lane;
      bool in = j < end;
      float e1 = in ? expf(lrelu(ftx_i + fyh[csr_dst[j]]) - mx_n) : 0.f;
      float pa = in ? expf(csr_w[j] - mx_a) * r_a : 0.f;
      float ps = in ? expf(simh[j] - mx_s) * r_s : 0.f;
      float pn = in ? expf((e1 - 1.f) * inv_s1) * r_n : 0.f;
      int dstj = in ? csr_dst[j] : 0;
      wbuf[wslot][lane] = make_float4(pa, ps, pn, __int_as_float(dstj << 6));
      int len = min(64, end - j0);
      for (int jj = 0; jj < len; ++jj) {
        float4 wv = wbuf[wslot][jj];
        unsigned int u = fth32[__float_as_int(wv.w) + lane];
        pkfma3(wv.x, wv.y, wv.z, bfp2(u), aa, av, an);
      }
    }
  }

  // epilogue: view attention
  f32x2 fi = bfp2(*(const unsigned int*)&fth[(size_t)n * 128 + lane * 2]);
  float2 wa = *(const float2*)&w_view[(size_t)h * 256 + lane * 2];
  float2 wb = *(const float2*)&w_view[(size_t)h * 256 + 128 + lane * 2];
  float d0 = wave_sum(fi[0] * wa.x + fi[1] * wa.y);
  float b0 = wave_sum(fi[0] * wb.x + fi[1] * wb.y);
  float b1 = wave_sum(aa[0] * wb.x + aa[1] * wb.y);
  float b2 = wave_sum(av[0] * wb.x + av[1] * wb.y);
  float b3 = wave_sum(an[0] * wb.x + an[1] * wb.y);
  float z0 = expf(lrelu(d0 + b0));
  float z1 = expf(lrelu(d0 + b1));
  float z2 = expf(lrelu(d0 + b2));
  float z3 = expf(lrelu(d0 + b3));
  float zm = fmaxf(fmaxf(z0, z1), fmaxf(z2, z3));
  float c0 = expf(z0 - zm), c1 = expf(z1 - zm), c2 = expf(z2 - zm), c3 = expf(z3 - zm);
  float rcs = 1.f / (c0 + c1 + c2 + c3);
  c0 *= rcs;
  c1 *= rcs;
  c2 *= rcs;
  c3 *= rcs;
  float2 bb = *(const float2*)&bias[(size_t)h * 128 + lane * 2];
  float ox = c0 * fi[0] + c1 * aa[0] + c2 * av[0] + c3 * an[0] + bb.x;
  float oy = c0 * fi[1] + c1 * aa[1] + c2 * av[1] + c3 * an[1] + bb.y;
  ox = ox > 0.f ? ox : expm1f(ox);
  oy = oy > 0.f ? oy : expm1f(oy);
  *(float2*)&out[(size_t)n * (H * 128) + (size_t)h * 128 + lane * 2] = make_float2(ox, oy);
}

extern "C" void kernel_launch(void* const* d_in, const int* in_sizes, int n_in,
                              void* d_out, int out_size, void* d_ws, size_t ws_size,
                              hipStream_t stream) {
  const float* features = (const float*)d_in[0];
  const int* adj = (const int*)d_in[1];
  const float* adj_val = (const float*)d_in[2];
  const float* W_trans = (const float*)d_in[3];
  const float* w_ftx = (const float*)d_in[4];
  const float* w_fty = (const float*)d_in[5];
  const float* w_view = (const float*)d_in[6];
  const float* bias = (const float*)d_in[7];
  float* out = (float*)d_out;

  const int IN_DIM = 256, D = 128;
  const int N = in_sizes[0] / IN_DIM;
  const int E = in_sizes[2];
  const int H = in_sizes[7] / D;

  char* p = (char*)d_ws;
  auto alloc = [&](size_t bytes) {
    char* r = p;
    p += (bytes + 255) & ~(size_t)255;
    return r;
  };
  // total ~76.6 MB (proven footprint)
  unsigned short* ft = (unsigned short*)alloc((size_t)H * N * D * 2);  // 51.2 MB
  float* rnorm = (float*)alloc((size_t)H * N * 4);
  float* ftx = (float*)alloc((size_t)H * N * 4);
  float* fty = (float*)alloc((size_t)H * N * 4);
  float* sim = (float*)alloc((size_t)H * E * 4);  // 12.8 MB
  int* row_ptr = (int*)alloc((size_t)(N + 1) * 4);
  int* deg = (int*)alloc((size_t)N * 4);
  int* cursor = (int*)alloc((size_t)N * 4);
  int* csr_dst = (int*)alloc((size_t)E * 4);
  float* csr_w = (float*)alloc((size_t)E * 4);
  int* src_of = (int*)alloc((size_t)E * 4);
  (void)ws_size;
  (void)n_in;
  (void)out_size;

  // WT (512 KB) and tilesum (4 KB) live INSIDE sim (dead before sim is written)
  unsigned short* WT = (unsigned short*)sim;
  int* tilesum = (int*)((char*)sim + 512 * 1024);

  int ntiles = (N + 1023) / 1024;

  // CSR build
  zero2_kernel<<<256, 256, 0, stream>>>(deg, cursor, N);
  hist_kernel<<<1024, 256, 0, stream>>>(adj, deg, E);
  scan_a<<<ntiles, 1024, 0, stream>>>(deg, row_ptr, tilesum, N);
  scan_b<<<1, 1024, 0, stream>>>(tilesum, ntiles);
  scan_c<<<ntiles, 1024, 0, stream>>>(row_ptr, tilesum, N, ntiles);
  scatter_kernel<<<1024, 256, 0, stream>>>(adj, adj_val, row_ptr, cursor, csr_dst, csr_w, E);
  srcfill_kernel<<<(N + 3) / 4, 256, 0, stream>>>(row_ptr, src_of, N);

  // W transpose + MFMA GEMM (ft bf16)
  transw_kernel<<<(H * IN_DIM * D) / 256, 256, 0, stream>>>(W_trans, WT);
  dim3 ggrid(H, (N + 127) / 128);
  gemm_mfma<<<ggrid, 256, 0, stream>>>(features, WT, ft, N);

  // per-node scalars
  int waves = N * H;
  node_prep<<<(waves + 3) / 4, 256, 0, stream>>>(ft, w_ftx, w_fty, rnorm, ftx, fty, N, H);

  // per-edge similarity (MFMA diagonal, 16 edges/wave)
  dim3 sgrid((E + 63) / 64, H);
  sim_kernel<<<sgrid, 256, 0, stream>>>(ft, rnorm, src_of, csr_dst, sim, E, N);

  // fused aggregation + view attention
  dim3 agrid((N + 3) / 4, H);
  aggregate_kernel<<<agrid, 256, 0, stream>>>(ft, ftx, fty, sim, row_ptr, csr_dst, csr_w,
                                              w_view, bias, out, N, E, H);
}

// Round 7
// 608.879 us; speedup vs baseline: 2.4377x; 1.0384x over previous
//
#include <hip/hip_runtime.h>
#include <math.h>

#define LALPHA 0.2f

using bf16x8 = __attribute__((ext_vector_type(8))) short;
using f32x4 = __attribute__((ext_vector_type(4))) float;
using f32x2 = __attribute__((ext_vector_type(2))) float;

__device__ __forceinline__ float wave_sum(float v) {
#pragma unroll
  for (int off = 32; off > 0; off >>= 1) v += __shfl_xor(v, off);
  return v;
}
__device__ __forceinline__ float wave_max(float v) {
#pragma unroll
  for (int off = 32; off > 0; off >>= 1) v = fmaxf(v, __shfl_xor(v, off));
  return v;
}
__device__ __forceinline__ float lrelu(float x) { return x >= 0.f ? x : LALPHA * x; }

// bf16 pair -> f32x2 (bf16 = high 16 bits of f32)
__device__ __forceinline__ f32x2 bfp2(unsigned int u) {
  f32x2 r;
  r[0] = __uint_as_float(u << 16);
  r[1] = __uint_as_float(u & 0xffff0000u);
  return r;
}
__device__ __forceinline__ unsigned short f2bf(float x) {
  unsigned int b = __float_as_uint(x);
  return (unsigned short)((b + 0x7fffu + ((b >> 16) & 1u)) >> 16);  // RNE
}
// packed 2xf32 -> 2xbf16 (RNE) in one instruction
__device__ __forceinline__ unsigned int cvtpk(float lo, float hi) {
  unsigned int r;
  asm("v_cvt_pk_bf16_f32 %0, %1, %2" : "=v"(r) : "v"(lo), "v"(hi));
  return r;
}
// acc{a,b,c} += {pa,ps,pn} * f — plain C; clang splats and fuses.
__device__ __forceinline__ void pkfma3(float pa, float ps, float pn, f32x2 f, f32x2& a,
                                       f32x2& b, f32x2& c) {
  a += f * pa;
  b += f * ps;
  c += f * pn;
}

// ---------------- CSR build ----------------
__global__ void zero2_kernel(int* a, int* b, int n) {
  for (int i = blockIdx.x * blockDim.x + threadIdx.x; i < n; i += gridDim.x * blockDim.x) {
    a[i] = 0;
    b[i] = 0;
  }
}

__global__ void hist_kernel(const int* __restrict__ adj, int* __restrict__ deg, int E) {
  for (int e = blockIdx.x * blockDim.x + threadIdx.x; e < E; e += gridDim.x * blockDim.x)
    atomicAdd(&deg[adj[2 * e]], 1);
}

// hierarchical scan
__global__ __launch_bounds__(1024) void scan_a(const int* __restrict__ deg,
                                               int* __restrict__ row_ptr,
                                               int* __restrict__ tilesum, int n) {
  __shared__ int sm[1024];
  int tid = threadIdx.x;
  int idx = blockIdx.x * 1024 + tid;
  int v = (idx < n) ? deg[idx] : 0;
  sm[tid] = v;
  __syncthreads();
  for (int off = 1; off < 1024; off <<= 1) {
    int t = (tid >= off) ? sm[tid - off] : 0;
    __syncthreads();
    sm[tid] += t;
    __syncthreads();
  }
  if (idx < n) row_ptr[idx] = sm[tid] - v;
  if (tid == 1023) tilesum[blockIdx.x] = sm[1023];
}

__global__ __launch_bounds__(1024) void scan_b(int* __restrict__ tilesum, int ntiles) {
  __shared__ int sm[1024];
  int tid = threadIdx.x;
  int v = (tid < ntiles) ? tilesum[tid] : 0;
  sm[tid] = v;
  __syncthreads();
  for (int off = 1; off < 1024; off <<= 1) {
    int t = (tid >= off) ? sm[tid - off] : 0;
    __syncthreads();
    sm[tid] += t;
    __syncthreads();
  }
  if (tid < ntiles) tilesum[tid] = sm[tid] - v;
  if (tid == ntiles - 1) tilesum[ntiles] = sm[tid];
}

__global__ __launch_bounds__(1024) void scan_c(int* __restrict__ row_ptr,
                                               const int* __restrict__ tilesum, int n,
                                               int ntiles) {
  int idx = blockIdx.x * 1024 + threadIdx.x;
  if (idx < n) row_ptr[idx] += tilesum[blockIdx.x];
  if (idx == 0) row_ptr[n] = tilesum[ntiles];
}

__global__ void scatter_kernel(const int* __restrict__ adj, const float* __restrict__ av,
                               const int* __restrict__ row_ptr, int* __restrict__ cursor,
                               int* __restrict__ csr_dst, float* __restrict__ csr_w, int E) {
  for (int e = blockIdx.x * blockDim.x + threadIdx.x; e < E; e += gridDim.x * blockDim.x) {
    int s = adj[2 * e], d = adj[2 * e + 1];
    int pos = row_ptr[s] + atomicAdd(&cursor[s], 1);
    csr_dst[pos] = d;
    csr_w[pos] = av[e];
  }
}

// ---------------- W transpose: WT[h][d][k] = bf16(W[h][k][d]) ----------------
__global__ void transw_kernel(const float* __restrict__ W, unsigned short* __restrict__ WT) {
  int idx = blockIdx.x * 256 + threadIdx.x;
  int d = idx & 127;
  int k = (idx >> 7) & 255;
  int h = idx >> 15;
  WT[((size_t)h * 128 + d) * 256 + k] = f2bf(W[idx]);
}

// ---------------- ft = features @ W_trans via MFMA, bf16 out ----------------
__global__ __launch_bounds__(256) void gemm_mfma(const float* __restrict__ A,
                                                 const unsigned short* __restrict__ WT,
                                                 unsigned short* __restrict__ ft, int N) {
  const int K = 256;
  int h = blockIdx.x;
  int r0 = blockIdx.y * 128 + (threadIdx.x >> 6) * 32;
  int lane = threadIdx.x & 63;
  int lr = lane & 15, lg = lane >> 4;
  int ra0 = min(r0 + lr, N - 1);
  int ra1 = min(r0 + 16 + lr, N - 1);
  const float* pa0 = A + (size_t)ra0 * K + lg * 8;
  const float* pa1 = A + (size_t)ra1 * K + lg * 8;
  const unsigned short* pb = WT + ((size_t)h * 128 + lr) * K + lg * 8;

  f32x4 acc[2][8] = {};
  for (int k0 = 0; k0 < K; k0 += 32) {
    union {
      bf16x8 v;
      unsigned int u[4];
    } a0, a1;
    float4 f0 = *(const float4*)(pa0 + k0);
    float4 f1 = *(const float4*)(pa0 + k0 + 4);
    a0.u[0] = cvtpk(f0.x, f0.y);
    a0.u[1] = cvtpk(f0.z, f0.w);
    a0.u[2] = cvtpk(f1.x, f1.y);
    a0.u[3] = cvtpk(f1.z, f1.w);
    float4 g0 = *(const float4*)(pa1 + k0);
    float4 g1 = *(const float4*)(pa1 + k0 + 4);
    a1.u[0] = cvtpk(g0.x, g0.y);
    a1.u[1] = cvtpk(g0.z, g0.w);
    a1.u[2] = cvtpk(g1.x, g1.y);
    a1.u[3] = cvtpk(g1.z, g1.w);
    bf16x8 b[8];
#pragma unroll
    for (int cb = 0; cb < 8; ++cb) b[cb] = *(const bf16x8*)(pb + (size_t)cb * 16 * K + k0);
#pragma unroll
    for (int cb = 0; cb < 8; ++cb) {
      acc[0][cb] = __builtin_amdgcn_mfma_f32_16x16x32_bf16(a0.v, b[cb], acc[0][cb], 0, 0, 0);
      acc[1][cb] = __builtin_amdgcn_mfma_f32_16x16x32_bf16(a1.v, b[cb], acc[1][cb], 0, 0, 0);
    }
  }
#pragma unroll
  for (int i = 0; i < 2; ++i) {
#pragma unroll
    for (int cb = 0; cb < 8; ++cb) {
      int nb = r0 + i * 16 + lg * 4;
      int d = cb * 16 + lr;
      unsigned short* po = ft + ((size_t)h * N + nb) * 128 + d;
      unsigned int u01 = cvtpk(acc[i][cb][0], acc[i][cb][1]);
      unsigned int u23 = cvtpk(acc[i][cb][2], acc[i][cb][3]);
      if (nb + 3 < N) {
        po[0] = (unsigned short)u01;
        po[128] = (unsigned short)(u01 >> 16);
        po[256] = (unsigned short)u23;
        po[384] = (unsigned short)(u23 >> 16);
      } else {
        if (nb < N) po[0] = (unsigned short)u01;
        if (nb + 1 < N) po[128] = (unsigned short)(u01 >> 16);
        if (nb + 2 < N) po[256] = (unsigned short)u23;
        if (nb + 3 < N) po[384] = (unsigned short)(u23 >> 16);
      }
    }
  }
}

// ---------------- per-node prep: rnorm, ftx, fty ----------------
__global__ __launch_bounds__(256) void node_prep(const unsigned short* __restrict__ ft,
                                                 const float* __restrict__ w_ftx,
                                                 const float* __restrict__ w_fty,
                                                 float* __restrict__ rnorm,
                                                 float* __restrict__ ftx,
                                                 float* __restrict__ fty, int N, int H) {
  int wid = blockIdx.x * 4 + (threadIdx.x >> 6);
  int lane = threadIdx.x & 63;
  if (wid >= N * H) return;
  int h = wid / N;
  f32x2 f = bfp2(*(const unsigned int*)&ft[(size_t)wid * 128 + lane * 2]);
  float2 wx = *(const float2*)&w_ftx[(size_t)h * 128 + lane * 2];
  float2 wy = *(const float2*)&w_fty[(size_t)h * 128 + lane * 2];
  float ss = wave_sum(f[0] * f[0] + f[1] * f[1]);
  float sx = wave_sum(f[0] * wx.x + f[1] * wx.y);
  float sy = wave_sum(f[0] * wy.x + f[1] * wy.y);
  if (lane == 0) {
    rnorm[wid] = rsqrtf(fmaxf(ss, 1e-12f));
    ftx[wid] = sx;
    fty[wid] = sy;
  }
}

// ---------------- fused sim + aggregation + view attention + ELU ----------------
// Per (node,head) wave. Sim computed in-kernel via MFMA: A rows = ft[dst_e],
// B = ft[n] broadcast to all 16 cols -> C[m][*] = dot(ft[dst_m], ft[n]) in every
// column; lanes (lane&15)==0 hold rows (lane>>4)*4+reg, redistributed via LDS.
__global__ __launch_bounds__(256) void aggregate_kernel(
    const unsigned short* __restrict__ ft, const float* __restrict__ ftx,
    const float* __restrict__ fty, const float* __restrict__ rnorm,
    const int* __restrict__ row_ptr, const int* __restrict__ csr_dst,
    const float* __restrict__ csr_w, const float* __restrict__ w_view,
    const float* __restrict__ bias, float* __restrict__ out, int N, int E, int H) {
  __shared__ float4 wbuf[4][64];  // per-wave (pa, ps, pn, dword-offset)
  __shared__ f32x4 simq[4][16];   // per-wave raw sim redistribution
  int h = blockIdx.y;
  int wslot = threadIdx.x >> 6;
  int n = blockIdx.x * 4 + wslot;
  int lane = threadIdx.x & 63;
  if (n >= N) return;
  int start = __builtin_amdgcn_readfirstlane(row_ptr[n]);
  int end = __builtin_amdgcn_readfirstlane(row_ptr[n + 1]);
  int deg = end - start;
  const unsigned short* fth = ft + (size_t)h * N * 128;
  const unsigned int* fth32 = (const unsigned int*)fth;
  const float* fyh = fty + (size_t)h * N;
  const float* rnh = rnorm + (size_t)h * N;
  float ftx_i = ftx[(size_t)h * N + n];
  float rn_n = rnh[n];

  // raw sim (un-normalized dot) for chunk edges [j0, j0+cnt), cnt<=64.
  // Returns per-lane value for edge j0+lane (garbage for lane>=cnt).
  const unsigned short* pbn = fth + (size_t)n * 128 + (lane >> 4) * 8;
  auto sim_chunk = [&](int j0, int cnt) -> float {
    int ngroups = (cnt + 15) >> 4;
    for (int g = 0; g < ngroups; ++g) {
      int e = j0 + g * 16 + (lane & 15);
      int row = csr_dst[e < end ? e : (end - 1)];
      const unsigned short* pa = fth + (size_t)row * 128 + (lane >> 4) * 8;
      f32x4 acc = {0.f, 0.f, 0.f, 0.f};
#pragma unroll
      for (int t = 0; t < 4; ++t) {
        bf16x8 a = *(const bf16x8*)(pa + t * 32);
        bf16x8 b = *(const bf16x8*)(pbn + t * 32);
        acc = __builtin_amdgcn_mfma_f32_16x16x32_bf16(a, b, acc, 0, 0, 0);
      }
      if ((lane & 15) == 0) simq[wslot][g * 4 + (lane >> 4)] = acc;
    }
    asm volatile("s_waitcnt lgkmcnt(0)" ::: "memory");
    return ((const float*)&simq[wslot][0])[lane];
  };

  f32x2 aa = {0.f, 0.f}, av = {0.f, 0.f}, an = {0.f, 0.f};

  if (deg > 0 && deg <= 64) {
    // ---- fast path ----
    float s_raw = sim_chunk(start, deg);
    int j = start + lane;
    bool in = lane < deg;
    float w = in ? csr_w[j] : -INFINITY;
    int dstj = in ? csr_dst[j] : 0;
    float si = in ? s_raw * rn_n * rnh[dstj] : -INFINITY;
    float v = in ? lrelu(ftx_i + fyh[dstj]) : -INFINITY;
    float mx_a = wave_max(w);
    float mx_s = wave_max(si);
    float mx_n = wave_max(v);
    float e_a = in ? __expf(w - mx_a) : 0.f;
    float e_s = in ? __expf(si - mx_s) : 0.f;
    float e1 = in ? __expf(v - mx_n) : 0.f;
    float s_a = wave_sum(e_a);
    float s_s = wave_sum(e_s);
    float inv_s1 = 1.f / wave_sum(e1);
    float en = in ? __expf((e1 - 1.f) * inv_s1) : 0.f;
    float s_n2 = wave_sum(en);
    wbuf[wslot][lane] =
        make_float4(e_a / s_a, e_s / s_s, en / s_n2, __int_as_float(dstj << 6));
    // pass 4: 8-deep pipelined gather+FMA batches (MLP=8)
    int j0 = 0;
    for (; j0 + 8 <= deg; j0 += 8) {
      float4 wv[8];
      unsigned int u[8];
#pragma unroll
      for (int t = 0; t < 8; ++t) wv[t] = wbuf[wslot][j0 + t];
#pragma unroll
      for (int t = 0; t < 8; ++t) u[t] = fth32[__float_as_int(wv[t].w) + lane];
#pragma unroll
      for (int t = 0; t < 8; ++t) pkfma3(wv[t].x, wv[t].y, wv[t].z, bfp2(u[t]), aa, av, an);
    }
    for (; j0 < deg; ++j0) {
      float4 wv = wbuf[wslot][j0];
      unsigned int u = fth32[__float_as_int(wv.w) + lane];
      pkfma3(wv.x, wv.y, wv.z, bfp2(u), aa, av, an);
    }
  } else if (deg > 0) {
    // ---- generic path (deg > 64, ~never at E/N=16): recompute per sweep ----
    float mx_a = -INFINITY, mx_s = -INFINITY, mx_n = -INFINITY;
    for (int j0 = start; j0 < end; j0 += 64) {
      int cnt = min(64, end - j0);
      float sr = sim_chunk(j0, cnt);
      int j = j0 + lane;
      bool in = lane < cnt;
      int dstj = in ? csr_dst[j] : 0;
      mx_a = fmaxf(mx_a, in ? csr_w[j] : -INFINITY);
      mx_s = fmaxf(mx_s, in ? sr * rn_n * rnh[dstj] : -INFINITY);
      mx_n = fmaxf(mx_n, in ? lrelu(ftx_i + fyh[dstj]) : -INFINITY);
    }
    mx_a = wave_max(mx_a);
    mx_s = wave_max(mx_s);
    mx_n = wave_max(mx_n);
    float s_a = 0.f, s_s = 0.f, s_n1 = 0.f;
    for (int j0 = start; j0 < end; j0 += 64) {
      int cnt = min(64, end - j0);
      float sr = sim_chunk(j0, cnt);
      int j = j0 + lane;
      bool in = lane < cnt;
      int dstj = in ? csr_dst[j] : 0;
      s_a += in ? __expf(csr_w[j] - mx_a) : 0.f;
      s_s += in ? __expf(sr * rn_n * rnh[dstj] - mx_s) : 0.f;
      s_n1 += in ? __expf(lrelu(ftx_i + fyh[dstj]) - mx_n) : 0.f;
    }
    s_a = wave_sum(s_a);
    s_s = wave_sum(s_s);
    float inv_s1 = 1.f / wave_sum(s_n1);
    float s_n2 = 0.f;
    for (int j0 = start; j0 < end; j0 += 64) {
      int cnt = min(64, end - j0);
      int j = j0 + lane;
      bool in = lane < cnt;
      float e1 = in ? __expf(lrelu(ftx_i + fyh[csr_dst[j]]) - mx_n) : 0.f;
      s_n2 += in ? __expf((e1 - 1.f) * inv_s1) : 0.f;
    }
    s_n2 = wave_sum(s_n2);
    float r_a = 1.f / s_a, r_s = 1.f / s_s, r_n = 1.f / s_n2;
    for (int j0 = start; j0 < end; j0 += 64) {
      int cnt = min(64, end - j0);
      float sr = sim_chunk(j0, cnt);
      int j = j0 + lane;
      bool in = lane < cnt;
      int dstj = in ? csr_dst[j] : 0;
      float e1 = in ? __expf(lrelu(ftx_i + fyh[dstj]) - mx_n) : 0.f;
      float pa = in ? __expf(csr_w[j] - mx_a) * r_a : 0.f;
      float ps = in ? __expf(sr * rn_n * rnh[dstj] - mx_s) * r_s : 0.f;
      float pn = in ? __expf((e1 - 1.f) * inv_s1) * r_n : 0.f;
      wbuf[wslot][lane] = make_float4(pa, ps, pn, __int_as_float(dstj << 6));
      for (int t = 0; t < cnt; ++t) {
        float4 wv = wbuf[wslot][t];
        unsigned int u = fth32[__float_as_int(wv.w) + lane];
        pkfma3(wv.x, wv.y, wv.z, bfp2(u), aa, av, an);
      }
    }
  }

  // epilogue: view attention
  f32x2 fi = bfp2(*(const unsigned int*)&fth[(size_t)n * 128 + lane * 2]);
  float2 wa = *(const float2*)&w_view[(size_t)h * 256 + lane * 2];
  float2 wb = *(const float2*)&w_view[(size_t)h * 256 + 128 + lane * 2];
  float d0 = wave_sum(fi[0] * wa.x + fi[1] * wa.y);
  float b0 = wave_sum(fi[0] * wb.x + fi[1] * wb.y);
  float b1 = wave_sum(aa[0] * wb.x + aa[1] * wb.y);
  float b2 = wave_sum(av[0] * wb.x + av[1] * wb.y);
  float b3 = wave_sum(an[0] * wb.x + an[1] * wb.y);
  float z0 = __expf(lrelu(d0 + b0));
  float z1 = __expf(lrelu(d0 + b1));
  float z2 = __expf(lrelu(d0 + b2));
  float z3 = __expf(lrelu(d0 + b3));
  float zm = fmaxf(fmaxf(z0, z1), fmaxf(z2, z3));
  float c0 = __expf(z0 - zm), c1 = __expf(z1 - zm), c2 = __expf(z2 - zm),
        c3 = __expf(z3 - zm);
  float rcs = 1.f / (c0 + c1 + c2 + c3);
  c0 *= rcs;
  c1 *= rcs;
  c2 *= rcs;
  c3 *= rcs;
  float2 bb = *(const float2*)&bias[(size_t)h * 128 + lane * 2];
  float ox = c0 * fi[0] + c1 * aa[0] + c2 * av[0] + c3 * an[0] + bb.x;
  float oy = c0 * fi[1] + c1 * aa[1] + c2 * av[1] + c3 * an[1] + bb.y;
  ox = ox > 0.f ? ox : expm1f(ox);
  oy = oy > 0.f ? oy : expm1f(oy);
  *(float2*)&out[(size_t)n * (H * 128) + (size_t)h * 128 + lane * 2] = make_float2(ox, oy);
}

extern "C" void kernel_launch(void* const* d_in, const int* in_sizes, int n_in,
                              void* d_out, int out_size, void* d_ws, size_t ws_size,
                              hipStream_t stream) {
  const float* features = (const float*)d_in[0];
  const int* adj = (const int*)d_in[1];
  const float* adj_val = (const float*)d_in[2];
  const float* W_trans = (const float*)d_in[3];
  const float* w_ftx = (const float*)d_in[4];
  const float* w_fty = (const float*)d_in[5];
  const float* w_view = (const float*)d_in[6];
  const float* bias = (const float*)d_in[7];
  float* out = (float*)d_out;

  const int IN_DIM = 256, D = 128;
  const int N = in_sizes[0] / IN_DIM;
  const int E = in_sizes[2];
  const int H = in_sizes[7] / D;

  char* p = (char*)d_ws;
  auto alloc = [&](size_t bytes) {
    char* r = p;
    p += (bytes + 255) & ~(size_t)255;
    return r;
  };
  // total ~63 MB
  unsigned short* ft = (unsigned short*)alloc((size_t)H * N * D * 2);  // 51.2 MB
  float* rnorm = (float*)alloc((size_t)H * N * 4);
  float* ftx = (float*)alloc((size_t)H * N * 4);
  float* fty = (float*)alloc((size_t)H * N * 4);
  int* row_ptr = (int*)alloc((size_t)(N + 1) * 4);
  int* deg = (int*)alloc((size_t)N * 4);
  int* cursor = (int*)alloc((size_t)N * 4);
  int* csr_dst = (int*)alloc((size_t)E * 4);
  float* csr_w = (float*)alloc((size_t)E * 4);
  unsigned short* WT = (unsigned short*)alloc((size_t)H * IN_DIM * D * 2);  // 512 KB
  int* tilesum = (int*)alloc(4096 * 4);
  (void)ws_size;
  (void)n_in;
  (void)out_size;

  int ntiles = (N + 1023) / 1024;

  // CSR build
  zero2_kernel<<<256, 256, 0, stream>>>(deg, cursor, N);
  hist_kernel<<<1024, 256, 0, stream>>>(adj, deg, E);
  scan_a<<<ntiles, 1024, 0, stream>>>(deg, row_ptr, tilesum, N);
  scan_b<<<1, 1024, 0, stream>>>(tilesum, ntiles);
  scan_c<<<ntiles, 1024, 0, stream>>>(row_ptr, tilesum, N, ntiles);
  scatter_kernel<<<1024, 256, 0, stream>>>(adj, adj_val, row_ptr, cursor, csr_dst, csr_w, E);

  // W transpose + MFMA GEMM (ft bf16)
  transw_kernel<<<(H * IN_DIM * D) / 256, 256, 0, stream>>>(W_trans, WT);
  dim3 ggrid(H, (N + 127) / 128);
  gemm_mfma<<<ggrid, 256, 0, stream>>>(features, WT, ft, N);

  // per-node scalars
  int waves = N * H;
  node_prep<<<(waves + 3) / 4, 256, 0, stream>>>(ft, w_ftx, w_fty, rnorm, ftx, fty, N, H);

  // fused sim + aggregation + view attention
  dim3 agrid((N + 3) / 4, H);
  aggregate_kernel<<<agrid, 256, 0, stream>>>(ft, ftx, fty, rnorm, row_ptr, csr_dst, csr_w,
                                              w_view, bias, out, N, E, H);
}

// Round 8
// 510.794 us; speedup vs baseline: 2.9058x; 1.1920x over previous
//
#include <hip/hip_runtime.h>
#include <math.h>

#define LALPHA 0.2f

using bf16x8 = __attribute__((ext_vector_type(8))) short;
using f32x4 = __attribute__((ext_vector_type(4))) float;
using f32x2 = __attribute__((ext_vector_type(2))) float;

__device__ __forceinline__ float wave_sum(float v) {
#pragma unroll
  for (int off = 32; off > 0; off >>= 1) v += __shfl_xor(v, off);
  return v;
}
// 16-lane group reduce (lanes with same lane>>4)
__device__ __forceinline__ float grp_sum(float v) {
#pragma unroll
  for (int off = 8; off > 0; off >>= 1) v += __shfl_xor(v, off);
  return v;
}
__device__ __forceinline__ float grp_max(float v) {
#pragma unroll
  for (int off = 8; off > 0; off >>= 1) v = fmaxf(v, __shfl_xor(v, off));
  return v;
}
__device__ __forceinline__ float lrelu(float x) { return x >= 0.f ? x : LALPHA * x; }

// bf16 pair -> f32x2 (bf16 = high 16 bits of f32)
__device__ __forceinline__ f32x2 bfp2(unsigned int u) {
  f32x2 r;
  r[0] = __uint_as_float(u << 16);
  r[1] = __uint_as_float(u & 0xffff0000u);
  return r;
}
__device__ __forceinline__ unsigned short f2bf(float x) {
  unsigned int b = __float_as_uint(x);
  return (unsigned short)((b + 0x7fffu + ((b >> 16) & 1u)) >> 16);  // RNE
}
__device__ __forceinline__ unsigned int cvtpk(float lo, float hi) {
  unsigned int r;
  asm("v_cvt_pk_bf16_f32 %0, %1, %2" : "=v"(r) : "v"(lo), "v"(hi));
  return r;
}

// per-edge accumulate: O{a,s,n}[k] += f[k] * w.{x,y,z}, static unroll
__device__ __forceinline__ void acc_edge(uint4 u, float4 wv, f32x2* Oa, f32x2* Os,
                                         f32x2* On) {
  f32x2 f[4] = {bfp2(u.x), bfp2(u.y), bfp2(u.z), bfp2(u.w)};
#pragma unroll
  for (int k = 0; k < 4; ++k) {
    Oa[k] += f[k] * wv.x;
    Os[k] += f[k] * wv.y;
    On[k] += f[k] * wv.z;
  }
}

// ---------------- CSR build ----------------
__global__ void zero2_kernel(int* a, int* b, int n) {
  for (int i = blockIdx.x * blockDim.x + threadIdx.x; i < n; i += gridDim.x * blockDim.x) {
    a[i] = 0;
    b[i] = 0;
  }
}

__global__ void hist_kernel(const int* __restrict__ adj, int* __restrict__ deg, int E) {
  for (int e = blockIdx.x * blockDim.x + threadIdx.x; e < E; e += gridDim.x * blockDim.x)
    atomicAdd(&deg[adj[2 * e]], 1);
}

__global__ __launch_bounds__(1024) void scan_a(const int* __restrict__ deg,
                                               int* __restrict__ row_ptr,
                                               int* __restrict__ tilesum, int n) {
  __shared__ int sm[1024];
  int tid = threadIdx.x;
  int idx = blockIdx.x * 1024 + tid;
  int v = (idx < n) ? deg[idx] : 0;
  sm[tid] = v;
  __syncthreads();
  for (int off = 1; off < 1024; off <<= 1) {
    int t = (tid >= off) ? sm[tid - off] : 0;
    __syncthreads();
    sm[tid] += t;
    __syncthreads();
  }
  if (idx < n) row_ptr[idx] = sm[tid] - v;
  if (tid == 1023) tilesum[blockIdx.x] = sm[1023];
}

__global__ __launch_bounds__(1024) void scan_b(int* __restrict__ tilesum, int ntiles) {
  __shared__ int sm[1024];
  int tid = threadIdx.x;
  int v = (tid < ntiles) ? tilesum[tid] : 0;
  sm[tid] = v;
  __syncthreads();
  for (int off = 1; off < 1024; off <<= 1) {
    int t = (tid >= off) ? sm[tid - off] : 0;
    __syncthreads();
    sm[tid] += t;
    __syncthreads();
  }
  if (tid < ntiles) tilesum[tid] = sm[tid] - v;
  if (tid == ntiles - 1) tilesum[ntiles] = sm[tid];
}

__global__ __launch_bounds__(1024) void scan_c(int* __restrict__ row_ptr,
                                               const int* __restrict__ tilesum, int n,
                                               int ntiles) {
  int idx = blockIdx.x * 1024 + threadIdx.x;
  if (idx < n) row_ptr[idx] += tilesum[blockIdx.x];
  if (idx == 0) row_ptr[n] = tilesum[ntiles];
}

__global__ void scatter_kernel(const int* __restrict__ adj, const float* __restrict__ av,
                               const int* __restrict__ row_ptr, int* __restrict__ cursor,
                               int* __restrict__ csr_dst, float* __restrict__ csr_w, int E) {
  for (int e = blockIdx.x * blockDim.x + threadIdx.x; e < E; e += gridDim.x * blockDim.x) {
    int s = adj[2 * e], d = adj[2 * e + 1];
    int pos = row_ptr[s] + atomicAdd(&cursor[s], 1);
    csr_dst[pos] = d;
    csr_w[pos] = av[e];
  }
}

__global__ void srcfill_kernel(const int* __restrict__ row_ptr, int* __restrict__ src_of,
                               int N) {
  int n = blockIdx.x * 4 + (threadIdx.x >> 6);
  int lane = threadIdx.x & 63;
  if (n >= N) return;
  int start = row_ptr[n], end = row_ptr[n + 1];
  for (int j = start + lane; j < end; j += 64) src_of[j] = n;
}

// ---------------- W transpose: WT[h][d][k] = bf16(W[h][k][d]) ----------------
__global__ void transw_kernel(const float* __restrict__ W, unsigned short* __restrict__ WT) {
  int idx = blockIdx.x * 256 + threadIdx.x;
  int d = idx & 127;
  int k = (idx >> 7) & 255;
  int h = idx >> 15;
  WT[((size_t)h * 128 + d) * 256 + k] = f2bf(W[idx]);
}

// ---------------- ft = features @ W_trans via MFMA, bf16 out, layout (N, H*128) ----
__global__ __launch_bounds__(256) void gemm_mfma(const float* __restrict__ A,
                                                 const unsigned short* __restrict__ WT,
                                                 unsigned short* __restrict__ ft, int N,
                                                 int H) {
  const int K = 256;
  int h = blockIdx.x;
  int r0 = blockIdx.y * 128 + (threadIdx.x >> 6) * 32;
  int lane = threadIdx.x & 63;
  int lr = lane & 15, lg = lane >> 4;
  int ra0 = min(r0 + lr, N - 1);
  int ra1 = min(r0 + 16 + lr, N - 1);
  const float* pa0 = A + (size_t)ra0 * K + lg * 8;
  const float* pa1 = A + (size_t)ra1 * K + lg * 8;
  const unsigned short* pb = WT + ((size_t)h * 128 + lr) * K + lg * 8;
  size_t st = (size_t)H * 128;

  f32x4 acc[2][8] = {};
  for (int k0 = 0; k0 < K; k0 += 32) {
    union {
      bf16x8 v;
      unsigned int u[4];
    } a0, a1;
    float4 f0 = *(const float4*)(pa0 + k0);
    float4 f1 = *(const float4*)(pa0 + k0 + 4);
    a0.u[0] = cvtpk(f0.x, f0.y);
    a0.u[1] = cvtpk(f0.z, f0.w);
    a0.u[2] = cvtpk(f1.x, f1.y);
    a0.u[3] = cvtpk(f1.z, f1.w);
    float4 g0 = *(const float4*)(pa1 + k0);
    float4 g1 = *(const float4*)(pa1 + k0 + 4);
    a1.u[0] = cvtpk(g0.x, g0.y);
    a1.u[1] = cvtpk(g0.z, g0.w);
    a1.u[2] = cvtpk(g1.x, g1.y);
    a1.u[3] = cvtpk(g1.z, g1.w);
    bf16x8 b[8];
#pragma unroll
    for (int cb = 0; cb < 8; ++cb) b[cb] = *(const bf16x8*)(pb + (size_t)cb * 16 * K + k0);
#pragma unroll
    for (int cb = 0; cb < 8; ++cb) {
      acc[0][cb] = __builtin_amdgcn_mfma_f32_16x16x32_bf16(a0.v, b[cb], acc[0][cb], 0, 0, 0);
      acc[1][cb] = __builtin_amdgcn_mfma_f32_16x16x32_bf16(a1.v, b[cb], acc[1][cb], 0, 0, 0);
    }
  }
#pragma unroll
  for (int i = 0; i < 2; ++i) {
#pragma unroll
    for (int cb = 0; cb < 8; ++cb) {
      int nb = r0 + i * 16 + lg * 4;
      int d = cb * 16 + lr;
      unsigned short* po = ft + (size_t)nb * st + (size_t)h * 128 + d;
      unsigned int u01 = cvtpk(acc[i][cb][0], acc[i][cb][1]);
      unsigned int u23 = cvtpk(acc[i][cb][2], acc[i][cb][3]);
      if (nb + 3 < N) {
        po[0] = (unsigned short)u01;
        po[st] = (unsigned short)(u01 >> 16);
        po[2 * st] = (unsigned short)u23;
        po[3 * st] = (unsigned short)(u23 >> 16);
      } else {
        if (nb < N) po[0] = (unsigned short)u01;
        if (nb + 1 < N) po[st] = (unsigned short)(u01 >> 16);
        if (nb + 2 < N) po[2 * st] = (unsigned short)u23;
        if (nb + 3 < N) po[3 * st] = (unsigned short)(u23 >> 16);
      }
    }
  }
}

// ---------------- per-node prep: rnorm, ftx, fty (layout n*H + h) ----------------
__global__ __launch_bounds__(256) void node_prep(const unsigned short* __restrict__ ft,
                                                 const float* __restrict__ w_ftx,
                                                 const float* __restrict__ w_fty,
                                                 float* __restrict__ rnorm,
                                                 float* __restrict__ ftx,
                                                 float* __restrict__ fty, int N, int H) {
  int wid = blockIdx.x * 4 + (threadIdx.x >> 6);  // wid = n*H + h
  int lane = threadIdx.x & 63;
  if (wid >= N * H) return;
  int h = wid & 3;
  f32x2 f = bfp2(*(const unsigned int*)&ft[(size_t)wid * 128 + lane * 2]);
  float2 wx = *(const float2*)&w_ftx[(size_t)h * 128 + lane * 2];
  float2 wy = *(const float2*)&w_fty[(size_t)h * 128 + lane * 2];
  float ss = wave_sum(f[0] * f[0] + f[1] * f[1]);
  float sx = wave_sum(f[0] * wx.x + f[1] * wx.y);
  float sy = wave_sum(f[0] * wy.x + f[1] * wy.y);
  if (lane == 0) {
    rnorm[wid] = rsqrtf(fmaxf(ss, 1e-12f));
    ftx[wid] = sx;
    fty[wid] = sy;
  }
}

// ---------------- per-edge cosine similarity via MFMA diagonal, out (E,H) --------
__global__ __launch_bounds__(256) void sim_kernel(const unsigned short* __restrict__ ft,
                                                  const float* __restrict__ rnorm,
                                                  const int* __restrict__ src_of,
                                                  const int* __restrict__ csr_dst,
                                                  float* __restrict__ sim, int E, int H) {
  int h = blockIdx.y;
  int wid = blockIdx.x * 4 + (threadIdx.x >> 6);
  int lane = threadIdx.x & 63;
  long base = (long)wid * 16;
  if (base >= E) return;
  int e = (int)base + (lane & 15);
  bool ok = e < E;
  int ec = ok ? e : (int)base;
  int s = src_of[ec], d = csr_dst[ec];
  int g = lane >> 4;
  const unsigned short* fs = ft + ((size_t)s * H + h) * 128 + g * 8;
  const unsigned short* fd = ft + ((size_t)d * H + h) * 128 + g * 8;
  f32x4 acc = {0.f, 0.f, 0.f, 0.f};
#pragma unroll
  for (int t = 0; t < 4; ++t) {
    bf16x8 a = *(const bf16x8*)(fs + t * 32);
    bf16x8 b = *(const bf16x8*)(fd + t * 32);
    acc = __builtin_amdgcn_mfma_f32_16x16x32_bf16(a, b, acc, 0, 0, 0);
  }
  if ((((lane & 15) >> 2) == g) && ok) {
    float v = acc[lane & 3];
    sim[(size_t)e * H + h] = v * rnorm[(size_t)s * H + h] * rnorm[(size_t)d * H + h];
  }
}

// ---------------- fused aggregation + view attention + ELU ----------------
// One wave per NODE (all 4 heads). lane = lg*16+ll: head lg, dims ll*8..ll*8+7.
// Per edge: ONE dwordx4 gather per lane covers all heads (1KB node row).
__global__ __launch_bounds__(256) void aggregate_kernel(
    const unsigned short* __restrict__ ft, const float* __restrict__ ftx,
    const float* __restrict__ fty, const float* __restrict__ sim,
    const int* __restrict__ row_ptr, const int* __restrict__ csr_dst,
    const float* __restrict__ csr_w, const float* __restrict__ w_view,
    const float* __restrict__ bias, float* __restrict__ out, int N, int H) {
  __shared__ float4 wbuf[4][64][4];  // [wave][edge][head] {pa, ps, pn, -}
  __shared__ int dbuf[4][64];        // [wave][edge] uint4-index of dst row
  int wslot = threadIdx.x >> 6;
  int n = blockIdx.x * 4 + wslot;
  int lane = threadIdx.x & 63;
  int lg = lane >> 4, ll = lane & 15;
  if (n >= N) return;
  int start = __builtin_amdgcn_readfirstlane(row_ptr[n]);
  int end = __builtin_amdgcn_readfirstlane(row_ptr[n + 1]);
  int deg = end - start;
  const uint4* ft4 = (const uint4*)ft;  // node row n at index n*64 + lane
  float ftx_nh = ftx[(size_t)n * 4 + lg];

  f32x2 Oa[4] = {}, Os[4] = {}, On[4] = {};

  if (deg > 0 && deg <= 64) {
    // ---- stats, fully register-resident (each group: 16 edges x 4 iters) ----
    float wc[4], sc[4], vc[4];
    int dc[4];
    float mxa = -INFINITY, mxs = -INFINITY, mxn = -INFINITY;
#pragma unroll
    for (int t = 0; t < 4; ++t) {
      int idx = t * 16 + ll;
      bool in = idx < deg;
      int j = in ? (start + idx) : start;
      wc[t] = in ? csr_w[j] : -INFINITY;
      dc[t] = csr_dst[j];
      sc[t] = in ? sim[(size_t)j * 4 + lg] : -INFINITY;
      vc[t] = in ? lrelu(ftx_nh + fty[(size_t)dc[t] * 4 + lg]) : -INFINITY;
      mxa = fmaxf(mxa, wc[t]);
      mxs = fmaxf(mxs, sc[t]);
      mxn = fmaxf(mxn, vc[t]);
    }
    mxa = grp_max(mxa);
    mxs = grp_max(mxs);
    mxn = grp_max(mxn);
    float ea[4], es[4], e1[4];
    float sa = 0.f, ss = 0.f, s1 = 0.f;
#pragma unroll
    for (int t = 0; t < 4; ++t) {
      ea[t] = __expf(wc[t] - mxa);  // 0 for padding (-INF)
      es[t] = __expf(sc[t] - mxs);
      e1[t] = __expf(vc[t] - mxn);
      sa += ea[t];
      ss += es[t];
      s1 += e1[t];
    }
    sa = grp_sum(sa);
    ss = grp_sum(ss);
    float inv1 = 1.f / grp_sum(s1);
    float en[4];
    float s2 = 0.f;
#pragma unroll
    for (int t = 0; t < 4; ++t) {
      bool in = (t * 16 + ll) < deg;
      en[t] = in ? __expf((e1[t] - 1.f) * inv1) : 0.f;
      s2 += en[t];
    }
    s2 = grp_sum(s2);
    float ra = 1.f / sa, rs = 1.f / ss, rn = 1.f / s2;
#pragma unroll
    for (int t = 0; t < 4; ++t) {
      int idx = t * 16 + ll;
      if (idx < deg) {
        wbuf[wslot][idx][lg] = make_float4(ea[t] * ra, es[t] * rs, en[t] * rn, 0.f);
        if (lg == 0) dbuf[wslot][idx] = dc[t] * 64;
      }
    }
    // ---- gather+accumulate, 4-deep batches (MLP=4) ----
    int jj = 0;
    for (; jj + 4 <= deg; jj += 4) {
      int r0 = dbuf[wslot][jj + 0], r1 = dbuf[wslot][jj + 1];
      int r2 = dbuf[wslot][jj + 2], r3 = dbuf[wslot][jj + 3];
      float4 w0 = wbuf[wslot][jj + 0][lg], w1 = wbuf[wslot][jj + 1][lg];
      float4 w2 = wbuf[wslot][jj + 2][lg], w3 = wbuf[wslot][jj + 3][lg];
      uint4 u0 = ft4[r0 + lane], u1 = ft4[r1 + lane];
      uint4 u2 = ft4[r2 + lane], u3 = ft4[r3 + lane];
      acc_edge(u0, w0, Oa, Os, On);
      acc_edge(u1, w1, Oa, Os, On);
      acc_edge(u2, w2, Oa, Os, On);
      acc_edge(u3, w3, Oa, Os, On);
    }
    for (; jj < deg; ++jj) {
      int r0 = dbuf[wslot][jj];
      float4 w0 = wbuf[wslot][jj][lg];
      uint4 u0 = ft4[r0 + lane];
      acc_edge(u0, w0, Oa, Os, On);
    }
  } else if (deg > 0) {
    // ---- generic path (deg > 64): strided sweeps, chunked accumulate ----
    float mxa = -INFINITY, mxs = -INFINITY, mxn = -INFINITY;
    for (int idx = ll; idx < deg; idx += 16) {
      int j = start + idx;
      mxa = fmaxf(mxa, csr_w[j]);
      mxs = fmaxf(mxs, sim[(size_t)j * 4 + lg]);
      mxn = fmaxf(mxn, lrelu(ftx_nh + fty[(size_t)csr_dst[j] * 4 + lg]));
    }
    mxa = grp_max(mxa);
    mxs = grp_max(mxs);
    mxn = grp_max(mxn);
    float sa = 0.f, ss = 0.f, s1 = 0.f;
    for (int idx = ll; idx < deg; idx += 16) {
      int j = start + idx;
      sa += __expf(csr_w[j] - mxa);
      ss += __expf(sim[(size_t)j * 4 + lg] - mxs);
      s1 += __expf(lrelu(ftx_nh + fty[(size_t)csr_dst[j] * 4 + lg]) - mxn);
    }
    sa = grp_sum(sa);
    ss = grp_sum(ss);
    float inv1 = 1.f / grp_sum(s1);
    float s2 = 0.f;
    for (int idx = ll; idx < deg; idx += 16) {
      int j = start + idx;
      float e1 = __expf(lrelu(ftx_nh + fty[(size_t)csr_dst[j] * 4 + lg]) - mxn);
      s2 += __expf((e1 - 1.f) * inv1);
    }
    s2 = grp_sum(s2);
    float ra = 1.f / sa, rs = 1.f / ss, rn = 1.f / s2;
    for (int c0 = 0; c0 < deg; c0 += 64) {
      int cnt = min(64, deg - c0);
#pragma unroll
      for (int t = 0; t < 4; ++t) {
        int idx = c0 + t * 16 + ll;
        if (idx < deg && (t * 16 + ll) < cnt) {
          int j = start + idx;
          int d = csr_dst[j];
          float pa = __expf(csr_w[j] - mxa) * ra;
          float ps = __expf(sim[(size_t)j * 4 + lg] - mxs) * rs;
          float e1 = __expf(lrelu(ftx_nh + fty[(size_t)d * 4 + lg]) - mxn);
          float pn = __expf((e1 - 1.f) * inv1) * rn;
          wbuf[wslot][t * 16 + ll][lg] = make_float4(pa, ps, pn, 0.f);
          if (lg == 0) dbuf[wslot][t * 16 + ll] = d * 64;
        }
      }
      for (int jj = 0; jj < cnt; ++jj) {
        int r0 = dbuf[wslot][jj];
        float4 w0 = wbuf[wslot][jj][lg];
        uint4 u0 = ft4[r0 + lane];
        acc_edge(u0, w0, Oa, Os, On);
      }
    }
  }

  // ---- epilogue: view attention per head group ----
  uint4 su = ft4[(size_t)n * 64 + lane];
  f32x2 fi[4] = {bfp2(su.x), bfp2(su.y), bfp2(su.z), bfp2(su.w)};
  const float4* wa4 = (const float4*)&w_view[(size_t)lg * 256 + ll * 8];
  const float4* wb4 = (const float4*)&w_view[(size_t)lg * 256 + 128 + ll * 8];
  float4 wa0 = wa4[0], wa1 = wa4[1];
  float4 wb0 = wb4[0], wb1 = wb4[1];
  float waf[8] = {wa0.x, wa0.y, wa0.z, wa0.w, wa1.x, wa1.y, wa1.z, wa1.w};
  float wbf[8] = {wb0.x, wb0.y, wb0.z, wb0.w, wb1.x, wb1.y, wb1.z, wb1.w};
  float d0 = 0.f, b0 = 0.f, b1 = 0.f, b2 = 0.f, b3 = 0.f;
#pragma unroll
  for (int k = 0; k < 4; ++k) {
    d0 += fi[k][0] * waf[2 * k] + fi[k][1] * waf[2 * k + 1];
    b0 += fi[k][0] * wbf[2 * k] + fi[k][1] * wbf[2 * k + 1];
    b1 += Oa[k][0] * wbf[2 * k] + Oa[k][1] * wbf[2 * k + 1];
    b2 += Os[k][0] * wbf[2 * k] + Os[k][1] * wbf[2 * k + 1];
    b3 += On[k][0] * wbf[2 * k] + On[k][1] * wbf[2 * k + 1];
  }
  d0 = grp_sum(d0);
  b0 = grp_sum(b0);
  b1 = grp_sum(b1);
  b2 = grp_sum(b2);
  b3 = grp_sum(b3);
  float z0 = __expf(lrelu(d0 + b0));
  float z1 = __expf(lrelu(d0 + b1));
  float z2 = __expf(lrelu(d0 + b2));
  float z3 = __expf(lrelu(d0 + b3));
  float zm = fmaxf(fmaxf(z0, z1), fmaxf(z2, z3));
  float c0 = __expf(z0 - zm), c1 = __expf(z1 - zm), c2 = __expf(z2 - zm),
        c3 = __expf(z3 - zm);
  float rcs = 1.f / (c0 + c1 + c2 + c3);
  c0 *= rcs;
  c1 *= rcs;
  c2 *= rcs;
  c3 *= rcs;
  const float4* bb4 = (const float4*)&bias[(size_t)lg * 128 + ll * 8];
  float4 bv0 = bb4[0], bv1 = bb4[1];
  float bbf[8] = {bv0.x, bv0.y, bv0.z, bv0.w, bv1.x, bv1.y, bv1.z, bv1.w};
  float of[8];
#pragma unroll
  for (int k = 0; k < 4; ++k) {
    float ox = c0 * fi[k][0] + c1 * Oa[k][0] + c2 * Os[k][0] + c3 * On[k][0] + bbf[2 * k];
    float oy =
        c0 * fi[k][1] + c1 * Oa[k][1] + c2 * Os[k][1] + c3 * On[k][1] + bbf[2 * k + 1];
    of[2 * k] = ox > 0.f ? ox : expm1f(ox);
    of[2 * k + 1] = oy > 0.f ? oy : expm1f(oy);
  }
  float4* po = (float4*)&out[(size_t)n * 512 + lane * 8];
  po[0] = make_float4(of[0], of[1], of[2], of[3]);
  po[1] = make_float4(of[4], of[5], of[6], of[7]);
}

extern "C" void kernel_launch(void* const* d_in, const int* in_sizes, int n_in,
                              void* d_out, int out_size, void* d_ws, size_t ws_size,
                              hipStream_t stream) {
  const float* features = (const float*)d_in[0];
  const int* adj = (const int*)d_in[1];
  const float* adj_val = (const float*)d_in[2];
  const float* W_trans = (const float*)d_in[3];
  const float* w_ftx = (const float*)d_in[4];
  const float* w_fty = (const float*)d_in[5];
  const float* w_view = (const float*)d_in[6];
  const float* bias = (const float*)d_in[7];
  float* out = (float*)d_out;

  const int IN_DIM = 256, D = 128;
  const int N = in_sizes[0] / IN_DIM;
  const int E = in_sizes[2];
  const int H = in_sizes[7] / D;

  char* p = (char*)d_ws;
  auto alloc = [&](size_t bytes) {
    char* r = p;
    p += (bytes + 255) & ~(size_t)255;
    return r;
  };
  // total ~77 MB (proven budget)
  unsigned short* ft = (unsigned short*)alloc((size_t)N * H * D * 2);  // 51.2 MB (N, H*128)
  float* rnorm = (float*)alloc((size_t)N * H * 4);
  float* ftx = (float*)alloc((size_t)N * H * 4);
  float* fty = (float*)alloc((size_t)N * H * 4);
  float* sim = (float*)alloc((size_t)E * H * 4);  // 12.8 MB, layout (E, H)
  int* row_ptr = (int*)alloc((size_t)(N + 1) * 4);
  int* deg = (int*)alloc((size_t)N * 4);
  int* cursor = (int*)alloc((size_t)N * 4);
  int* csr_dst = (int*)alloc((size_t)E * 4);
  float* csr_w = (float*)alloc((size_t)E * 4);
  int* src_of = (int*)alloc((size_t)E * 4);
  unsigned short* WT = (unsigned short*)alloc((size_t)H * IN_DIM * D * 2);  // 512 KB
  int* tilesum = (int*)alloc(4096 * 4);
  (void)ws_size;
  (void)n_in;
  (void)out_size;

  int ntiles = (N + 1023) / 1024;

  // CSR build
  zero2_kernel<<<256, 256, 0, stream>>>(deg, cursor, N);
  hist_kernel<<<1024, 256, 0, stream>>>(adj, deg, E);
  scan_a<<<ntiles, 1024, 0, stream>>>(deg, row_ptr, tilesum, N);
  scan_b<<<1, 1024, 0, stream>>>(tilesum, ntiles);
  scan_c<<<ntiles, 1024, 0, stream>>>(row_ptr, tilesum, N, ntiles);
  scatter_kernel<<<1024, 256, 0, stream>>>(adj, adj_val, row_ptr, cursor, csr_dst, csr_w, E);
  srcfill_kernel<<<(N + 3) / 4, 256, 0, stream>>>(row_ptr, src_of, N);

  // W transpose + MFMA GEMM (ft bf16, (N, H*128))
  transw_kernel<<<(H * IN_DIM * D) / 256, 256, 0, stream>>>(W_trans, WT);
  dim3 ggrid(H, (N + 127) / 128);
  gemm_mfma<<<ggrid, 256, 0, stream>>>(features, WT, ft, N, H);

  // per-node scalars
  int waves = N * H;
  node_prep<<<(waves + 3) / 4, 256, 0, stream>>>(ft, w_ftx, w_fty, rnorm, ftx, fty, N, H);

  // per-edge similarity (MFMA diagonal, 16 edges/wave), out (E,H)
  dim3 sgrid((E + 63) / 64, H);
  sim_kernel<<<sgrid, 256, 0, stream>>>(ft, rnorm, src_of, csr_dst, sim, E, H);

  // fused aggregation + view attention (one wave per node, all heads)
  dim3 agrid((N + 3) / 4);
  aggregate_kernel<<<agrid, 256, 0, stream>>>(ft, ftx, fty, sim, row_ptr, csr_dst, csr_w,
                                              w_view, bias, out, N, H);
}

// Round 9
// 465.606 us; speedup vs baseline: 3.1879x; 1.0971x over previous
//
#include <hip/hip_runtime.h>
#include <math.h>

#define LALPHA 0.2f

using bf16x8 = __attribute__((ext_vector_type(8))) short;
using f32x4 = __attribute__((ext_vector_type(4))) float;
using f32x2 = __attribute__((ext_vector_type(2))) float;

__device__ __forceinline__ float wave_sum(float v) {
#pragma unroll
  for (int off = 32; off > 0; off >>= 1) v += __shfl_xor(v, off);
  return v;
}
// 16-lane group reduce (lanes with same lane>>4)
__device__ __forceinline__ float grp_sum(float v) {
#pragma unroll
  for (int off = 8; off > 0; off >>= 1) v += __shfl_xor(v, off);
  return v;
}
__device__ __forceinline__ float grp_max(float v) {
#pragma unroll
  for (int off = 8; off > 0; off >>= 1) v = fmaxf(v, __shfl_xor(v, off));
  return v;
}
__device__ __forceinline__ float lrelu(float x) { return x >= 0.f ? x : LALPHA * x; }

// bf16 pair -> f32x2 (bf16 = high 16 bits of f32)
__device__ __forceinline__ f32x2 bfp2(unsigned int u) {
  f32x2 r;
  r[0] = __uint_as_float(u << 16);
  r[1] = __uint_as_float(u & 0xffff0000u);
  return r;
}
__device__ __forceinline__ unsigned short f2bf(float x) {
  unsigned int b = __float_as_uint(x);
  return (unsigned short)((b + 0x7fffu + ((b >> 16) & 1u)) >> 16);  // RNE
}
__device__ __forceinline__ unsigned int cvtpk(float lo, float hi) {
  unsigned int r;
  asm("v_cvt_pk_bf16_f32 %0, %1, %2" : "=v"(r) : "v"(lo), "v"(hi));
  return r;
}

// per-edge accumulate: O{a,s,n}[k] += f[k] * w.{x,y,z}
__device__ __forceinline__ void acc_edge(uint4 u, float4 wv, f32x2* Oa, f32x2* Os,
                                         f32x2* On) {
  f32x2 f[4] = {bfp2(u.x), bfp2(u.y), bfp2(u.z), bfp2(u.w)};
#pragma unroll
  for (int k = 0; k < 4; ++k) {
    Oa[k] += f[k] * wv.x;
    Os[k] += f[k] * wv.y;
    On[k] += f[k] * wv.z;
  }
}

// ---------------- CSR build ----------------
__global__ void zero2_kernel(int* a, int* b, int n) {
  for (int i = blockIdx.x * blockDim.x + threadIdx.x; i < n; i += gridDim.x * blockDim.x) {
    a[i] = 0;
    b[i] = 0;
  }
}

__global__ void hist_kernel(const int* __restrict__ adj, int* __restrict__ deg, int E) {
  for (int e = blockIdx.x * blockDim.x + threadIdx.x; e < E; e += gridDim.x * blockDim.x)
    atomicAdd(&deg[adj[2 * e]], 1);
}

__global__ __launch_bounds__(1024) void scan_a(const int* __restrict__ deg,
                                               int* __restrict__ row_ptr,
                                               int* __restrict__ tilesum, int n) {
  __shared__ int sm[1024];
  int tid = threadIdx.x;
  int idx = blockIdx.x * 1024 + tid;
  int v = (idx < n) ? deg[idx] : 0;
  sm[tid] = v;
  __syncthreads();
  for (int off = 1; off < 1024; off <<= 1) {
    int t = (tid >= off) ? sm[tid - off] : 0;
    __syncthreads();
    sm[tid] += t;
    __syncthreads();
  }
  if (idx < n) row_ptr[idx] = sm[tid] - v;
  if (tid == 1023) tilesum[blockIdx.x] = sm[1023];
}

__global__ __launch_bounds__(1024) void scan_b(int* __restrict__ tilesum, int ntiles) {
  __shared__ int sm[1024];
  int tid = threadIdx.x;
  int v = (tid < ntiles) ? tilesum[tid] : 0;
  sm[tid] = v;
  __syncthreads();
  for (int off = 1; off < 1024; off <<= 1) {
    int t = (tid >= off) ? sm[tid - off] : 0;
    __syncthreads();
    sm[tid] += t;
    __syncthreads();
  }
  if (tid < ntiles) tilesum[tid] = sm[tid] - v;
  if (tid == ntiles - 1) tilesum[ntiles] = sm[tid];
}

__global__ __launch_bounds__(1024) void scan_c(int* __restrict__ row_ptr,
                                               const int* __restrict__ tilesum, int n,
                                               int ntiles) {
  int idx = blockIdx.x * 1024 + threadIdx.x;
  if (idx < n) row_ptr[idx] += tilesum[blockIdx.x];
  if (idx == 0) row_ptr[n] = tilesum[ntiles];
}

__global__ void scatter_kernel(const int* __restrict__ adj, const float* __restrict__ av,
                               const int* __restrict__ row_ptr, int* __restrict__ cursor,
                               int* __restrict__ csr_dst, float* __restrict__ csr_w, int E) {
  for (int e = blockIdx.x * blockDim.x + threadIdx.x; e < E; e += gridDim.x * blockDim.x) {
    int s = adj[2 * e], d = adj[2 * e + 1];
    int pos = row_ptr[s] + atomicAdd(&cursor[s], 1);
    csr_dst[pos] = d;
    csr_w[pos] = av[e];
  }
}

// ---------------- W transpose: WT[h][d][k] = bf16(W[h][k][d]) ----------------
__global__ void transw_kernel(const float* __restrict__ W, unsigned short* __restrict__ WT) {
  int idx = blockIdx.x * 256 + threadIdx.x;
  int d = idx & 127;
  int k = (idx >> 7) & 255;
  int h = idx >> 15;
  WT[((size_t)h * 128 + d) * 256 + k] = f2bf(W[idx]);
}

// ---------------- ft = features @ W_trans via MFMA, bf16 out, layout (N, H*128) ----
__global__ __launch_bounds__(256) void gemm_mfma(const float* __restrict__ A,
                                                 const unsigned short* __restrict__ WT,
                                                 unsigned short* __restrict__ ft, int N,
                                                 int H) {
  __shared__ unsigned short tile[4][32][136];  // per-wave staging, padded stride
  const int K = 256;
  int h = blockIdx.x;
  int w = threadIdx.x >> 6;
  int r0 = blockIdx.y * 128 + w * 32;
  int lane = threadIdx.x & 63;
  int lr = lane & 15, lg = lane >> 4;
  int ra0 = min(r0 + lr, N - 1);
  int ra1 = min(r0 + 16 + lr, N - 1);
  const float* pa0 = A + (size_t)ra0 * K + lg * 8;
  const float* pa1 = A + (size_t)ra1 * K + lg * 8;
  const unsigned short* pb = WT + ((size_t)h * 128 + lr) * K + lg * 8;
  size_t st = (size_t)H * 128;

  f32x4 acc[2][8] = {};
  for (int k0 = 0; k0 < K; k0 += 32) {
    union {
      bf16x8 v;
      unsigned int u[4];
    } a0, a1;
    float4 f0 = *(const float4*)(pa0 + k0);
    float4 f1 = *(const float4*)(pa0 + k0 + 4);
    a0.u[0] = cvtpk(f0.x, f0.y);
    a0.u[1] = cvtpk(f0.z, f0.w);
    a0.u[2] = cvtpk(f1.x, f1.y);
    a0.u[3] = cvtpk(f1.z, f1.w);
    float4 g0 = *(const float4*)(pa1 + k0);
    float4 g1 = *(const float4*)(pa1 + k0 + 4);
    a1.u[0] = cvtpk(g0.x, g0.y);
    a1.u[1] = cvtpk(g0.z, g0.w);
    a1.u[2] = cvtpk(g1.x, g1.y);
    a1.u[3] = cvtpk(g1.z, g1.w);
    bf16x8 b[8];
#pragma unroll
    for (int cb = 0; cb < 8; ++cb) b[cb] = *(const bf16x8*)(pb + (size_t)cb * 16 * K + k0);
#pragma unroll
    for (int cb = 0; cb < 8; ++cb) {
      acc[0][cb] = __builtin_amdgcn_mfma_f32_16x16x32_bf16(a0.v, b[cb], acc[0][cb], 0, 0, 0);
      acc[1][cb] = __builtin_amdgcn_mfma_f32_16x16x32_bf16(a1.v, b[cb], acc[1][cb], 0, 0, 0);
    }
  }
  // stage tile in LDS (per-wave region, no cross-wave barrier needed)
#pragma unroll
  for (int i = 0; i < 2; ++i) {
#pragma unroll
    for (int cb = 0; cb < 8; ++cb) {
      int rbase = i * 16 + lg * 4;
      int col = cb * 16 + lr;
      unsigned int u01 = cvtpk(acc[i][cb][0], acc[i][cb][1]);
      unsigned int u23 = cvtpk(acc[i][cb][2], acc[i][cb][3]);
      tile[w][rbase + 0][col] = (unsigned short)u01;
      tile[w][rbase + 1][col] = (unsigned short)(u01 >> 16);
      tile[w][rbase + 2][col] = (unsigned short)u23;
      tile[w][rbase + 3][col] = (unsigned short)(u23 >> 16);
    }
  }
  // coalesced write-out: 4 rows per pass (16 lanes x 16B = 256B per row)
#pragma unroll
  for (int rr = 0; rr < 8; ++rr) {
    int row = rr * 4 + lg;
    int nb = r0 + row;
    if (nb < N) {
      *(uint4*)&ft[(size_t)nb * st + (size_t)h * 128 + lr * 8] =
          *(const uint4*)&tile[w][row][lr * 8];
    }
  }
}

// ---------------- per-node prep: rnorm, ftx, fty (layout n*H + h) ----------------
__global__ __launch_bounds__(256) void node_prep(const unsigned short* __restrict__ ft,
                                                 const float* __restrict__ w_ftx,
                                                 const float* __restrict__ w_fty,
                                                 float* __restrict__ rnorm,
                                                 float* __restrict__ ftx,
                                                 float* __restrict__ fty, int N, int H) {
  int wid = blockIdx.x * 4 + (threadIdx.x >> 6);  // wid = n*H + h
  int lane = threadIdx.x & 63;
  if (wid >= N * H) return;
  int h = wid & 3;
  f32x2 f = bfp2(*(const unsigned int*)&ft[(size_t)wid * 128 + lane * 2]);
  float2 wx = *(const float2*)&w_ftx[(size_t)h * 128 + lane * 2];
  float2 wy = *(const float2*)&w_fty[(size_t)h * 128 + lane * 2];
  float ss = wave_sum(f[0] * f[0] + f[1] * f[1]);
  float sx = wave_sum(f[0] * wx.x + f[1] * wx.y);
  float sy = wave_sum(f[0] * wy.x + f[1] * wy.y);
  if (lane == 0) {
    rnorm[wid] = rsqrtf(fmaxf(ss, 1e-12f));
    ftx[wid] = sx;
    fty[wid] = sy;
  }
}

// ---------------- fused sim + aggregation + view attention + ELU ----------------
// One wave per NODE (all 4 heads). lane = lg*16+ll: head lg, dims ll*8..ll*8+7.
// Sim computed in-pass: gather dst row (same rows pass 4 needs -> L2-warm),
// 4 head-dots via per-lane partials + grp_sum; owning lane keeps it in a reg.
__global__ __launch_bounds__(256) void aggregate_kernel(
    const unsigned short* __restrict__ ft, const float* __restrict__ ftx,
    const float* __restrict__ fty, const float* __restrict__ rnorm,
    const int* __restrict__ row_ptr, const int* __restrict__ csr_dst,
    const float* __restrict__ csr_w, const float* __restrict__ w_view,
    const float* __restrict__ bias, float* __restrict__ out, int N, int H) {
  __shared__ float4 wbuf[4][64][4];  // [wave][edge][head] {pa, ps, pn, -}
  __shared__ int dbuf[4][64];        // [wave][edge] uint4-index of dst row
  int wslot = threadIdx.x >> 6;
  int n = blockIdx.x * 4 + wslot;
  int lane = threadIdx.x & 63;
  int lg = lane >> 4, ll = lane & 15;
  if (n >= N) return;
  int start = __builtin_amdgcn_readfirstlane(row_ptr[n]);
  int end = __builtin_amdgcn_readfirstlane(row_ptr[n + 1]);
  int deg = end - start;
  const uint4* ft4 = (const uint4*)ft;  // node row r at index r*64 + lane
  float ftx_nh = ftx[(size_t)n * 4 + lg];
  float rn_n = rnorm[(size_t)n * 4 + lg];

  // own row, kept in regs (used for sim dots AND epilogue)
  uint4 su = ft4[(size_t)n * 64 + lane];
  f32x2 fsu[4] = {bfp2(su.x), bfp2(su.y), bfp2(su.z), bfp2(su.w)};

  // dot of gathered row u with own row, per head lg (full after grp_sum)
  auto dot_own = [&](uint4 u) -> float {
    f32x2 pp = bfp2(u.x) * fsu[0];
    pp += bfp2(u.y) * fsu[1];
    pp += bfp2(u.z) * fsu[2];
    pp += bfp2(u.w) * fsu[3];
    return grp_sum(pp[0] + pp[1]);
  };

  // compute sims for chunk [c0, c0+64): sc[t] = sim of edge c0+t*16+ll (head lg),
  // -INF on non-owning / out-of-range lanes.
  auto compute_sims = [&](int c0, float* sc) {
#pragma unroll
    for (int t = 0; t < 4; ++t) {
      sc[t] = -INFINITY;
      int lim = deg - c0 - t * 16;
      if (lim <= 0) continue;
      if (lim > 16) lim = 16;
      bool in = ll < lim;
      int j = start + c0 + (in ? t * 16 + ll : 0);
      int dcl = csr_dst[j];
      float rcl = rnorm[(size_t)dcl * 4 + lg];
      int jb = 0;
      for (; jb + 4 <= lim; jb += 4) {
        int r0 = __builtin_amdgcn_readlane(dcl, jb + 0) * 64;
        int r1 = __builtin_amdgcn_readlane(dcl, jb + 1) * 64;
        int r2 = __builtin_amdgcn_readlane(dcl, jb + 2) * 64;
        int r3 = __builtin_amdgcn_readlane(dcl, jb + 3) * 64;
        uint4 u0 = ft4[r0 + lane], u1 = ft4[r1 + lane];
        uint4 u2 = ft4[r2 + lane], u3 = ft4[r3 + lane];
        float d0 = dot_own(u0), d1 = dot_own(u1), d2 = dot_own(u2), d3 = dot_own(u3);
        if (ll == jb + 0) sc[t] = d0 * rcl * rn_n;
        if (ll == jb + 1) sc[t] = d1 * rcl * rn_n;
        if (ll == jb + 2) sc[t] = d2 * rcl * rn_n;
        if (ll == jb + 3) sc[t] = d3 * rcl * rn_n;
      }
      for (; jb < lim; ++jb) {
        int r0 = __builtin_amdgcn_readlane(dcl, jb) * 64;
        uint4 u0 = ft4[r0 + lane];
        float d0 = dot_own(u0);
        if (ll == jb) sc[t] = d0 * rcl * rn_n;
      }
    }
  };

  f32x2 Oa[4] = {}, Os[4] = {}, On[4] = {};

  if (deg > 0 && deg <= 64) {
    // ---- pass A: sims in registers ----
    float sc[4];
    compute_sims(0, sc);
    // ---- stats, register-resident ----
    float wc[4], vc[4];
    int dc[4];
    float mxa = -INFINITY, mxs = -INFINITY, mxn = -INFINITY;
#pragma unroll
    for (int t = 0; t < 4; ++t) {
      int idx = t * 16 + ll;
      bool in = idx < deg;
      int j = in ? (start + idx) : start;
      wc[t] = in ? csr_w[j] : -INFINITY;
      dc[t] = csr_dst[j];
      vc[t] = in ? lrelu(ftx_nh + fty[(size_t)dc[t] * 4 + lg]) : -INFINITY;
      mxa = fmaxf(mxa, wc[t]);
      mxs = fmaxf(mxs, sc[t]);
      mxn = fmaxf(mxn, vc[t]);
    }
    mxa = grp_max(mxa);
    mxs = grp_max(mxs);
    mxn = grp_max(mxn);
    float ea[4], es[4], e1[4];
    float sa = 0.f, ss = 0.f, s1 = 0.f;
#pragma unroll
    for (int t = 0; t < 4; ++t) {
      ea[t] = __expf(wc[t] - mxa);  // 0 for padding (-INF)
      es[t] = __expf(sc[t] - mxs);
      e1[t] = __expf(vc[t] - mxn);
      sa += ea[t];
      ss += es[t];
      s1 += e1[t];
    }
    sa = grp_sum(sa);
    ss = grp_sum(ss);
    float inv1 = 1.f / grp_sum(s1);
    float en[4];
    float s2 = 0.f;
#pragma unroll
    for (int t = 0; t < 4; ++t) {
      bool in = (t * 16 + ll) < deg;
      en[t] = in ? __expf((e1[t] - 1.f) * inv1) : 0.f;
      s2 += en[t];
    }
    s2 = grp_sum(s2);
    float ra = 1.f / sa, rs = 1.f / ss, rn = 1.f / s2;
#pragma unroll
    for (int t = 0; t < 4; ++t) {
      int idx = t * 16 + ll;
      if (idx < deg) {
        wbuf[wslot][idx][lg] = make_float4(ea[t] * ra, es[t] * rs, en[t] * rn, 0.f);
        if (lg == 0) dbuf[wslot][idx] = dc[t] * 64;
      }
    }
    // ---- pass 4: gather+accumulate, 4-deep (rows L2-warm from pass A) ----
    int jj = 0;
    for (; jj + 4 <= deg; jj += 4) {
      int r0 = dbuf[wslot][jj + 0], r1 = dbuf[wslot][jj + 1];
      int r2 = dbuf[wslot][jj + 2], r3 = dbuf[wslot][jj + 3];
      float4 w0 = wbuf[wslot][jj + 0][lg], w1 = wbuf[wslot][jj + 1][lg];
      float4 w2 = wbuf[wslot][jj + 2][lg], w3 = wbuf[wslot][jj + 3][lg];
      uint4 u0 = ft4[r0 + lane], u1 = ft4[r1 + lane];
      uint4 u2 = ft4[r2 + lane], u3 = ft4[r3 + lane];
      acc_edge(u0, w0, Oa, Os, On);
      acc_edge(u1, w1, Oa, Os, On);
      acc_edge(u2, w2, Oa, Os, On);
      acc_edge(u3, w3, Oa, Os, On);
    }
    for (; jj < deg; ++jj) {
      int r0 = dbuf[wslot][jj];
      float4 w0 = wbuf[wslot][jj][lg];
      uint4 u0 = ft4[r0 + lane];
      acc_edge(u0, w0, Oa, Os, On);
    }
  } else if (deg > 0) {
    // ---- generic path (deg > 64, ~never at mean degree 16): recompute sweeps ----
    float mxa = -INFINITY, mxs = -INFINITY, mxn = -INFINITY;
    for (int idx = ll; idx < deg; idx += 16) {
      int j = start + idx;
      mxa = fmaxf(mxa, csr_w[j]);
      mxn = fmaxf(mxn, lrelu(ftx_nh + fty[(size_t)csr_dst[j] * 4 + lg]));
    }
    for (int c0 = 0; c0 < deg; c0 += 64) {
      float scc[4];
      compute_sims(c0, scc);
#pragma unroll
      for (int t = 0; t < 4; ++t) mxs = fmaxf(mxs, scc[t]);
    }
    mxa = grp_max(mxa);
    mxs = grp_max(mxs);
    mxn = grp_max(mxn);
    float sa = 0.f, ss = 0.f, s1 = 0.f;
    for (int idx = ll; idx < deg; idx += 16) {
      int j = start + idx;
      sa += __expf(csr_w[j] - mxa);
      s1 += __expf(lrelu(ftx_nh + fty[(size_t)csr_dst[j] * 4 + lg]) - mxn);
    }
    for (int c0 = 0; c0 < deg; c0 += 64) {
      float scc[4];
      compute_sims(c0, scc);
#pragma unroll
      for (int t = 0; t < 4; ++t) ss += (scc[t] > -INFINITY) ? __expf(scc[t] - mxs) : 0.f;
    }
    sa = grp_sum(sa);
    ss = grp_sum(ss);
    float inv1 = 1.f / grp_sum(s1);
    float s2 = 0.f;
    for (int idx = ll; idx < deg; idx += 16) {
      int j = start + idx;
      float e1 = __expf(lrelu(ftx_nh + fty[(size_t)csr_dst[j] * 4 + lg]) - mxn);
      s2 += __expf((e1 - 1.f) * inv1);
    }
    s2 = grp_sum(s2);
    float ra = 1.f / sa, rs = 1.f / ss, rn = 1.f / s2;
    for (int c0 = 0; c0 < deg; c0 += 64) {
      int cnt = min(64, deg - c0);
      float scc[4];
      compute_sims(c0, scc);
#pragma unroll
      for (int t = 0; t < 4; ++t) {
        int loc = t * 16 + ll;
        if (loc < cnt) {
          int j = start + c0 + loc;
          int d = csr_dst[j];
          float pa = __expf(csr_w[j] - mxa) * ra;
          float ps = __expf(scc[t] - mxs) * rs;
          float e1 = __expf(lrelu(ftx_nh + fty[(size_t)d * 4 + lg]) - mxn);
          float pn = __expf((e1 - 1.f) * inv1) * rn;
          wbuf[wslot][loc][lg] = make_float4(pa, ps, pn, 0.f);
          if (lg == 0) dbuf[wslot][loc] = d * 64;
        }
      }
      for (int jj = 0; jj < cnt; ++jj) {
        int r0 = dbuf[wslot][jj];
        float4 w0 = wbuf[wslot][jj][lg];
        uint4 u0 = ft4[r0 + lane];
        acc_edge(u0, w0, Oa, Os, On);
      }
    }
  }

  // ---- epilogue: view attention per head group ----
  f32x2* fi = fsu;
  const float4* wa4 = (const float4*)&w_view[(size_t)lg * 256 + ll * 8];
  const float4* wb4 = (const float4*)&w_view[(size_t)lg * 256 + 128 + ll * 8];
  float4 wa0 = wa4[0], wa1 = wa4[1];
  float4 wb0 = wb4[0], wb1 = wb4[1];
  float waf[8] = {wa0.x, wa0.y, wa0.z, wa0.w, wa1.x, wa1.y, wa1.z, wa1.w};
  float wbf[8] = {wb0.x, wb0.y, wb0.z, wb0.w, wb1.x, wb1.y, wb1.z, wb1.w};
  float d0 = 0.f, b0 = 0.f, b1 = 0.f, b2 = 0.f, b3 = 0.f;
#pragma unroll
  for (int k = 0; k < 4; ++k) {
    d0 += fi[k][0] * waf[2 * k] + fi[k][1] * waf[2 * k + 1];
    b0 += fi[k][0] * wbf[2 * k] + fi[k][1] * wbf[2 * k + 1];
    b1 += Oa[k][0] * wbf[2 * k] + Oa[k][1] * wbf[2 * k + 1];
    b2 += Os[k][0] * wbf[2 * k] + Os[k][1] * wbf[2 * k + 1];
    b3 += On[k][0] * wbf[2 * k] + On[k][1] * wbf[2 * k + 1];
  }
  d0 = grp_sum(d0);
  b0 = grp_sum(b0);
  b1 = grp_sum(b1);
  b2 = grp_sum(b2);
  b3 = grp_sum(b3);
  float z0 = __expf(lrelu(d0 + b0));
  float z1 = __expf(lrelu(d0 + b1));
  float z2 = __expf(lrelu(d0 + b2));
  float z3 = __expf(lrelu(d0 + b3));
  float zm = fmaxf(fmaxf(z0, z1), fmaxf(z2, z3));
  float c0 = __expf(z0 - zm), c1 = __expf(z1 - zm), c2 = __expf(z2 - zm),
        c3 = __expf(z3 - zm);
  float rcs = 1.f / (c0 + c1 + c2 + c3);
  c0 *= rcs;
  c1 *= rcs;
  c2 *= rcs;
  c3 *= rcs;
  const float4* bb4 = (const float4*)&bias[(size_t)lg * 128 + ll * 8];
  float4 bv0 = bb4[0], bv1 = bb4[1];
  float bbf[8] = {bv0.x, bv0.y, bv0.z, bv0.w, bv1.x, bv1.y, bv1.z, bv1.w};
  float of[8];
#pragma unroll
  for (int k = 0; k < 4; ++k) {
    float ox = c0 * fi[k][0] + c1 * Oa[k][0] + c2 * Os[k][0] + c3 * On[k][0] + bbf[2 * k];
    float oy =
        c0 * fi[k][1] + c1 * Oa[k][1] + c2 * Os[k][1] + c3 * On[k][1] + bbf[2 * k + 1];
    of[2 * k] = ox > 0.f ? ox : expm1f(ox);
    of[2 * k + 1] = oy > 0.f ? oy : expm1f(oy);
  }
  float4* po = (float4*)&out[(size_t)n * 512 + lane * 8];
  po[0] = make_float4(of[0], of[1], of[2], of[3]);
  po[1] = make_float4(of[4], of[5], of[6], of[7]);
}

extern "C" void kernel_launch(void* const* d_in, const int* in_sizes, int n_in,
                              void* d_out, int out_size, void* d_ws, size_t ws_size,
                              hipStream_t stream) {
  const float* features = (const float*)d_in[0];
  const int* adj = (const int*)d_in[1];
  const float* adj_val = (const float*)d_in[2];
  const float* W_trans = (const float*)d_in[3];
  const float* w_ftx = (const float*)d_in[4];
  const float* w_fty = (const float*)d_in[5];
  const float* w_view = (const float*)d_in[6];
  const float* bias = (const float*)d_in[7];
  float* out = (float*)d_out;

  const int IN_DIM = 256, D = 128;
  const int N = in_sizes[0] / IN_DIM;
  const int E = in_sizes[2];
  const int H = in_sizes[7] / D;

  char* p = (char*)d_ws;
  auto alloc = [&](size_t bytes) {
    char* r = p;
    p += (bytes + 255) & ~(size_t)255;
    return r;
  };
  // total ~60 MB
  unsigned short* ft = (unsigned short*)alloc((size_t)N * H * D * 2);  // 51.2 MB (N, H*128)
  float* rnorm = (float*)alloc((size_t)N * H * 4);
  float* ftx = (float*)alloc((size_t)N * H * 4);
  float* fty = (float*)alloc((size_t)N * H * 4);
  int* row_ptr = (int*)alloc((size_t)(N + 1) * 4);
  int* deg = (int*)alloc((size_t)N * 4);
  int* cursor = (int*)alloc((size_t)N * 4);
  int* csr_dst = (int*)alloc((size_t)E * 4);
  float* csr_w = (float*)alloc((size_t)E * 4);
  unsigned short* WT = (unsigned short*)alloc((size_t)H * IN_DIM * D * 2);  // 512 KB
  int* tilesum = (int*)alloc(4096 * 4);
  (void)ws_size;
  (void)n_in;
  (void)out_size;

  int ntiles = (N + 1023) / 1024;

  // CSR build
  zero2_kernel<<<256, 256, 0, stream>>>(deg, cursor, N);
  hist_kernel<<<1024, 256, 0, stream>>>(adj, deg, E);
  scan_a<<<ntiles, 1024, 0, stream>>>(deg, row_ptr, tilesum, N);
  scan_b<<<1, 1024, 0, stream>>>(tilesum, ntiles);
  scan_c<<<ntiles, 1024, 0, stream>>>(row_ptr, tilesum, N, ntiles);
  scatter_kernel<<<1024, 256, 0, stream>>>(adj, adj_val, row_ptr, cursor, csr_dst, csr_w, E);

  // W transpose + MFMA GEMM (ft bf16, (N, H*128))
  transw_kernel<<<(H * IN_DIM * D) / 256, 256, 0, stream>>>(W_trans, WT);
  dim3 ggrid(H, (N + 127) / 128);
  gemm_mfma<<<ggrid, 256, 0, stream>>>(features, WT, ft, N, H);

  // per-node scalars
  int waves = N * H;
  node_prep<<<(waves + 3) / 4, 256, 0, stream>>>(ft, w_ftx, w_fty, rnorm, ftx, fty, N, H);

  // fused sim + aggregation + view attention (one wave per node, all heads)
  dim3 agrid((N + 3) / 4);
  aggregate_kernel<<<agrid, 256, 0, stream>>>(ft, ftx, fty, rnorm, row_ptr, csr_dst, csr_w,
                                              w_view, bias, out, N, H);
}

// Round 10
// 389.051 us; speedup vs baseline: 3.8152x; 1.1968x over previous
//
#include <hip/hip_runtime.h>
#include <math.h>

#define LALPHA 0.2f

using bf16x8 = __attribute__((ext_vector_type(8))) short;
using f32x4 = __attribute__((ext_vector_type(4))) float;
using f32x2 = __attribute__((ext_vector_type(2))) float;

__device__ __forceinline__ float wave_sum(float v) {
#pragma unroll
  for (int off = 32; off > 0; off >>= 1) v += __shfl_xor(v, off);
  return v;
}
// 16-lane group reduce (lanes with same lane>>4)
__device__ __forceinline__ float grp_sum(float v) {
#pragma unroll
  for (int off = 8; off > 0; off >>= 1) v += __shfl_xor(v, off);
  return v;
}
__device__ __forceinline__ float grp_max(float v) {
#pragma unroll
  for (int off = 8; off > 0; off >>= 1) v = fmaxf(v, __shfl_xor(v, off));
  return v;
}
__device__ __forceinline__ float lrelu(float x) { return x >= 0.f ? x : LALPHA * x; }

// bf16 pair -> f32x2 (bf16 = high 16 bits of f32)
__device__ __forceinline__ f32x2 bfp2(unsigned int u) {
  f32x2 r;
  r[0] = __uint_as_float(u << 16);
  r[1] = __uint_as_float(u & 0xffff0000u);
  return r;
}
__device__ __forceinline__ unsigned short f2bf(float x) {
  unsigned int b = __float_as_uint(x);
  return (unsigned short)((b + 0x7fffu + ((b >> 16) & 1u)) >> 16);  // RNE
}
__device__ __forceinline__ unsigned int cvtpk(float lo, float hi) {
  unsigned int r;
  asm("v_cvt_pk_bf16_f32 %0, %1, %2" : "=v"(r) : "v"(lo), "v"(hi));
  return r;
}

// ---------------- CSR build ----------------
__global__ void zero2_kernel(int* a, int* b, int n) {
  for (int i = blockIdx.x * blockDim.x + threadIdx.x; i < n; i += gridDim.x * blockDim.x) {
    a[i] = 0;
    b[i] = 0;
  }
}

__global__ void hist_kernel(const int* __restrict__ adj, int* __restrict__ deg, int E) {
  for (int e = blockIdx.x * blockDim.x + threadIdx.x; e < E; e += gridDim.x * blockDim.x)
    atomicAdd(&deg[adj[2 * e]], 1);
}

__global__ __launch_bounds__(1024) void scan_a(const int* __restrict__ deg,
                                               int* __restrict__ row_ptr,
                                               int* __restrict__ tilesum, int n) {
  __shared__ int sm[1024];
  int tid = threadIdx.x;
  int idx = blockIdx.x * 1024 + tid;
  int v = (idx < n) ? deg[idx] : 0;
  sm[tid] = v;
  __syncthreads();
  for (int off = 1; off < 1024; off <<= 1) {
    int t = (tid >= off) ? sm[tid - off] : 0;
    __syncthreads();
    sm[tid] += t;
    __syncthreads();
  }
  if (idx < n) row_ptr[idx] = sm[tid] - v;
  if (tid == 1023) tilesum[blockIdx.x] = sm[1023];
}

__global__ __launch_bounds__(1024) void scan_b(int* __restrict__ tilesum, int ntiles) {
  __shared__ int sm[1024];
  int tid = threadIdx.x;
  int v = (tid < ntiles) ? tilesum[tid] : 0;
  sm[tid] = v;
  __syncthreads();
  for (int off = 1; off < 1024; off <<= 1) {
    int t = (tid >= off) ? sm[tid - off] : 0;
    __syncthreads();
    sm[tid] += t;
    __syncthreads();
  }
  if (tid < ntiles) tilesum[tid] = sm[tid] - v;
  if (tid == ntiles - 1) tilesum[ntiles] = sm[tid];
}

__global__ __launch_bounds__(1024) void scan_c(int* __restrict__ row_ptr,
                                               const int* __restrict__ tilesum, int n,
                                               int ntiles) {
  int idx = blockIdx.x * 1024 + threadIdx.x;
  if (idx < n) row_ptr[idx] += tilesum[blockIdx.x];
  if (idx == 0) row_ptr[n] = tilesum[ntiles];
}

__global__ void scatter_kernel(const int* __restrict__ adj, const float* __restrict__ av,
                               const int* __restrict__ row_ptr, int* __restrict__ cursor,
                               int* __restrict__ csr_dst, float* __restrict__ csr_w, int E) {
  for (int e = blockIdx.x * blockDim.x + threadIdx.x; e < E; e += gridDim.x * blockDim.x) {
    int s = adj[2 * e], d = adj[2 * e + 1];
    int pos = row_ptr[s] + atomicAdd(&cursor[s], 1);
    csr_dst[pos] = d;
    csr_w[pos] = av[e];
  }
}

// ---------------- W transpose: WT[h][d][k] = bf16(W[h][k][d]) ----------------
__global__ void transw_kernel(const float* __restrict__ W, unsigned short* __restrict__ WT) {
  int idx = blockIdx.x * 256 + threadIdx.x;
  int d = idx & 127;
  int k = (idx >> 7) & 255;
  int h = idx >> 15;
  WT[((size_t)h * 128 + d) * 256 + k] = f2bf(W[idx]);
}

// ---------------- ft = features @ W_trans via MFMA, bf16 out, layout (N, H*128) ----
__global__ __launch_bounds__(256) void gemm_mfma(const float* __restrict__ A,
                                                 const unsigned short* __restrict__ WT,
                                                 unsigned short* __restrict__ ft, int N,
                                                 int H) {
  __shared__ unsigned short tile[4][32][136];  // per-wave staging, padded stride
  const int K = 256;
  int h = blockIdx.x;
  int w = threadIdx.x >> 6;
  int r0 = blockIdx.y * 128 + w * 32;
  int lane = threadIdx.x & 63;
  int lr = lane & 15, lg = lane >> 4;
  int ra0 = min(r0 + lr, N - 1);
  int ra1 = min(r0 + 16 + lr, N - 1);
  const float* pa0 = A + (size_t)ra0 * K + lg * 8;
  const float* pa1 = A + (size_t)ra1 * K + lg * 8;
  const unsigned short* pb = WT + ((size_t)h * 128 + lr) * K + lg * 8;
  size_t st = (size_t)H * 128;

  f32x4 acc[2][8] = {};
  for (int k0 = 0; k0 < K; k0 += 32) {
    union {
      bf16x8 v;
      unsigned int u[4];
    } a0, a1;
    float4 f0 = *(const float4*)(pa0 + k0);
    float4 f1 = *(const float4*)(pa0 + k0 + 4);
    a0.u[0] = cvtpk(f0.x, f0.y);
    a0.u[1] = cvtpk(f0.z, f0.w);
    a0.u[2] = cvtpk(f1.x, f1.y);
    a0.u[3] = cvtpk(f1.z, f1.w);
    float4 g0 = *(const float4*)(pa1 + k0);
    float4 g1 = *(const float4*)(pa1 + k0 + 4);
    a1.u[0] = cvtpk(g0.x, g0.y);
    a1.u[1] = cvtpk(g0.z, g0.w);
    a1.u[2] = cvtpk(g1.x, g1.y);
    a1.u[3] = cvtpk(g1.z, g1.w);
    bf16x8 b[8];
#pragma unroll
    for (int cb = 0; cb < 8; ++cb) b[cb] = *(const bf16x8*)(pb + (size_t)cb * 16 * K + k0);
#pragma unroll
    for (int cb = 0; cb < 8; ++cb) {
      acc[0][cb] = __builtin_amdgcn_mfma_f32_16x16x32_bf16(a0.v, b[cb], acc[0][cb], 0, 0, 0);
      acc[1][cb] = __builtin_amdgcn_mfma_f32_16x16x32_bf16(a1.v, b[cb], acc[1][cb], 0, 0, 0);
    }
  }
#pragma unroll
  for (int i = 0; i < 2; ++i) {
#pragma unroll
    for (int cb = 0; cb < 8; ++cb) {
      int rbase = i * 16 + lg * 4;
      int col = cb * 16 + lr;
      unsigned int u01 = cvtpk(acc[i][cb][0], acc[i][cb][1]);
      unsigned int u23 = cvtpk(acc[i][cb][2], acc[i][cb][3]);
      tile[w][rbase + 0][col] = (unsigned short)u01;
      tile[w][rbase + 1][col] = (unsigned short)(u01 >> 16);
      tile[w][rbase + 2][col] = (unsigned short)u23;
      tile[w][rbase + 3][col] = (unsigned short)(u23 >> 16);
    }
  }
#pragma unroll
  for (int rr = 0; rr < 8; ++rr) {
    int row = rr * 4 + lg;
    int nb = r0 + row;
    if (nb < N) {
      *(uint4*)&ft[(size_t)nb * st + (size_t)h * 128 + lr * 8] =
          *(const uint4*)&tile[w][row][lr * 8];
    }
  }
}

// ---------------- per-node prep: rnorm, ftx, fty (layout n*H + h) ----------------
__global__ __launch_bounds__(256) void node_prep(const unsigned short* __restrict__ ft,
                                                 const float* __restrict__ w_ftx,
                                                 const float* __restrict__ w_fty,
                                                 float* __restrict__ rnorm,
                                                 float* __restrict__ ftx,
                                                 float* __restrict__ fty, int N, int H) {
  int wid = blockIdx.x * 4 + (threadIdx.x >> 6);  // wid = n*H + h
  int lane = threadIdx.x & 63;
  if (wid >= N * H) return;
  int h = wid & 3;
  f32x2 f = bfp2(*(const unsigned int*)&ft[(size_t)wid * 128 + lane * 2]);
  float2 wx = *(const float2*)&w_ftx[(size_t)h * 128 + lane * 2];
  float2 wy = *(const float2*)&w_fty[(size_t)h * 128 + lane * 2];
  float ss = wave_sum(f[0] * f[0] + f[1] * f[1]);
  float sx = wave_sum(f[0] * wx.x + f[1] * wx.y);
  float sy = wave_sum(f[0] * wy.x + f[1] * wy.y);
  if (lane == 0) {
    rnorm[wid] = rsqrtf(fmaxf(ss, 1e-12f));
    ftx[wid] = sx;
    fty[wid] = sy;
  }
}

// ---------------- fused sim + aggregation + view attention + ELU ----------------
// One wave per NODE (all 4 heads). lane = lg*16+ll: head lg, dims ll*8..ll*8+7.
// Single row-gather per edge: sim dot + all three weighted accumulations happen
// in one loop. adj channel uses fixed shift 1.0 (values uniform[0,1)); sim channel
// uses shift 0 (|cos| <= ~1) -- softmax is shift-invariant, so identical math.
// nn channel's data-dependent max needs only 4B fty gathers (pre-pass).
__global__ __launch_bounds__(256) void aggregate_kernel(
    const unsigned short* __restrict__ ft, const float* __restrict__ ftx,
    const float* __restrict__ fty, const float* __restrict__ rnorm,
    const int* __restrict__ row_ptr, const int* __restrict__ csr_dst,
    const float* __restrict__ csr_w, const float* __restrict__ w_view,
    const float* __restrict__ bias, float* __restrict__ out, int N, int H) {
  __shared__ float4 wbuf[4][64][4];  // [wave][edge][head] {pa, pn, rn_dst, -}
  __shared__ int dbuf[4][64];        // [wave][edge] uint4-index of dst row
  int wslot = threadIdx.x >> 6;
  int n = blockIdx.x * 4 + wslot;
  int lane = threadIdx.x & 63;
  int lg = lane >> 4, ll = lane & 15;
  if (n >= N) return;
  int start = __builtin_amdgcn_readfirstlane(row_ptr[n]);
  int end = __builtin_amdgcn_readfirstlane(row_ptr[n + 1]);
  int deg = end - start;
  const uint4* ft4 = (const uint4*)ft;  // node row r at index r*64 + lane
  float ftx_nh = ftx[(size_t)n * 4 + lg];
  float rn_n = rnorm[(size_t)n * 4 + lg];

  // own row in regs (sim dots + epilogue)
  uint4 su = ft4[(size_t)n * 64 + lane];
  f32x2 fsu[4] = {bfp2(su.x), bfp2(su.y), bfp2(su.z), bfp2(su.w)};

  // dot of gathered row u with own row, per head lg (uniform in group after grp_sum)
  auto dot_own = [&](uint4 u) -> float {
    f32x2 pp = bfp2(u.x) * fsu[0];
    pp += bfp2(u.y) * fsu[1];
    pp += bfp2(u.z) * fsu[2];
    pp += bfp2(u.w) * fsu[3];
    return grp_sum(pp[0] + pp[1]);
  };

  f32x2 Oa[4] = {}, Os[4] = {}, On[4] = {};
  float ss = 0.f;  // running sim-softmax denominator (uniform within group)

  // single-edge work: gather u (done by caller), dot -> sim -> exp -> accumulate
  auto process = [&](uint4 u, float4 wv) {
    float d = dot_own(u);
    float es = __expf(d * rn_n * wv.z);
    ss += es;
    f32x2 f[4] = {bfp2(u.x), bfp2(u.y), bfp2(u.z), bfp2(u.w)};
#pragma unroll
    for (int k = 0; k < 4; ++k) {
      Oa[k] += f[k] * wv.x;
      Os[k] += f[k] * es;
      On[k] += f[k] * wv.y;
    }
  };

  if (deg > 0 && deg <= 64) {
    // ---- loop 0: cheap stats (4B gathers only) ----
    float wc[4], vc[4], rnd[4];
    int dc[4];
    float mxn = -INFINITY;
#pragma unroll
    for (int t = 0; t < 4; ++t) {
      int idx = t * 16 + ll;
      bool in = idx < deg;
      int j = in ? (start + idx) : start;
      wc[t] = in ? csr_w[j] : -INFINITY;
      dc[t] = csr_dst[j];
      rnd[t] = rnorm[(size_t)dc[t] * 4 + lg];
      vc[t] = in ? lrelu(ftx_nh + fty[(size_t)dc[t] * 4 + lg]) : -INFINITY;
      mxn = fmaxf(mxn, vc[t]);
    }
    mxn = grp_max(mxn);
    float ea[4], e1[4];
    float sa = 0.f, s1 = 0.f;
#pragma unroll
    for (int t = 0; t < 4; ++t) {
      ea[t] = __expf(wc[t] - 1.f);  // fixed shift (values in [0,1)); 0 for pad
      e1[t] = __expf(vc[t] - mxn);
      sa += ea[t];
      s1 += e1[t];
    }
    sa = grp_sum(sa);
    float inv1 = 1.f / grp_sum(s1);
    float en[4];
    float s2 = 0.f;
#pragma unroll
    for (int t = 0; t < 4; ++t) {
      bool in = (t * 16 + ll) < deg;
      en[t] = in ? __expf((e1[t] - 1.f) * inv1) : 0.f;
      s2 += en[t];
    }
    s2 = grp_sum(s2);
    float ra = 1.f / sa, rn2 = 1.f / s2;
#pragma unroll
    for (int t = 0; t < 4; ++t) {
      int idx = t * 16 + ll;
      if (idx < deg) {
        wbuf[wslot][idx][lg] = make_float4(ea[t] * ra, en[t] * rn2, rnd[t], 0.f);
        if (lg == 0) dbuf[wslot][idx] = dc[t] * 64;
      }
    }
    // ---- loop 1: THE row-gather loop (one gather per edge), 4-deep MLP ----
    int jj = 0;
    for (; jj + 4 <= deg; jj += 4) {
      int r0 = dbuf[wslot][jj + 0], r1 = dbuf[wslot][jj + 1];
      int r2 = dbuf[wslot][jj + 2], r3 = dbuf[wslot][jj + 3];
      float4 w0 = wbuf[wslot][jj + 0][lg], w1 = wbuf[wslot][jj + 1][lg];
      float4 w2 = wbuf[wslot][jj + 2][lg], w3 = wbuf[wslot][jj + 3][lg];
      uint4 u0 = ft4[r0 + lane], u1 = ft4[r1 + lane];
      uint4 u2 = ft4[r2 + lane], u3 = ft4[r3 + lane];
      process(u0, w0);
      process(u1, w1);
      process(u2, w2);
      process(u3, w3);
    }
    for (; jj < deg; ++jj) {
      int r0 = dbuf[wslot][jj];
      float4 w0 = wbuf[wslot][jj][lg];
      uint4 u0 = ft4[r0 + lane];
      process(u0, w0);
    }
  } else if (deg > 0) {
    // ---- generic path (deg > 64): strided cheap-stat sweeps, chunked gather loop ----
    float mxn = -INFINITY;
    for (int idx = ll; idx < deg; idx += 16) {
      int j = start + idx;
      mxn = fmaxf(mxn, lrelu(ftx_nh + fty[(size_t)csr_dst[j] * 4 + lg]));
    }
    mxn = grp_max(mxn);
    float sa = 0.f, s1 = 0.f;
    for (int idx = ll; idx < deg; idx += 16) {
      int j = start + idx;
      sa += __expf(csr_w[j] - 1.f);
      s1 += __expf(lrelu(ftx_nh + fty[(size_t)csr_dst[j] * 4 + lg]) - mxn);
    }
    sa = grp_sum(sa);
    float inv1 = 1.f / grp_sum(s1);
    float s2 = 0.f;
    for (int idx = ll; idx < deg; idx += 16) {
      int j = start + idx;
      float e1 = __expf(lrelu(ftx_nh + fty[(size_t)csr_dst[j] * 4 + lg]) - mxn);
      s2 += __expf((e1 - 1.f) * inv1);
    }
    s2 = grp_sum(s2);
    float ra = 1.f / sa, rn2 = 1.f / s2;
    for (int c0 = 0; c0 < deg; c0 += 64) {
      int cnt = min(64, deg - c0);
#pragma unroll
      for (int t = 0; t < 4; ++t) {
        int loc = t * 16 + ll;
        if (loc < cnt) {
          int j = start + c0 + loc;
          int d = csr_dst[j];
          float pa = __expf(csr_w[j] - 1.f) * ra;
          float e1 = __expf(lrelu(ftx_nh + fty[(size_t)d * 4 + lg]) - mxn);
          float pn = __expf((e1 - 1.f) * inv1) * rn2;
          wbuf[wslot][loc][lg] = make_float4(pa, pn, rnorm[(size_t)d * 4 + lg], 0.f);
          if (lg == 0) dbuf[wslot][loc] = d * 64;
        }
      }
      for (int jj = 0; jj < cnt; ++jj) {
        int r0 = dbuf[wslot][jj];
        float4 w0 = wbuf[wslot][jj][lg];
        uint4 u0 = ft4[r0 + lane];
        process(u0, w0);
      }
    }
  }

  // normalize sim channel (ss uniform within group)
  if (deg > 0) {
    float rs = 1.f / ss;
#pragma unroll
    for (int k = 0; k < 4; ++k) Os[k] *= rs;
  }

  // ---- epilogue: view attention per head group ----
  f32x2* fi = fsu;
  const float4* wa4 = (const float4*)&w_view[(size_t)lg * 256 + ll * 8];
  const float4* wb4 = (const float4*)&w_view[(size_t)lg * 256 + 128 + ll * 8];
  float4 wa0 = wa4[0], wa1 = wa4[1];
  float4 wb0 = wb4[0], wb1 = wb4[1];
  float waf[8] = {wa0.x, wa0.y, wa0.z, wa0.w, wa1.x, wa1.y, wa1.z, wa1.w};
  float wbf[8] = {wb0.x, wb0.y, wb0.z, wb0.w, wb1.x, wb1.y, wb1.z, wb1.w};
  float d0 = 0.f, b0 = 0.f, b1 = 0.f, b2 = 0.f, b3 = 0.f;
#pragma unroll
  for (int k = 0; k < 4; ++k) {
    d0 += fi[k][0] * waf[2 * k] + fi[k][1] * waf[2 * k + 1];
    b0 += fi[k][0] * wbf[2 * k] + fi[k][1] * wbf[2 * k + 1];
    b1 += Oa[k][0] * wbf[2 * k] + Oa[k][1] * wbf[2 * k + 1];
    b2 += Os[k][0] * wbf[2 * k] + Os[k][1] * wbf[2 * k + 1];
    b3 += On[k][0] * wbf[2 * k] + On[k][1] * wbf[2 * k + 1];
  }
  d0 = grp_sum(d0);
  b0 = grp_sum(b0);
  b1 = grp_sum(b1);
  b2 = grp_sum(b2);
  b3 = grp_sum(b3);
  float z0 = __expf(lrelu(d0 + b0));
  float z1 = __expf(lrelu(d0 + b1));
  float z2 = __expf(lrelu(d0 + b2));
  float z3 = __expf(lrelu(d0 + b3));
  float zm = fmaxf(fmaxf(z0, z1), fmaxf(z2, z3));
  float c0 = __expf(z0 - zm), c1 = __expf(z1 - zm), c2 = __expf(z2 - zm),
        c3 = __expf(z3 - zm);
  float rcs = 1.f / (c0 + c1 + c2 + c3);
  c0 *= rcs;
  c1 *= rcs;
  c2 *= rcs;
  c3 *= rcs;
  const float4* bb4 = (const float4*)&bias[(size_t)lg * 128 + ll * 8];
  float4 bv0 = bb4[0], bv1 = bb4[1];
  float bbf[8] = {bv0.x, bv0.y, bv0.z, bv0.w, bv1.x, bv1.y, bv1.z, bv1.w};
  float of[8];
#pragma unroll
  for (int k = 0; k < 4; ++k) {
    float ox = c0 * fi[k][0] + c1 * Oa[k][0] + c2 * Os[k][0] + c3 * On[k][0] + bbf[2 * k];
    float oy =
        c0 * fi[k][1] + c1 * Oa[k][1] + c2 * Os[k][1] + c3 * On[k][1] + bbf[2 * k + 1];
    of[2 * k] = ox > 0.f ? ox : expm1f(ox);
    of[2 * k + 1] = oy > 0.f ? oy : expm1f(oy);
  }
  float4* po = (float4*)&out[(size_t)n * 512 + lane * 8];
  po[0] = make_float4(of[0], of[1], of[2], of[3]);
  po[1] = make_float4(of[4], of[5], of[6], of[7]);
}

extern "C" void kernel_launch(void* const* d_in, const int* in_sizes, int n_in,
                              void* d_out, int out_size, void* d_ws, size_t ws_size,
                              hipStream_t stream) {
  const float* features = (const float*)d_in[0];
  const int* adj = (const int*)d_in[1];
  const float* adj_val = (const float*)d_in[2];
  const float* W_trans = (const float*)d_in[3];
  const float* w_ftx = (const float*)d_in[4];
  const float* w_fty = (const float*)d_in[5];
  const float* w_view = (const float*)d_in[6];
  const float* bias = (const float*)d_in[7];
  float* out = (float*)d_out;

  const int IN_DIM = 256, D = 128;
  const int N = in_sizes[0] / IN_DIM;
  const int E = in_sizes[2];
  const int H = in_sizes[7] / D;

  char* p = (char*)d_ws;
  auto alloc = [&](size_t bytes) {
    char* r = p;
    p += (bytes + 255) & ~(size_t)255;
    return r;
  };
  // total ~60 MB
  unsigned short* ft = (unsigned short*)alloc((size_t)N * H * D * 2);  // 51.2 MB (N, H*128)
  float* rnorm = (float*)alloc((size_t)N * H * 4);
  float* ftx = (float*)alloc((size_t)N * H * 4);
  float* fty = (float*)alloc((size_t)N * H * 4);
  int* row_ptr = (int*)alloc((size_t)(N + 1) * 4);
  int* deg = (int*)alloc((size_t)N * 4);
  int* cursor = (int*)alloc((size_t)N * 4);
  int* csr_dst = (int*)alloc((size_t)E * 4);
  float* csr_w = (float*)alloc((size_t)E * 4);
  unsigned short* WT = (unsigned short*)alloc((size_t)H * IN_DIM * D * 2);  // 512 KB
  int* tilesum = (int*)alloc(4096 * 4);
  (void)ws_size;
  (void)n_in;
  (void)out_size;

  int ntiles = (N + 1023) / 1024;

  // CSR build
  zero2_kernel<<<256, 256, 0, stream>>>(deg, cursor, N);
  hist_kernel<<<1024, 256, 0, stream>>>(adj, deg, E);
  scan_a<<<ntiles, 1024, 0, stream>>>(deg, row_ptr, tilesum, N);
  scan_b<<<1, 1024, 0, stream>>>(tilesum, ntiles);
  scan_c<<<ntiles, 1024, 0, stream>>>(row_ptr, tilesum, N, ntiles);
  scatter_kernel<<<1024, 256, 0, stream>>>(adj, adj_val, row_ptr, cursor, csr_dst, csr_w, E);

  // W transpose + MFMA GEMM (ft bf16, (N, H*128))
  transw_kernel<<<(H * IN_DIM * D) / 256, 256, 0, stream>>>(W_trans, WT);
  dim3 ggrid(H, (N + 127) / 128);
  gemm_mfma<<<ggrid, 256, 0, stream>>>(features, WT, ft, N, H);

  // per-node scalars
  int waves = N * H;
  node_prep<<<(waves + 3) / 4, 256, 0, stream>>>(ft, w_ftx, w_fty, rnorm, ftx, fty, N, H);

  // fused sim + aggregation + view attention (one wave per node, all heads)
  dim3 agrid((N + 3) / 4);
  aggregate_kernel<<<agrid, 256, 0, stream>>>(ft, ftx, fty, rnorm, row_ptr, csr_dst, csr_w,
                                              w_view, bias, out, N, H);
}

// Round 11
// 376.780 us; speedup vs baseline: 3.9394x; 1.0326x over previous
//
#include <hip/hip_runtime.h>
#include <math.h>

#define LALPHA 0.2f

using bf16x8 = __attribute__((ext_vector_type(8))) short;
using f32x4 = __attribute__((ext_vector_type(4))) float;
using f32x2 = __attribute__((ext_vector_type(2))) float;

__device__ __forceinline__ float wave_sum(float v) {
#pragma unroll
  for (int off = 32; off > 0; off >>= 1) v += __shfl_xor(v, off);
  return v;
}
// 16-lane group reduce (lanes with same lane>>4)
__device__ __forceinline__ float grp_sum(float v) {
#pragma unroll
  for (int off = 8; off > 0; off >>= 1) v += __shfl_xor(v, off);
  return v;
}
__device__ __forceinline__ float grp_max(float v) {
#pragma unroll
  for (int off = 8; off > 0; off >>= 1) v = fmaxf(v, __shfl_xor(v, off));
  return v;
}
__device__ __forceinline__ float lrelu(float x) { return x >= 0.f ? x : LALPHA * x; }

// bf16 pair -> f32x2 (bf16 = high 16 bits of f32)
__device__ __forceinline__ f32x2 bfp2(unsigned int u) {
  f32x2 r;
  r[0] = __uint_as_float(u << 16);
  r[1] = __uint_as_float(u & 0xffff0000u);
  return r;
}
__device__ __forceinline__ unsigned short f2bf(float x) {
  unsigned int b = __float_as_uint(x);
  return (unsigned short)((b + 0x7fffu + ((b >> 16) & 1u)) >> 16);  // RNE
}
__device__ __forceinline__ unsigned int cvtpk(float lo, float hi) {
  unsigned int r;
  asm("v_cvt_pk_bf16_f32 %0, %1, %2" : "=v"(r) : "v"(lo), "v"(hi));
  return r;
}

// ---------------- CSR build ----------------
__global__ void zero2_kernel(int* a, int* b, int n) {
  for (int i = blockIdx.x * blockDim.x + threadIdx.x; i < n; i += gridDim.x * blockDim.x) {
    a[i] = 0;
    b[i] = 0;
  }
}

__global__ void hist_kernel(const int* __restrict__ adj, int* __restrict__ deg, int E) {
  for (int e = blockIdx.x * blockDim.x + threadIdx.x; e < E; e += gridDim.x * blockDim.x)
    atomicAdd(&deg[adj[2 * e]], 1);
}

__global__ __launch_bounds__(1024) void scan_a(const int* __restrict__ deg,
                                               int* __restrict__ row_ptr,
                                               int* __restrict__ tilesum, int n) {
  __shared__ int sm[1024];
  int tid = threadIdx.x;
  int idx = blockIdx.x * 1024 + tid;
  int v = (idx < n) ? deg[idx] : 0;
  sm[tid] = v;
  __syncthreads();
  for (int off = 1; off < 1024; off <<= 1) {
    int t = (tid >= off) ? sm[tid - off] : 0;
    __syncthreads();
    sm[tid] += t;
    __syncthreads();
  }
  if (idx < n) row_ptr[idx] = sm[tid] - v;
  if (tid == 1023) tilesum[blockIdx.x] = sm[1023];
}

__global__ __launch_bounds__(1024) void scan_b(int* __restrict__ tilesum, int ntiles) {
  __shared__ int sm[1024];
  int tid = threadIdx.x;
  int v = (tid < ntiles) ? tilesum[tid] : 0;
  sm[tid] = v;
  __syncthreads();
  for (int off = 1; off < 1024; off <<= 1) {
    int t = (tid >= off) ? sm[tid - off] : 0;
    __syncthreads();
    sm[tid] += t;
    __syncthreads();
  }
  if (tid < ntiles) tilesum[tid] = sm[tid] - v;
  if (tid == ntiles - 1) tilesum[ntiles] = sm[tid];
}

__global__ __launch_bounds__(1024) void scan_c(int* __restrict__ row_ptr,
                                               const int* __restrict__ tilesum, int n,
                                               int ntiles) {
  int idx = blockIdx.x * 1024 + threadIdx.x;
  if (idx < n) row_ptr[idx] += tilesum[blockIdx.x];
  if (idx == 0) row_ptr[n] = tilesum[ntiles];
}

__global__ void scatter_kernel(const int* __restrict__ adj, const float* __restrict__ av,
                               const int* __restrict__ row_ptr, int* __restrict__ cursor,
                               int* __restrict__ csr_dst, float* __restrict__ csr_w, int E) {
  for (int e = blockIdx.x * blockDim.x + threadIdx.x; e < E; e += gridDim.x * blockDim.x) {
    int s = adj[2 * e], d = adj[2 * e + 1];
    int pos = row_ptr[s] + atomicAdd(&cursor[s], 1);
    csr_dst[pos] = d;
    csr_w[pos] = av[e];
  }
}

// ---------------- W transpose: WT[h][d][k] = bf16(W[h][k][d]) ----------------
__global__ void transw_kernel(const float* __restrict__ W, unsigned short* __restrict__ WT) {
  int idx = blockIdx.x * 256 + threadIdx.x;
  int d = idx & 127;
  int k = (idx >> 7) & 255;
  int h = idx >> 15;
  WT[((size_t)h * 128 + d) * 256 + k] = f2bf(W[idx]);
}

// ---------------- ft = features @ W_trans via MFMA, bf16 out, layout (N, H*128) ----
__global__ __launch_bounds__(256) void gemm_mfma(const float* __restrict__ A,
                                                 const unsigned short* __restrict__ WT,
                                                 unsigned short* __restrict__ ft, int N,
                                                 int H) {
  __shared__ unsigned short tile[4][32][136];  // per-wave staging, padded stride
  const int K = 256;
  int h = blockIdx.x;
  int w = threadIdx.x >> 6;
  int r0 = blockIdx.y * 128 + w * 32;
  int lane = threadIdx.x & 63;
  int lr = lane & 15, lg = lane >> 4;
  int ra0 = min(r0 + lr, N - 1);
  int ra1 = min(r0 + 16 + lr, N - 1);
  const float* pa0 = A + (size_t)ra0 * K + lg * 8;
  const float* pa1 = A + (size_t)ra1 * K + lg * 8;
  const unsigned short* pb = WT + ((size_t)h * 128 + lr) * K + lg * 8;
  size_t st = (size_t)H * 128;

  f32x4 acc[2][8] = {};
  for (int k0 = 0; k0 < K; k0 += 32) {
    union {
      bf16x8 v;
      unsigned int u[4];
    } a0, a1;
    float4 f0 = *(const float4*)(pa0 + k0);
    float4 f1 = *(const float4*)(pa0 + k0 + 4);
    a0.u[0] = cvtpk(f0.x, f0.y);
    a0.u[1] = cvtpk(f0.z, f0.w);
    a0.u[2] = cvtpk(f1.x, f1.y);
    a0.u[3] = cvtpk(f1.z, f1.w);
    float4 g0 = *(const float4*)(pa1 + k0);
    float4 g1 = *(const float4*)(pa1 + k0 + 4);
    a1.u[0] = cvtpk(g0.x, g0.y);
    a1.u[1] = cvtpk(g0.z, g0.w);
    a1.u[2] = cvtpk(g1.x, g1.y);
    a1.u[3] = cvtpk(g1.z, g1.w);
    bf16x8 b[8];
#pragma unroll
    for (int cb = 0; cb < 8; ++cb) b[cb] = *(const bf16x8*)(pb + (size_t)cb * 16 * K + k0);
#pragma unroll
    for (int cb = 0; cb < 8; ++cb) {
      acc[0][cb] = __builtin_amdgcn_mfma_f32_16x16x32_bf16(a0.v, b[cb], acc[0][cb], 0, 0, 0);
      acc[1][cb] = __builtin_amdgcn_mfma_f32_16x16x32_bf16(a1.v, b[cb], acc[1][cb], 0, 0, 0);
    }
  }
#pragma unroll
  for (int i = 0; i < 2; ++i) {
#pragma unroll
    for (int cb = 0; cb < 8; ++cb) {
      int rbase = i * 16 + lg * 4;
      int col = cb * 16 + lr;
      unsigned int u01 = cvtpk(acc[i][cb][0], acc[i][cb][1]);
      unsigned int u23 = cvtpk(acc[i][cb][2], acc[i][cb][3]);
      tile[w][rbase + 0][col] = (unsigned short)u01;
      tile[w][rbase + 1][col] = (unsigned short)(u01 >> 16);
      tile[w][rbase + 2][col] = (unsigned short)u23;
      tile[w][rbase + 3][col] = (unsigned short)(u23 >> 16);
    }
  }
#pragma unroll
  for (int rr = 0; rr < 8; ++rr) {
    int row = rr * 4 + lg;
    int nb = r0 + row;
    if (nb < N) {
      *(uint4*)&ft[(size_t)nb * st + (size_t)h * 128 + lr * 8] =
          *(const uint4*)&tile[w][row][lr * 8];
    }
  }
}

// ---------------- per-node prep: rnorm, ftx, fty (layout n*H + h) ----------------
__global__ __launch_bounds__(256) void node_prep(const unsigned short* __restrict__ ft,
                                                 const float* __restrict__ w_ftx,
                                                 const float* __restrict__ w_fty,
                                                 float* __restrict__ rnorm,
                                                 float* __restrict__ ftx,
                                                 float* __restrict__ fty, int N, int H) {
  int wid = blockIdx.x * 4 + (threadIdx.x >> 6);  // wid = n*H + h
  int lane = threadIdx.x & 63;
  if (wid >= N * H) return;
  int h = wid & 3;
  f32x2 f = bfp2(*(const unsigned int*)&ft[(size_t)wid * 128 + lane * 2]);
  float2 wx = *(const float2*)&w_ftx[(size_t)h * 128 + lane * 2];
  float2 wy = *(const float2*)&w_fty[(size_t)h * 128 + lane * 2];
  float ss = wave_sum(f[0] * f[0] + f[1] * f[1]);
  float sx = wave_sum(f[0] * wx.x + f[1] * wx.y);
  float sy = wave_sum(f[0] * wy.x + f[1] * wy.y);
  if (lane == 0) {
    rnorm[wid] = rsqrtf(fmaxf(ss, 1e-12f));
    ftx[wid] = sx;
    fty[wid] = sy;
  }
}

// ---------------- fused sim + aggregation + view attention + ELU ----------------
// One wave per NODE (all 4 heads). lane = lg*16+ll: head lg, dims ll*8..ll*8+7.
// Single row-gather per edge: sim dot + all three weighted accumulations happen
// in one loop. adj channel uses fixed shift 1.0 (values uniform[0,1)); sim channel
// uses shift 0 (|cos| <= ~1) -- softmax is shift-invariant, so identical math.
// nn channel's data-dependent max needs only 4B fty gathers (pre-pass).
__global__ __launch_bounds__(256) void aggregate_kernel(
    const unsigned short* __restrict__ ft, const float* __restrict__ ftx,
    const float* __restrict__ fty, const float* __restrict__ rnorm,
    const int* __restrict__ row_ptr, const int* __restrict__ csr_dst,
    const float* __restrict__ csr_w, const float* __restrict__ w_view,
    const float* __restrict__ bias, float* __restrict__ out, int N, int H) {
  __shared__ float4 wbuf[4][64][4];  // [wave][edge][head] {pa, pn, rn_dst, -}
  __shared__ int dbuf[4][64];        // [wave][edge] uint4-index of dst row
  int wslot = threadIdx.x >> 6;
  int n = blockIdx.x * 4 + wslot;
  int lane = threadIdx.x & 63;
  int lg = lane >> 4, ll = lane & 15;
  if (n >= N) return;
  int start = __builtin_amdgcn_readfirstlane(row_ptr[n]);
  int end = __builtin_amdgcn_readfirstlane(row_ptr[n + 1]);
  int deg = end - start;
  const uint4* ft4 = (const uint4*)ft;  // node row r at index r*64 + lane
  float ftx_nh = ftx[(size_t)n * 4 + lg];
  float rn_n = rnorm[(size_t)n * 4 + lg];

  // own row in regs (sim dots + epilogue)
  uint4 su = ft4[(size_t)n * 64 + lane];
  f32x2 fsu[4] = {bfp2(su.x), bfp2(su.y), bfp2(su.z), bfp2(su.w)};

  // dot of gathered row u with own row, per head lg (uniform in group after grp_sum)
  auto dot_own = [&](uint4 u) -> float {
    f32x2 pp = bfp2(u.x) * fsu[0];
    pp += bfp2(u.y) * fsu[1];
    pp += bfp2(u.z) * fsu[2];
    pp += bfp2(u.w) * fsu[3];
    return grp_sum(pp[0] + pp[1]);
  };

  f32x2 Oa[4] = {}, Os[4] = {}, On[4] = {};
  float ss = 0.f;  // running sim-softmax denominator (uniform within group)

  // single-edge work: gather u (done by caller), dot -> sim -> exp -> accumulate
  auto process = [&](uint4 u, float4 wv) {
    float d = dot_own(u);
    float es = __expf(d * rn_n * wv.z);
    ss += es;
    f32x2 f[4] = {bfp2(u.x), bfp2(u.y), bfp2(u.z), bfp2(u.w)};
#pragma unroll
    for (int k = 0; k < 4; ++k) {
      Oa[k] += f[k] * wv.x;
      Os[k] += f[k] * es;
      On[k] += f[k] * wv.y;
    }
  };

  if (deg > 0 && deg <= 64) {
    // ---- loop 0: cheap stats (4B gathers only) ----
    float wc[4], vc[4], rnd[4];
    int dc[4];
    float mxn = -INFINITY;
#pragma unroll
    for (int t = 0; t < 4; ++t) {
      int idx = t * 16 + ll;
      bool in = idx < deg;
      int j = in ? (start + idx) : start;
      wc[t] = in ? csr_w[j] : -INFINITY;
      dc[t] = csr_dst[j];
      rnd[t] = rnorm[(size_t)dc[t] * 4 + lg];
      vc[t] = in ? lrelu(ftx_nh + fty[(size_t)dc[t] * 4 + lg]) : -INFINITY;
      mxn = fmaxf(mxn, vc[t]);
    }
    mxn = grp_max(mxn);
    float ea[4], e1[4];
    float sa = 0.f, s1 = 0.f;
#pragma unroll
    for (int t = 0; t < 4; ++t) {
      ea[t] = __expf(wc[t] - 1.f);  // fixed shift (values in [0,1)); 0 for pad
      e1[t] = __expf(vc[t] - mxn);
      sa += ea[t];
      s1 += e1[t];
    }
    sa = grp_sum(sa);
    float inv1 = 1.f / grp_sum(s1);
    float en[4];
    float s2 = 0.f;
#pragma unroll
    for (int t = 0; t < 4; ++t) {
      bool in = (t * 16 + ll) < deg;
      en[t] = in ? __expf((e1[t] - 1.f) * inv1) : 0.f;
      s2 += en[t];
    }
    s2 = grp_sum(s2);
    float ra = 1.f / sa, rn2 = 1.f / s2;
#pragma unroll
    for (int t = 0; t < 4; ++t) {
      int idx = t * 16 + ll;
      if (idx < deg) {
        wbuf[wslot][idx][lg] = make_float4(ea[t] * ra, en[t] * rn2, rnd[t], 0.f);
        if (lg == 0) dbuf[wslot][idx] = dc[t] * 64;
      }
    }
    // ---- loop 1: THE row-gather loop (one gather per edge), 4-deep MLP ----
    int jj = 0;
    for (; jj + 4 <= deg; jj += 4) {
      int r0 = dbuf[wslot][jj + 0], r1 = dbuf[wslot][jj + 1];
      int r2 = dbuf[wslot][jj + 2], r3 = dbuf[wslot][jj + 3];
      float4 w0 = wbuf[wslot][jj + 0][lg], w1 = wbuf[wslot][jj + 1][lg];
      float4 w2 = wbuf[wslot][jj + 2][lg], w3 = wbuf[wslot][jj + 3][lg];
      uint4 u0 = ft4[r0 + lane], u1 = ft4[r1 + lane];
      uint4 u2 = ft4[r2 + lane], u3 = ft4[r3 + lane];
      process(u0, w0);
      process(u1, w1);
      process(u2, w2);
      process(u3, w3);
    }
    for (; jj < deg; ++jj) {
      int r0 = dbuf[wslot][jj];
      float4 w0 = wbuf[wslot][jj][lg];
      uint4 u0 = ft4[r0 + lane];
      process(u0, w0);
    }
  } else if (deg > 0) {
    // ---- generic path (deg > 64): strided cheap-stat sweeps, chunked gather loop ----
    float mxn = -INFINITY;
    for (int idx = ll; idx < deg; idx += 16) {
      int j = start + idx;
      mxn = fmaxf(mxn, lrelu(ftx_nh + fty[(size_t)csr_dst[j] * 4 + lg]));
    }
    mxn = grp_max(mxn);
    float sa = 0.f, s1 = 0.f;
    for (int idx = ll; idx < deg; idx += 16) {
      int j = start + idx;
      sa += __expf(csr_w[j] - 1.f);
      s1 += __expf(lrelu(ftx_nh + fty[(size_t)csr_dst[j] * 4 + lg]) - mxn);
    }
    sa = grp_sum(sa);
    float inv1 = 1.f / grp_sum(s1);
    float s2 = 0.f;
    for (int idx = ll; idx < deg; idx += 16) {
      int j = start + idx;
      float e1 = __expf(lrelu(ftx_nh + fty[(size_t)csr_dst[j] * 4 + lg]) - mxn);
      s2 += __expf((e1 - 1.f) * inv1);
    }
    s2 = grp_sum(s2);
    float ra = 1.f / sa, rn2 = 1.f / s2;
    for (int c0 = 0; c0 < deg; c0 += 64) {
      int cnt = min(64, deg - c0);
#pragma unroll
      for (int t = 0; t < 4; ++t) {
        int loc = t * 16 + ll;
        if (loc < cnt) {
          int j = start + c0 + loc;
          int d = csr_dst[j];
          float pa = __expf(csr_w[j] - 1.f) * ra;
          float e1 = __expf(lrelu(ftx_nh + fty[(size_t)d * 4 + lg]) - mxn);
          float pn = __expf((e1 - 1.f) * inv1) * rn2;
          wbuf[wslot][loc][lg] = make_float4(pa, pn, rnorm[(size_t)d * 4 + lg], 0.f);
          if (lg == 0) dbuf[wslot][loc] = d * 64;
        }
      }
      for (int jj = 0; jj < cnt; ++jj) {
        int r0 = dbuf[wslot][jj];
        float4 w0 = wbuf[wslot][jj][lg];
        uint4 u0 = ft4[r0 + lane];
        process(u0, w0);
      }
    }
  }

  // normalize sim channel (ss uniform within group)
  if (deg > 0) {
    float rs = 1.f / ss;
#pragma unroll
    for (int k = 0; k < 4; ++k) Os[k] *= rs;
  }

  // ---- epilogue: view attention per head group ----
  f32x2* fi = fsu;
  const float4* wa4 = (const float4*)&w_view[(size_t)lg * 256 + ll * 8];
  const float4* wb4 = (const float4*)&w_view[(size_t)lg * 256 + 128 + ll * 8];
  float4 wa0 = wa4[0], wa1 = wa4[1];
  float4 wb0 = wb4[0], wb1 = wb4[1];
  float waf[8] = {wa0.x, wa0.y, wa0.z, wa0.w, wa1.x, wa1.y, wa1.z, wa1.w};
  float wbf[8] = {wb0.x, wb0.y, wb0.z, wb0.w, wb1.x, wb1.y, wb1.z, wb1.w};
  float d0 = 0.f, b0 = 0.f, b1 = 0.f, b2 = 0.f, b3 = 0.f;
#pragma unroll
  for (int k = 0; k < 4; ++k) {
    d0 += fi[k][0] * waf[2 * k] + fi[k][1] * waf[2 * k + 1];
    b0 += fi[k][0] * wbf[2 * k] + fi[k][1] * wbf[2 * k + 1];
    b1 += Oa[k][0] * wbf[2 * k] + Oa[k][1] * wbf[2 * k + 1];
    b2 += Os[k][0] * wbf[2 * k] + Os[k][1] * wbf[2 * k + 1];
    b3 += On[k][0] * wbf[2 * k] + On[k][1] * wbf[2 * k + 1];
  }
  d0 = grp_sum(d0);
  b0 = grp_sum(b0);
  b1 = grp_sum(b1);
  b2 = grp_sum(b2);
  b3 = grp_sum(b3);
  float z0 = __expf(lrelu(d0 + b0));
  float z1 = __expf(lrelu(d0 + b1));
  float z2 = __expf(lrelu(d0 + b2));
  float z3 = __expf(lrelu(d0 + b3));
  float zm = fmaxf(fmaxf(z0, z1), fmaxf(z2, z3));
  float c0 = __expf(z0 - zm), c1 = __expf(z1 - zm), c2 = __expf(z2 - zm),
        c3 = __expf(z3 - zm);
  float rcs = 1.f / (c0 + c1 + c2 + c3);
  c0 *= rcs;
  c1 *= rcs;
  c2 *= rcs;
  c3 *= rcs;
  const float4* bb4 = (const float4*)&bias[(size_t)lg * 128 + ll * 8];
  float4 bv0 = bb4[0], bv1 = bb4[1];
  float bbf[8] = {bv0.x, bv0.y, bv0.z, bv0.w, bv1.x, bv1.y, bv1.z, bv1.w};
  float of[8];
#pragma unroll
  for (int k = 0; k < 4; ++k) {
    float ox = c0 * fi[k][0] + c1 * Oa[k][0] + c2 * Os[k][0] + c3 * On[k][0] + bbf[2 * k];
    float oy =
        c0 * fi[k][1] + c1 * Oa[k][1] + c2 * Os[k][1] + c3 * On[k][1] + bbf[2 * k + 1];
    of[2 * k] = ox > 0.f ? ox : expm1f(ox);
    of[2 * k + 1] = oy > 0.f ? oy : expm1f(oy);
  }
  float4* po = (float4*)&out[(size_t)n * 512 + lane * 8];
  po[0] = make_float4(of[0], of[1], of[2], of[3]);
  po[1] = make_float4(of[4], of[5], of[6], of[7]);
}

extern "C" void kernel_launch(void* const* d_in, const int* in_sizes, int n_in,
                              void* d_out, int out_size, void* d_ws, size_t ws_size,
                              hipStream_t stream) {
  const float* features = (const float*)d_in[0];
  const int* adj = (const int*)d_in[1];
  const float* adj_val = (const float*)d_in[2];
  const float* W_trans = (const float*)d_in[3];
  const float* w_ftx = (const float*)d_in[4];
  const float* w_fty = (const float*)d_in[5];
  const float* w_view = (const float*)d_in[6];
  const float* bias = (const float*)d_in[7];
  float* out = (float*)d_out;

  const int IN_DIM = 256, D = 128;
  const int N = in_sizes[0] / IN_DIM;
  const int E = in_sizes[2];
  const int H = in_sizes[7] / D;

  char* p = (char*)d_ws;
  auto alloc = [&](size_t bytes) {
    char* r = p;
    p += (bytes + 255) & ~(size_t)255;
    return r;
  };
  // total ~60 MB
  unsigned short* ft = (unsigned short*)alloc((size_t)N * H * D * 2);  // 51.2 MB (N, H*128)
  float* rnorm = (float*)alloc((size_t)N * H * 4);
  float* ftx = (float*)alloc((size_t)N * H * 4);
  float* fty = (float*)alloc((size_t)N * H * 4);
  int* row_ptr = (int*)alloc((size_t)(N + 1) * 4);
  int* deg = (int*)alloc((size_t)N * 4);
  int* cursor = (int*)alloc((size_t)N * 4);
  int* csr_dst = (int*)alloc((size_t)E * 4);
  float* csr_w = (float*)alloc((size_t)E * 4);
  unsigned short* WT = (unsigned short*)alloc((size_t)H * IN_DIM * D * 2);  // 512 KB
  int* tilesum = (int*)alloc(4096 * 4);
  (void)ws_size;
  (void)n_in;
  (void)out_size;

  int ntiles = (N + 1023) / 1024;

  // CSR build
  zero2_kernel<<<256, 256, 0, stream>>>(deg, cursor, N);
  hist_kernel<<<1024, 256, 0, stream>>>(adj, deg, E);
  scan_a<<<ntiles, 1024, 0, stream>>>(deg, row_ptr, tilesum, N);
  scan_b<<<1, 1024, 0, stream>>>(tilesum, ntiles);
  scan_c<<<ntiles, 1024, 0, stream>>>(row_ptr, tilesum, N, ntiles);
  scatter_kernel<<<1024, 256, 0, stream>>>(adj, adj_val, row_ptr, cursor, csr_dst, csr_w, E);

  // W transpose + MFMA GEMM (ft bf16, (N, H*128))
  transw_kernel<<<(H * IN_DIM * D) / 256, 256, 0, stream>>>(W_trans, WT);
  dim3 ggrid(H, (N + 127) / 128);
  gemm_mfma<<<ggrid, 256, 0, stream>>>(features, WT, ft, N, H);

  // per-node scalars
  int waves = N * H;
  node_prep<<<(waves + 3) / 4, 256, 0, stream>>>(ft, w_ftx, w_fty, rnorm, ftx, fty, N, H);

  // fused sim + aggregation + view attention (one wave per node, all heads)
  dim3 agrid((N + 3) / 4);
  aggregate_kernel<<<agrid, 256, 0, stream>>>(ft, ftx, fty, rnorm, row_ptr, csr_dst, csr_w,
                                              w_view, bias, out, N, H);
}